// Round 3
// baseline (1117.251 us; speedup 1.0000x reference)
//
#include <hip/hip_runtime.h>
#include <hip/hip_bf16.h>

#define EPSBN 2e-5f

typedef __attribute__((ext_vector_type(8))) short short8v;
typedef __attribute__((ext_vector_type(4))) float f32x4;

__device__ inline unsigned short f2bf(float f) {
  unsigned u = __float_as_uint(f);
  unsigned r = (u + 0x7FFFu + ((u >> 16) & 1u)) >> 16;
  return (unsigned short)r;
}
__device__ inline float bf2f(unsigned short h) {
  return __uint_as_float(((unsigned)h) << 16);
}

// ---------------------------------------------------------------------------
// Padded x staging — packed split-bf16: (hi16 << 16) | lo16.
// ---------------------------------------------------------------------------
constexpr int XPADL = 9984;
constexpr int XPADR = 14336;
constexpr int PROW = XPADL + 32768 + XPADR;  // 57088

__global__ __launch_bounds__(256) void pad_x_kernel(const float* __restrict__ x,
                                                    unsigned* __restrict__ xp) {
  int i = blockIdx.x * 256 + threadIdx.x;
  if (i >= 8 * PROW) return;
  int b = i / PROW;
  int pos = i - b * PROW - XPADL;
  float v = (pos >= 0 && pos < 32768) ? x[b * 32768 + pos] : 0.f;
  unsigned u = __float_as_uint(v);
  unsigned h = u >> 16;
  float lof = v - __uint_as_float(u & 0xffff0000u);
  unsigned lo = __float_as_uint(lof) >> 16;
  xp[i] = (h << 16) | lo;
}

// ---------------------------------------------------------------------------
// Per-scale pair-packed B source: for scale s (dilation d=2^s),
//   xpH[(s*8+b)*PROW + i] = hi(x[i]) | hi(x[i+d])<<16
//   xpL[...]              = lo(x[i]) | lo(x[i+d])<<16
// ---------------------------------------------------------------------------
__global__ __launch_bounds__(256) void pad_pair_kernel(
    const unsigned* __restrict__ xp, unsigned* __restrict__ xpH,
    unsigned* __restrict__ xpL) {
  const int i = blockIdx.x * 256 + threadIdx.x;
  if (i >= PROW) return;
  const int sb = blockIdx.y;  // s*8 + b
  const int s = sb >> 3;
  const int b = sb & 7;
  const int d = 1 << s;
  const unsigned* row = xp + b * PROW;
  unsigned u0 = row[i];
  unsigned u1 = (i + d < PROW) ? row[i + d] : 0u;
  size_t o = (size_t)sb * PROW + i;
  xpH[o] = (u0 >> 16) | (u1 & 0xffff0000u);
  xpL[o] = (u0 & 0xffffu) | (u1 << 16);
}

// ---------------------------------------------------------------------------
// Pack w1 [51][79] -> per-s split bf16 (1/2^s folded), [s][hi/lo][64][96]
// ---------------------------------------------------------------------------
__global__ __launch_bounds__(256) void pack_w1_kernel(
    const float* __restrict__ W, short* __restrict__ A) {
  int idx = blockIdx.x * 256 + threadIdx.x;
  if (idx >= 9 * 64 * 96) return;
  int s = idx / (64 * 96);
  int rem = idx - s * 64 * 96;
  int co = rem / 96;
  int k = rem - co * 96;
  float v = 0.f;
  if (co < 51 && k < 79)
    v = W[co * 79 + k] * __uint_as_float((unsigned)(127 - s) << 23);
  unsigned short hi = f2bf(v);
  unsigned short lo = f2bf(v - bf2f(hi));
  A[(size_t)s * 2 * 64 * 96 + co * 96 + k] = (short)hi;
  A[(size_t)s * 2 * 64 * 96 + 64 * 96 + co * 96 + k] = (short)lo;
}

// ---------------------------------------------------------------------------
// lift_mfma: lift conv K=79 as bf16 MFMA GEMM + fused pool4 + fused stats.
// B-column permutation c -> l0 + (c&15)*4 + (c>>4): the 4 pool members of
// each output land in ONE lane across t=0..3, so pool4 is 3 in-register
// fmax (no shuffles) and stores are 4 full-wave coalesced dwords/wave
// (was 16 stores with 3/4 lanes masked). XCD-chunked lc swizzle keeps
// overlapping dilated halos of neighboring blocks in one XCD's L2.
// ---------------------------------------------------------------------------
__global__ __launch_bounds__(256) void lift_mfma_kernel(
    const unsigned* __restrict__ xpH, const unsigned* __restrict__ xpL,
    const short* __restrict__ Apk1, float* __restrict__ y1,
    float* __restrict__ part1) {
  constexpr int P = 104;
  const int bid = blockIdx.x;
  const int lc = (bid & 7) * 64 + (bid >> 3);  // 512 = 8*64, bijective
  const int s = blockIdx.y;
  const int b = blockIdx.z;
  const int d = 1 << s;
  const int l0 = lc * 64;
  const int tid = threadIdx.x;
  const int lane = tid & 63;
  const int quad = lane >> 4;
  const int n0 = lane & 15;
  const int wv = tid >> 6;
  const int coBase = wv * 16;

  __shared__ __align__(16) short Bh[64 * P];
  __shared__ __align__(16) short Bl[64 * P];
  __shared__ float sCh[2][64];

  const int nB = tid & 63;
  const int pos = ((nB & 15) << 2) | (nB >> 4);  // column permutation
  const int ogu = __builtin_amdgcn_readfirstlane(tid >> 6);
  const unsigned* xqH = xpH + (size_t)(s * 8 + b) * PROW + XPADL + l0;
  const unsigned* xqL = xpL + (size_t)(s * 8 + b) * PROW + XPADL + l0;

#pragma unroll
  for (int r = 0; r < 3; ++r) {
    const int kb = (ogu + 4 * r) * 8;
    const int base = (kb - 39) * d;
    uint4 ph, pl;
    ph.x = xqH[base + pos];
    ph.y = xqH[base + 2 * d + pos];
    ph.z = xqH[base + 4 * d + pos];
    ph.w = xqH[base + 6 * d + pos];
    pl.x = xqL[base + pos];
    pl.y = xqL[base + 2 * d + pos];
    pl.z = xqL[base + 4 * d + pos];
    pl.w = xqL[base + 6 * d + pos];
    *(uint4*)(Bh + nB * P + kb) = ph;
    *(uint4*)(Bl + nB * P + kb) = pl;
  }

  const short* ApkS = Apk1 + (size_t)s * 2 * 64 * 96;
  const short* arowH = ApkS + (coBase + n0) * 96;
  const short* arowL = arowH + 64 * 96;

  __syncthreads();

  f32x4 acc[4];
#pragma unroll
  for (int t = 0; t < 4; ++t) acc[t] = (f32x4){0.f, 0.f, 0.f, 0.f};

#pragma unroll
  for (int ks = 0; ks < 3; ++ks) {
    short8v ah = *(const short8v*)(arowH + ks * 32 + quad * 8);
    short8v al = *(const short8v*)(arowL + ks * 32 + quad * 8);
#pragma unroll
    for (int t = 0; t < 4; ++t) {
      const int n = n0 + 16 * t;
      short8v bh = *(const short8v*)(Bh + n * P + ks * 32 + quad * 8);
      short8v bl = *(const short8v*)(Bl + n * P + ks * 32 + quad * 8);
      acc[t] = __builtin_amdgcn_mfma_f32_16x16x32_bf16(ah, bh, acc[t], 0, 0, 0);
      acc[t] = __builtin_amdgcn_mfma_f32_16x16x32_bf16(ah, bl, acc[t], 0, 0, 0);
      acc[t] = __builtin_amdgcn_mfma_f32_16x16x32_bf16(al, bh, acc[t], 0, 0, 0);
    }
  }

  // Epilogue: pool4 over t in-register; lane n0 <-> pooled position l1.
#pragma unroll
  for (int reg = 0; reg < 4; ++reg) {
    const int co = coBase + quad * 4 + reg;
    float po = fmaxf(fmaxf(acc[0][reg], acc[1][reg]),
                     fmaxf(acc[2][reg], acc[3][reg]));
    const bool valid = (co < 51);
    if (valid) {
      y1[(((size_t)b * 51 + co) * 9 + s) * 8192 + (l0 >> 2) + n0] = po;
    }
    float us = valid ? po : 0.f;
    float sq = us * us;
    us += __shfl_xor(us, 1);
    sq += __shfl_xor(sq, 1);
    us += __shfl_xor(us, 2);
    sq += __shfl_xor(sq, 2);
    us += __shfl_xor(us, 4);
    sq += __shfl_xor(sq, 4);
    us += __shfl_xor(us, 8);
    sq += __shfl_xor(sq, 8);
    if (n0 == 0) {
      sCh[0][co] = us;
      sCh[1][co] = sq;
    }
  }
  __syncthreads();
  if (tid < 51) {
    float* pp = part1 + (size_t)lc * 128;
    atomicAdd(&pp[tid], sCh[0][tid]);
    atomicAdd(&pp[64 + tid], sCh[1][tid]);
  }
}

// ---------------------------------------------------------------------------
// Reduce the 512 lc-sliced stats partials (stride 128: [0..50]=sum,
// [64..114]=sumsq) into st[c], st[512+c]. 8 blocks k-split, atomic merge.
// ---------------------------------------------------------------------------
__global__ __launch_bounds__(128) void reduce_stats1_kernel(
    const float* __restrict__ p, float* __restrict__ st) {
  const int t = threadIdx.x;
  if (t >= 102) return;
  const int k0 = blockIdx.x * 64;
  const int off = (t < 51) ? t : (64 + t - 51);
  float s = 0.f;
  for (int k = k0; k < k0 + 64; ++k) s += p[k * 128 + off];
  atomicAdd(&st[(t < 51) ? t : (512 + t - 51)], s);
}

// ---------------------------------------------------------------------------
// Per-channel sum/sumsq over [B,C,HL], HL split NS ways; grid (C,B,NS)
// ---------------------------------------------------------------------------
__global__ __launch_bounds__(256) void stats_kernel(
    const float* __restrict__ Y, float* __restrict__ st, int C, int HL,
    int NS) {
  const int c = blockIdx.x, b = blockIdx.y, z = blockIdx.z;
  const int slice = HL / NS;
  const float* p = Y + ((size_t)b * C + c) * HL + (size_t)z * slice;
  float s = 0.f, q = 0.f;
  for (int i = threadIdx.x; i < slice; i += 256) {
    float v = p[i];
    s += v;
    q += v * v;
  }
#pragma unroll
  for (int off = 32; off > 0; off >>= 1) {
    s += __shfl_down(s, off, 64);
    q += __shfl_down(q, off, 64);
  }
  __shared__ float ls[4], lq[4];
  const int wid = threadIdx.x >> 6, lane = threadIdx.x & 63;
  if (lane == 0) { ls[wid] = s; lq[wid] = q; }
  __syncthreads();
  if (threadIdx.x == 0) {
    atomicAdd(&st[c], ls[0] + ls[1] + ls[2] + ls[3]);
    atomicAdd(&st[512 + c], lq[0] + lq[1] + lq[2] + lq[3]);
  }
}

// ---------------------------------------------------------------------------
// reduce NS partial buffers: y[i] = sum_k p[k*stride + i]
// ---------------------------------------------------------------------------
__global__ __launch_bounds__(256) void reduce_parts_kernel(
    const float* __restrict__ p, float* __restrict__ y, int n, int stride,
    int ns) {
  int i = blockIdx.x * 256 + threadIdx.x;
  if (i >= n) return;
  float s = 0.f;
  for (int k = 0; k < ns; ++k) s += p[(size_t)k * stride + i];
  y[i] = s;
}

// ---------------------------------------------------------------------------
// BN(train)+ReLU+pool4, fp32 out
// ---------------------------------------------------------------------------
__global__ __launch_bounds__(256) void bnrelu_pool_kernel(
    const float* __restrict__ Y, const float* __restrict__ st,
    const float* __restrict__ g, const float* __restrict__ bb,
    float* __restrict__ Z, int C, int H, int Lin, float invN,
    unsigned int total) {
  unsigned int idx = blockIdx.x * 256u + threadIdx.x;
  if (idx >= total) return;
  const unsigned int Lo = (unsigned int)(Lin >> 2);
  unsigned int lo = idx % Lo;
  unsigned int r1 = idx / Lo;
  unsigned int h = r1 % (unsigned int)H;
  unsigned int r2 = r1 / (unsigned int)H;
  unsigned int c = r2 % (unsigned int)C;
  unsigned int b = r2 / (unsigned int)C;
  float m = st[c] * invN;
  float v = st[512 + c] * invN - m * m;
  float sc = g[c] * rsqrtf(v + EPSBN);
  float bi = bb[c] - m * sc;
  const float* p = Y + (((size_t)b * C + c) * H + h) * Lin + 4u * lo;
  float a0 = p[0] * sc + bi, a1 = p[1] * sc + bi;
  float a2 = p[2] * sc + bi, a3 = p[3] * sc + bi;
  float r = fmaxf(fmaxf(a0, a1), fmaxf(a2, a3));
  Z[idx] = fmaxf(r, 0.f);
}

// ---- same, bf16 out
__global__ __launch_bounds__(256) void bnrelu_pool_bf16_kernel(
    const float* __restrict__ Y, const float* __restrict__ st,
    const float* __restrict__ g, const float* __restrict__ bb,
    unsigned short* __restrict__ Z, int C, int H, int Lin, float invN,
    unsigned int total) {
  unsigned int idx = blockIdx.x * 256u + threadIdx.x;
  if (idx >= total) return;
  const unsigned int Lo = (unsigned int)(Lin >> 2);
  unsigned int lo = idx % Lo;
  unsigned int r1 = idx / Lo;
  unsigned int h = r1 % (unsigned int)H;
  unsigned int r2 = r1 / (unsigned int)H;
  unsigned int c = r2 % (unsigned int)C;
  unsigned int b = r2 / (unsigned int)C;
  float m = st[c] * invN;
  float v = st[512 + c] * invN - m * m;
  float sc = g[c] * rsqrtf(v + EPSBN);
  float bi = bb[c] - m * sc;
  const float* p = Y + (((size_t)b * C + c) * H + h) * Lin + 4u * lo;
  float a0 = p[0] * sc + bi, a1 = p[1] * sc + bi;
  float a2 = p[2] * sc + bi, a3 = p[3] * sc + bi;
  float r = fmaxf(fmaxf(a0, a1), fmaxf(a2, a3));
  Z[idx] = f2bf(fmaxf(r, 0.f));
}

// ---------------------------------------------------------------------------
// BN(train)+ReLU elementwise, fp32 / bf16 out
// ---------------------------------------------------------------------------
__global__ __launch_bounds__(256) void bnrelu_kernel(
    const float* __restrict__ Y, const float* __restrict__ st,
    const float* __restrict__ g, const float* __restrict__ bb,
    float* __restrict__ A, int C, int HL, float invN, unsigned int total) {
  unsigned int idx = blockIdx.x * 256u + threadIdx.x;
  if (idx >= total) return;
  unsigned int c = (idx / (unsigned int)HL) % (unsigned int)C;
  float m = st[c] * invN;
  float v = st[512 + c] * invN - m * m;
  float sc = g[c] * rsqrtf(v + EPSBN);
  float bi = bb[c] - m * sc;
  A[idx] = fmaxf(fmaf(Y[idx], sc, bi), 0.f);
}

__global__ __launch_bounds__(256) void bnrelu_bf16_kernel(
    const float* __restrict__ Y, const float* __restrict__ st,
    const float* __restrict__ g, const float* __restrict__ bb,
    unsigned short* __restrict__ A, int C, int HL, float invN,
    unsigned int total) {
  unsigned int idx = blockIdx.x * 256u + threadIdx.x;
  if (idx >= total) return;
  unsigned int c = (idx / (unsigned int)HL) % (unsigned int)C;
  float m = st[c] * invN;
  float v = st[512 + c] * invN - m * m;
  float sc = g[c] * rsqrtf(v + EPSBN);
  float bi = bb[c] - m * sc;
  A[idx] = f2bf(fmaxf(fmaf(Y[idx], sc, bi), 0.f));
}

// ---------------------------------------------------------------------------
// Pack fp32 weights -> per-s split bf16 packs with 2^-(s+i) folded.
// ---------------------------------------------------------------------------
__global__ __launch_bounds__(256) void pack_w2_kernel(
    const float* __restrict__ W, short* __restrict__ A, int Co, int KTOT,
    int KPAD, int COPAD, int NS, int nk3) {
  int idx = blockIdx.x * 256 + threadIdx.x;
  const int CK = COPAD * KPAD;
  if (idx >= NS * CK) return;
  int s = idx / CK;
  int rem = idx - s * CK;
  int co = rem / KPAD;
  int kk = rem - co * KPAD;
  float v = 0.f;
  if (co < Co && kk < KTOT) {
    int i = (kk % nk3) / 3;
    float scale = __uint_as_float((unsigned)(127 - (s + i)) << 23);
    v = W[co * KTOT + kk] * scale;
  }
  unsigned short hi = f2bf(v);
  unsigned short lo = f2bf(v - bf2f(hi));
  A[(size_t)s * 2 * CK + co * KPAD + kk] = (short)hi;
  A[(size_t)s * 2 * CK + CK + co * KPAD + kk] = (short)lo;
}

// ---------------------------------------------------------------------------
// gg_mfma5: bf16-input MFMA GConvGG, no fused stats (R15, unchanged)
// ---------------------------------------------------------------------------
template <int NKv, int LT>
__global__ __launch_bounds__(256) void gg_mfma5_kernel(
    const unsigned short* __restrict__ X, const short* __restrict__ Apk,
    float* __restrict__ Y, int Ci, int Co, int Hin, int L, int nL, int KTOT,
    int KPAD, int COPAD) {
  constexpr int T = LT / 16;
  constexpr int KO = 256 / LT;
  constexpr int RIT = 8 / KO;

  const int bx = blockIdx.x;
  const int lc = bx % nL;
  const int cog = bx / nL;
  const int s = blockIdx.y;
  const int b = blockIdx.z;
  const int Hout = Hin - NKv + 1;
  const int l0 = lc * LT;
  const int tid = threadIdx.x;
  const int lane = tid & 63;
  const int quad = lane >> 4;
  const int m0 = lane & 15;
  const int wv = tid >> 6;
  const int coBase = cog * 64 + wv * 16;

  __shared__ __align__(16) short Bh[LT * 72];
  __shared__ int roT[512];
  __shared__ int shT[512];

  for (int kk = tid; kk < KPAD; kk += 256) {
    int ro = 0, sh = -(1 << 30);
    if (kk < KTOT) {
      int ci = kk / (3 * NKv);
      int rem = kk - ci * (3 * NKv);
      int i = rem / 3;
      int k = rem - 3 * i;
      ro = (ci * Hin + s + i) * L;
      sh = (k - 1) * (1 << (s + i));
    }
    roT[kk] = ro;
    shT[kk] = sh;
  }
  __syncthreads();

  f32x4 acc[T];
#pragma unroll
  for (int t = 0; t < T; ++t) acc[t] = (f32x4){0.f, 0.f, 0.f, 0.f};

  const short* ApkS = Apk + (size_t)s * 2 * COPAD * KPAD;
  const short* arowH = ApkS + (size_t)(coBase + m0) * KPAD;
  const short* arowL = arowH + (size_t)COPAD * KPAD;
  const unsigned short* Xb = X + (size_t)b * Ci * Hin * L;

  const int lB = tid & (LT - 1);
  const int oc0 = tid / LT;
  const int nch = (KTOT + 63) >> 6;

  uint4 v0[RIT], v1[RIT], v2[RIT];
  auto gather = [&](int c0, uint4 (&pk)[RIT]) {
#pragma unroll
    for (int r = 0; r < RIT; ++r) {
      const int oct = oc0 + KO * r;
      const int kkb = (c0 << 6) + oct * 8;
      unsigned w[8];
#pragma unroll
      for (int j = 0; j < 8; ++j) {
        const int kk = kkb + j;
        const int pos = l0 + lB + shT[kk];
        const int posc = min(max(pos, 0), L - 1);
        unsigned u = (unsigned)Xb[roT[kk] + posc];
        w[j] = ((unsigned)pos < (unsigned)L) ? u : 0u;
      }
      pk[r].x = w[0] | (w[1] << 16);
      pk[r].y = w[2] | (w[3] << 16);
      pk[r].z = w[4] | (w[5] << 16);
      pk[r].w = w[6] | (w[7] << 16);
    }
  };

  gather(0, v0);
  if (nch > 1) gather(1, v1);
  for (int c0 = 0; c0 < nch; ++c0) {
#pragma unroll
    for (int r = 0; r < RIT; ++r)
      *(uint4*)(Bh + lB * 72 + (oc0 + KO * r) * 8) = v0[r];
    if (c0 + 2 < nch) gather(c0 + 2, v2);
    const int a0 = (c0 << 6) + quad * 8;
    short8v ah0 = *(const short8v*)(arowH + a0);
    short8v al0 = *(const short8v*)(arowL + a0);
    short8v ah1 = *(const short8v*)(arowH + a0 + 32);
    short8v al1 = *(const short8v*)(arowL + a0 + 32);
    __syncthreads();
#pragma unroll
    for (int t = 0; t < T; ++t) {
      const int l = m0 + 16 * t;
      short8v b0 = *(const short8v*)(Bh + l * 72 + quad * 8);
      short8v b1 = *(const short8v*)(Bh + l * 72 + 32 + quad * 8);
      acc[t] = __builtin_amdgcn_mfma_f32_16x16x32_bf16(ah0, b0, acc[t], 0, 0, 0);
      acc[t] = __builtin_amdgcn_mfma_f32_16x16x32_bf16(al0, b0, acc[t], 0, 0, 0);
      acc[t] = __builtin_amdgcn_mfma_f32_16x16x32_bf16(ah1, b1, acc[t], 0, 0, 0);
      acc[t] = __builtin_amdgcn_mfma_f32_16x16x32_bf16(al1, b1, acc[t], 0, 0, 0);
    }
    __syncthreads();
#pragma unroll
    for (int r = 0; r < RIT; ++r) {
      v0[r] = v1[r];
      v1[r] = v2[r];
    }
  }

#pragma unroll
  for (int reg = 0; reg < 4; ++reg) {
    const int co = coBase + quad * 4 + reg;
    if (co < Co) {
      float* yp = Y + (((size_t)b * Co + co) * Hout + s) * L + l0;
#pragma unroll
      for (int t = 0; t < T; ++t) yp[m0 + 16 * t] = acc[t][reg];
    }
  }
}

// ---------------------------------------------------------------------------
// gg_tail3: unrolled, atomic-free tail GConvGG.
// ---------------------------------------------------------------------------
template <int NK, int L, int COSUB, int UN>
__global__ __launch_bounds__(256) void gg_tail3_kernel(
    const float* __restrict__ X, const float* __restrict__ W,
    float* __restrict__ Y, int Ci, int Co, int Hin, int NSPLIT, int ciPer,
    int partStride) {
  const int l = threadIdx.x % L;
  const int cs = threadIdx.x / L;
  const int co = blockIdx.x * COSUB + cs;
  const int s = blockIdx.y / NSPLIT;
  const int seg = blockIdx.y % NSPLIT;
  const int b = blockIdx.z;
  const int Hout = Hin - NK + 1;
  const int ciBeg = seg * ciPer;
  const int ciEnd = min(Ci, ciBeg + ciPer);

  float acc[NK];
#pragma unroll
  for (int i = 0; i < NK; ++i) acc[i] = 0.f;

  const float* wbase = W + (size_t)co * Ci * NK * 3;
  const float* xbase = X + ((size_t)b * Ci * Hin + s) * L;

  int ci = ciBeg;
  for (; ci + UN <= ciEnd; ci += UN) {
    float xv[UN][NK][3];
#pragma unroll
    for (int u = 0; u < UN; ++u) {
      const float* xr = xbase + (size_t)(ci + u) * (Hin * L);
#pragma unroll
      for (int i = 0; i < NK; ++i) {
        const int d = 1 << (s + i);
        const float* row = xr + i * L;
        xv[u][i][0] = (l >= d) ? row[l - d] : 0.f;
        xv[u][i][1] = row[l];
        xv[u][i][2] = (l + d < L) ? row[l + d] : 0.f;
      }
    }
#pragma unroll
    for (int u = 0; u < UN; ++u) {
      const float* wp = wbase + (ci + u) * (NK * 3);
#pragma unroll
      for (int i = 0; i < NK; ++i)
        acc[i] = fmaf(wp[3 * i], xv[u][i][0],
                      fmaf(wp[3 * i + 1], xv[u][i][1],
                           fmaf(wp[3 * i + 2], xv[u][i][2], acc[i])));
    }
  }
  for (; ci < ciEnd; ++ci) {
    const float* xr = xbase + (size_t)ci * (Hin * L);
    const float* wp = wbase + ci * (NK * 3);
#pragma unroll
    for (int i = 0; i < NK; ++i) {
      const int d = 1 << (s + i);
      const float* row = xr + i * L;
      float xm = (l >= d) ? row[l - d] : 0.f;
      float xc = row[l];
      float xp = (l + d < L) ? row[l + d] : 0.f;
      acc[i] = fmaf(wp[3 * i], xm,
                    fmaf(wp[3 * i + 1], xc, fmaf(wp[3 * i + 2], xp, acc[i])));
    }
  }
  float out = 0.f;
#pragma unroll
  for (int i = 0; i < NK; ++i) {
    float invd = __uint_as_float((unsigned)(127 - (s + i)) << 23);
    out = fmaf(acc[i], invd, out);
  }
  Y[(size_t)seg * partStride + (((size_t)b * Co + co) * Hout + s) * L + l] =
      out;
}

// ---------------------------------------------------------------------------
// Final: bn10+relu, mean over L, classifier
// ---------------------------------------------------------------------------
__global__ __launch_bounds__(256) void final_kernel(
    const float* __restrict__ Y, const float* __restrict__ st,
    const float* __restrict__ g, const float* __restrict__ bb,
    const float* __restrict__ w11, float* __restrict__ out) {
  const int b = blockIdx.x;
  const int tid = threadIdx.x;
  __shared__ float tch[408];
  for (int c = tid; c < 408; c += 256) {
    float m = st[c] * (1.f / 256.f);
    float v = st[512 + c] * (1.f / 256.f) - m * m;
    float sc = g[c] * rsqrtf(v + EPSBN);
    float bi = bb[c] - m * sc;
    const float* p = Y + ((size_t)b * 408 + c) * 32;
    float ssum = 0.f;
#pragma unroll
    for (int l = 0; l < 32; ++l) ssum += fmaxf(p[l] * sc + bi, 0.f);
    tch[c] = ssum * (1.f / 32.f);
  }
  __syncthreads();
  if (tid < 10) {
    float ssum = 0.f;
    for (int c = 0; c < 408; ++c) ssum += w11[tid * 408 + c] * tch[c];
    out[b * 10 + tid] = ssum;
  }
}

// ---------------------------------------------------------------------------
extern "C" void kernel_launch(void* const* d_in, const int* in_sizes, int n_in,
                              void* d_out, int out_size, void* d_ws,
                              size_t ws_size, hipStream_t stream) {
  const float* x = (const float*)d_in[0];
  const float* w1 = (const float*)d_in[1];
  const float* w2 = (const float*)d_in[2];
  const float* w3 = (const float*)d_in[3];
  const float* w4 = (const float*)d_in[4];
  const float* w5 = (const float*)d_in[5];
  const float* w6 = (const float*)d_in[6];
  const float* w7 = (const float*)d_in[7];
  const float* w8 = (const float*)d_in[8];
  const float* w9 = (const float*)d_in[9];
  const float* w10 = (const float*)d_in[10];
  const float* w11 = (const float*)d_in[11];
  const float* gg[11];
  const float* bbv[11];
  for (int i = 1; i <= 10; ++i) {
    gg[i] = (const float*)d_in[12 + 2 * (i - 1)];
    bbv[i] = (const float*)d_in[12 + 2 * (i - 1) + 1];
  }

  float* ws = (float*)d_ws;
  const size_t AR0 = 0;
  const size_t AR1 = 30081024;
  const size_t STATS = 38900000;
  float* y1 = ws + AR0;
  unsigned* xpad = (unsigned*)(ws + AR1);                 // 456704 dw
  short* apk1 = (short*)(ws + AR1 + 460800);              // 110592 shorts
  unsigned* xpairH = (unsigned*)(ws + AR1 + 520000);      // 4110336 dw
  unsigned* xpairL = (unsigned*)(ws + AR1 + 4630336);     // 4110336 dw
  float* part1 = ws + AR1 + 8740672;                      // 512*128 fp32
  unsigned short* z1b = (unsigned short*)(ws + AR1);
  unsigned short* a3b = (unsigned short*)(ws + AR1);
  unsigned short* z3b = (unsigned short*)(ws + AR1);
  unsigned short* a5b = (unsigned short*)(ws + AR1 + 1500000);
  float* z5 = ws + AR1;
  float* a6 = ws + AR1 + 522240;
  float* a7 = ws + AR1 + 1148928;
  float* z8 = ws + AR1;
  float* a9 = ws + AR1 + 1775616;
  float* part9 = ws + AR1 + 1900000;   // 4 * 104448
  float* part10 = ws + AR1 + 2400000;  // 4 * 104448
  float* y2 = ws + AR0;
  float* y3 = ws + AR0 + 5849088;
  float* y4 = ws + AR0;
  float* y5 = ws + AR0 + 2088960;
  float* y6 = ws + AR0;
  float* y7 = ws + AR0 + 626688;
  float* y8 = ws + AR0 + 1253376;
  float* y9 = ws + AR0;
  float* y10 = ws + AR0 + 104448;
  short* apk2 = (short*)(ws + 12000000);
  short* apk3 = apk2 + 7 * 2 * 64 * 512;
  short* apk4 = apk3 + 7 * 2 * 64 * 192;
  short* apk5 = apk4 + 5 * 2 * 128 * 512;
  float* st[11];
  for (int i = 1; i <= 10; ++i) st[i] = ws + STATS + (size_t)(i - 1) * 1024;

  hipMemsetAsync((void*)(ws + STATS), 0, 10 * 1024 * sizeof(float), stream);
  hipMemsetAsync((void*)part1, 0, 512 * 128 * sizeof(float), stream);

  // ---- pad x (packed split-bf16), per-s pair arrays, pack w1, MFMA lift
  pad_x_kernel<<<(8 * PROW + 255) / 256, 256, 0, stream>>>(x, xpad);
  pad_pair_kernel<<<dim3((PROW + 255) / 256, 72), 256, 0, stream>>>(
      xpad, xpairH, xpairL);
  pack_w1_kernel<<<(9 * 64 * 96 + 255) / 256, 256, 0, stream>>>(w1, apk1);
  lift_mfma_kernel<<<dim3(512, 9, 8), 256, 0, stream>>>(xpairH, xpairL, apk1,
                                                        y1, part1);
  reduce_stats1_kernel<<<8, 128, 0, stream>>>(part1, st[1]);
  {
    unsigned int tot = 8u * 51 * 9 * 2048;
    bnrelu_pool_bf16_kernel<<<(tot + 255) / 256, 256, 0, stream>>>(
        y1, st[1], gg[1], bbv[1], z1b, 51, 9, 8192, 1.f / 589824.f, tot);
  }
  // ---- per-s weight packs
  pack_w2_kernel<<<(7 * 64 * 512 + 255) / 256, 256, 0, stream>>>(
      w2, apk2, 51, 459, 512, 64, 7, 9);
  pack_w2_kernel<<<(7 * 64 * 192 + 255) / 256, 256, 0, stream>>>(
      w3, apk3, 51, 153, 192, 64, 7, 3);
  pack_w2_kernel<<<(5 * 128 * 512 + 255) / 256, 256, 0, stream>>>(
      w4, apk4, 102, 459, 512, 128, 5, 9);
  pack_w2_kernel<<<(5 * 128 * 320 + 255) / 256, 256, 0, stream>>>(
      w5, apk5, 102, 306, 320, 128, 5, 3);
  // ---- gg2: 51->51, H 9->7, L=2048
  gg_mfma5_kernel<3, 64><<<dim3(32, 7, 8), 256, 0, stream>>>(
      z1b, apk2, y2, 51, 51, 9, 2048, 32, 459, 512, 64);
  stats_kernel<<<dim3(51, 8, 4), 256, 0, stream>>>(y2, st[2], 51, 7 * 2048, 4);
  {
    unsigned int tot = 8u * 51 * 7 * 2048;
    bnrelu_bf16_kernel<<<(tot + 255) / 256, 256, 0, stream>>>(
        y2, st[2], gg[2], bbv[2], a3b, 51, 7 * 2048, 1.f / 114688.f, tot);
  }
  // ---- gg3: 51->51, H7, L=2048
  gg_mfma5_kernel<1, 64><<<dim3(32, 7, 8), 256, 0, stream>>>(
      a3b, apk3, y3, 51, 51, 7, 2048, 32, 153, 192, 64);
  stats_kernel<<<dim3(51, 8, 4), 256, 0, stream>>>(y3, st[3], 51, 7 * 2048, 4);
  {
    unsigned int tot = 8u * 51 * 7 * 512;
    bnrelu_pool_bf16_kernel<<<(tot + 255) / 256, 256, 0, stream>>>(
        y3, st[3], gg[3], bbv[3], z3b, 51, 7, 2048, 1.f / 114688.f, tot);
  }
  // ---- gg4: 51->102, H 7->5, L=512
  gg_mfma5_kernel<3, 32><<<dim3(32, 5, 8), 256, 0, stream>>>(
      z3b, apk4, y4, 51, 102, 7, 512, 16, 459, 512, 128);
  stats_kernel<<<dim3(102, 8, 2), 256, 0, stream>>>(y4, st[4], 102, 5 * 512,
                                                    2);
  {
    unsigned int tot = 8u * 102 * 5 * 512;
    bnrelu_bf16_kernel<<<(tot + 255) / 256, 256, 0, stream>>>(
        y4, st[4], gg[4], bbv[4], a5b, 102, 5 * 512, 1.f / 20480.f, tot);
  }
  // ---- gg5: 102->102, H5, L=512
  gg_mfma5_kernel<1, 32><<<dim3(32, 5, 8), 256, 0, stream>>>(
      a5b, apk5, y5, 102, 102, 5, 512, 16, 306, 320, 128);
  stats_kernel<<<dim3(102, 8, 2), 256, 0, stream>>>(y5, st[5], 102, 5 * 512,
                                                    2);
  {
    unsigned int tot = 8u * 102 * 5 * 128;
    bnrelu_pool_kernel<<<(tot + 255) / 256, 256, 0, stream>>>(
        y5, st[5], gg[5], bbv[5], z5, 102, 5, 512, 1.f / 20480.f, tot);
  }
  // ---- gg6: 102->204, H 5->3, L=128 (unrolled, direct store)
  gg_tail3_kernel<3, 128, 2, 2><<<dim3(102, 3, 8), 256, 0, stream>>>(
      z5, w6, y6, 102, 204, 5, 1, 102, 0);
  stats_kernel<<<dim3(204, 8, 1), 256, 0, stream>>>(y6, st[6], 204, 384, 1);
  {
    unsigned int tot = 8u * 204 * 3 * 128;
    bnrelu_kernel<<<(tot + 255) / 256, 256, 0, stream>>>(
        y6, st[6], gg[6], bbv[6], a6, 204, 3 * 128, 1.f / 3072.f, tot);
  }
  // ---- gg7: 204->204, H3, L=128
  gg_tail3_kernel<1, 128, 2, 8><<<dim3(102, 3, 8), 256, 0, stream>>>(
      a6, w7, y7, 204, 204, 3, 1, 204, 0);
  stats_kernel<<<dim3(204, 8, 1), 256, 0, stream>>>(y7, st[7], 204, 384, 1);
  {
    unsigned int tot = 8u * 204 * 3 * 128;
    bnrelu_kernel<<<(tot + 255) / 256, 256, 0, stream>>>(
        y7, st[7], gg[7], bbv[7], a7, 204, 3 * 128, 1.f / 3072.f, tot);
  }
  // ---- gg8: 204->204, H3, L=128
  gg_tail3_kernel<1, 128, 2, 8><<<dim3(102, 3, 8), 256, 0, stream>>>(
      a7, w8, y8, 204, 204, 3, 1, 204, 0);
  stats_kernel<<<dim3(204, 8, 1), 256, 0, stream>>>(y8, st[8], 204, 384, 1);
  {
    unsigned int tot = 8u * 204 * 3 * 32;
    bnrelu_pool_kernel<<<(tot + 255) / 256, 256, 0, stream>>>(
        y8, st[8], gg[8], bbv[8], z8, 204, 3, 128, 1.f / 3072.f, tot);
  }
  // ---- gg9: 204->408, H 3->1, L=32 (K-split x4 into partials, reduce)
  gg_tail3_kernel<3, 32, 8, 2><<<dim3(51, 4, 8), 256, 0, stream>>>(
      z8, w9, part9, 204, 408, 3, 4, 51, 104448);
  reduce_parts_kernel<<<(104448 + 255) / 256, 256, 0, stream>>>(
      part9, y9, 104448, 104448, 4);
  stats_kernel<<<dim3(408, 8, 1), 256, 0, stream>>>(y9, st[9], 408, 32, 1);
  {
    unsigned int tot = 8u * 408 * 32;
    bnrelu_kernel<<<(tot + 255) / 256, 256, 0, stream>>>(
        y9, st[9], gg[9], bbv[9], a9, 408, 32, 1.f / 256.f, tot);
  }
  // ---- gg10: 408->408, H1, L=32 (K-split x4 into partials, reduce)
  gg_tail3_kernel<1, 32, 8, 8><<<dim3(51, 4, 8), 256, 0, stream>>>(
      a9, w10, part10, 408, 408, 1, 4, 102, 104448);
  reduce_parts_kernel<<<(104448 + 255) / 256, 256, 0, stream>>>(
      part10, y10, 104448, 104448, 4);
  stats_kernel<<<dim3(408, 8, 1), 256, 0, stream>>>(y10, st[10], 408, 32, 1);
  // ---- final
  final_kernel<<<dim3(8), 256, 0, stream>>>(y10, st[10], gg[10], bbv[10], w11,
                                            (float*)d_out);
}

// Round 4
// 1014.492 us; speedup vs baseline: 1.1013x; 1.1013x over previous
//
#include <hip/hip_runtime.h>
#include <hip/hip_bf16.h>

#define EPSBN 2e-5f

typedef __attribute__((ext_vector_type(8))) short short8v;
typedef __attribute__((ext_vector_type(4))) float f32x4;

__device__ inline unsigned short f2bf(float f) {
  unsigned u = __float_as_uint(f);
  unsigned r = (u + 0x7FFFu + ((u >> 16) & 1u)) >> 16;
  return (unsigned short)r;
}
__device__ inline float bf2f(unsigned short h) {
  return __uint_as_float(((unsigned)h) << 16);
}

// ---------------------------------------------------------------------------
// Padded x staging — packed split-bf16: (hi16 << 16) | lo16.
// ---------------------------------------------------------------------------
constexpr int XPADL = 9984;
constexpr int XPADR = 14336;
constexpr int PROW = XPADL + 32768 + XPADR;  // 57088

__global__ __launch_bounds__(256) void pad_x_kernel(const float* __restrict__ x,
                                                    unsigned* __restrict__ xp) {
  int i = blockIdx.x * 256 + threadIdx.x;
  if (i >= 8 * PROW) return;
  int b = i / PROW;
  int pos = i - b * PROW - XPADL;
  float v = (pos >= 0 && pos < 32768) ? x[b * 32768 + pos] : 0.f;
  unsigned u = __float_as_uint(v);
  unsigned h = u >> 16;
  float lof = v - __uint_as_float(u & 0xffff0000u);
  unsigned lo = __float_as_uint(lof) >> 16;
  xp[i] = (h << 16) | lo;
}

// ---------------------------------------------------------------------------
// Per-scale pair-packed B source: for scale s (dilation d=2^s),
//   xpH[(s*8+b)*PROW + i] = hi(x[i]) | hi(x[i+d])<<16
//   xpL[...]              = lo(x[i]) | lo(x[i+d])<<16
// ---------------------------------------------------------------------------
__global__ __launch_bounds__(256) void pad_pair_kernel(
    const unsigned* __restrict__ xp, unsigned* __restrict__ xpH,
    unsigned* __restrict__ xpL) {
  const int i = blockIdx.x * 256 + threadIdx.x;
  if (i >= PROW) return;
  const int sb = blockIdx.y;  // s*8 + b
  const int s = sb >> 3;
  const int b = sb & 7;
  const int d = 1 << s;
  const unsigned* row = xp + b * PROW;
  unsigned u0 = row[i];
  unsigned u1 = (i + d < PROW) ? row[i + d] : 0u;
  size_t o = (size_t)sb * PROW + i;
  xpH[o] = (u0 >> 16) | (u1 & 0xffff0000u);
  xpL[o] = (u0 & 0xffffu) | (u1 << 16);
}

// ---------------------------------------------------------------------------
// Pack w1 [51][79] -> per-s split bf16 (1/2^s folded), [s][hi/lo][64][96]
// ---------------------------------------------------------------------------
__global__ __launch_bounds__(256) void pack_w1_kernel(
    const float* __restrict__ W, short* __restrict__ A) {
  int idx = blockIdx.x * 256 + threadIdx.x;
  if (idx >= 9 * 64 * 96) return;
  int s = idx / (64 * 96);
  int rem = idx - s * 64 * 96;
  int co = rem / 96;
  int k = rem - co * 96;
  float v = 0.f;
  if (co < 51 && k < 79)
    v = W[co * 79 + k] * __uint_as_float((unsigned)(127 - s) << 23);
  unsigned short hi = f2bf(v);
  unsigned short lo = f2bf(v - bf2f(hi));
  A[(size_t)s * 2 * 64 * 96 + co * 96 + k] = (short)hi;
  A[(size_t)s * 2 * 64 * 96 + 64 * 96 + co * 96 + k] = (short)lo;
}

// ---------------------------------------------------------------------------
// lift_mfma: lift conv K=79 as bf16 MFMA GEMM + fused pool4 + fused stats.
// Loads stay fully coalesced (lane nB -> offset nB, same as the 177 µs R2
// version). The pool-friendly column permutation is applied at the LDS
// WRITE row: rho(nB) = ((nB&3)<<4)|(nB>>2), so the unchanged MFMA B-read
// (col n0+16t, known-good bank pattern) retrieves position 4*n0+t. The 4
// pool members of each output land in ONE lane across t: pool4 is 3
// in-register fmax and stores are 4 full-wave coalesced dwords/wave.
// XCD-chunked lc swizzle keeps dilated halos of neighbor blocks in one L2.
// ---------------------------------------------------------------------------
__global__ __launch_bounds__(256) void lift_mfma_kernel(
    const unsigned* __restrict__ xpH, const unsigned* __restrict__ xpL,
    const short* __restrict__ Apk1, float* __restrict__ y1,
    float* __restrict__ part1) {
  constexpr int P = 104;
  const int bid = blockIdx.x;
  const int lc = (bid & 7) * 64 + (bid >> 3);  // 512 = 8*64, bijective
  const int s = blockIdx.y;
  const int b = blockIdx.z;
  const int d = 1 << s;
  const int l0 = lc * 64;
  const int tid = threadIdx.x;
  const int lane = tid & 63;
  const int quad = lane >> 4;
  const int n0 = lane & 15;
  const int wv = tid >> 6;
  const int coBase = wv * 16;

  __shared__ __align__(16) short Bh[64 * P];
  __shared__ __align__(16) short Bl[64 * P];
  __shared__ float sCh[2][64];

  const int nB = tid & 63;
  const int rowW = ((nB & 3) << 4) | (nB >> 2);  // LDS row permutation
  const int ogu = __builtin_amdgcn_readfirstlane(tid >> 6);
  const unsigned* xqH = xpH + (size_t)(s * 8 + b) * PROW + XPADL + l0;
  const unsigned* xqL = xpL + (size_t)(s * 8 + b) * PROW + XPADL + l0;

#pragma unroll
  for (int r = 0; r < 3; ++r) {
    const int kb = (ogu + 4 * r) * 8;
    const int base = (kb - 39) * d;
    uint4 ph, pl;
    ph.x = xqH[base + nB];
    ph.y = xqH[base + 2 * d + nB];
    ph.z = xqH[base + 4 * d + nB];
    ph.w = xqH[base + 6 * d + nB];
    pl.x = xqL[base + nB];
    pl.y = xqL[base + 2 * d + nB];
    pl.z = xqL[base + 4 * d + nB];
    pl.w = xqL[base + 6 * d + nB];
    *(uint4*)(Bh + rowW * P + kb) = ph;
    *(uint4*)(Bl + rowW * P + kb) = pl;
  }

  const short* ApkS = Apk1 + (size_t)s * 2 * 64 * 96;
  const short* arowH = ApkS + (coBase + n0) * 96;
  const short* arowL = arowH + 64 * 96;

  __syncthreads();

  f32x4 acc[4];
#pragma unroll
  for (int t = 0; t < 4; ++t) acc[t] = (f32x4){0.f, 0.f, 0.f, 0.f};

#pragma unroll
  for (int ks = 0; ks < 3; ++ks) {
    short8v ah = *(const short8v*)(arowH + ks * 32 + quad * 8);
    short8v al = *(const short8v*)(arowL + ks * 32 + quad * 8);
#pragma unroll
    for (int t = 0; t < 4; ++t) {
      const int n = n0 + 16 * t;  // row rho(4*n0+t): holds position 4*n0+t
      short8v bh = *(const short8v*)(Bh + n * P + ks * 32 + quad * 8);
      short8v bl = *(const short8v*)(Bl + n * P + ks * 32 + quad * 8);
      acc[t] = __builtin_amdgcn_mfma_f32_16x16x32_bf16(ah, bh, acc[t], 0, 0, 0);
      acc[t] = __builtin_amdgcn_mfma_f32_16x16x32_bf16(ah, bl, acc[t], 0, 0, 0);
      acc[t] = __builtin_amdgcn_mfma_f32_16x16x32_bf16(al, bh, acc[t], 0, 0, 0);
    }
  }

  // Epilogue: pool4 over t in-register; lane n0 <-> pooled position l1.
#pragma unroll
  for (int reg = 0; reg < 4; ++reg) {
    const int co = coBase + quad * 4 + reg;
    float po = fmaxf(fmaxf(acc[0][reg], acc[1][reg]),
                     fmaxf(acc[2][reg], acc[3][reg]));
    const bool valid = (co < 51);
    if (valid) {
      y1[(((size_t)b * 51 + co) * 9 + s) * 8192 + (l0 >> 2) + n0] = po;
    }
    float us = valid ? po : 0.f;
    float sq = us * us;
    us += __shfl_xor(us, 1);
    sq += __shfl_xor(sq, 1);
    us += __shfl_xor(us, 2);
    sq += __shfl_xor(sq, 2);
    us += __shfl_xor(us, 4);
    sq += __shfl_xor(sq, 4);
    us += __shfl_xor(us, 8);
    sq += __shfl_xor(sq, 8);
    if (n0 == 0) {
      sCh[0][co] = us;
      sCh[1][co] = sq;
    }
  }
  __syncthreads();
  if (tid < 51) {
    float* pp = part1 + (size_t)lc * 128;
    atomicAdd(&pp[tid], sCh[0][tid]);
    atomicAdd(&pp[64 + tid], sCh[1][tid]);
  }
}

// ---------------------------------------------------------------------------
// Reduce the 512 lc-sliced stats partials (stride 128: [0..50]=sum,
// [64..114]=sumsq) into st[c], st[512+c]. 8 blocks k-split, atomic merge.
// ---------------------------------------------------------------------------
__global__ __launch_bounds__(128) void reduce_stats1_kernel(
    const float* __restrict__ p, float* __restrict__ st) {
  const int t = threadIdx.x;
  if (t >= 102) return;
  const int k0 = blockIdx.x * 64;
  const int off = (t < 51) ? t : (64 + t - 51);
  float s = 0.f;
  for (int k = k0; k < k0 + 64; ++k) s += p[k * 128 + off];
  atomicAdd(&st[(t < 51) ? t : (512 + t - 51)], s);
}

// ---------------------------------------------------------------------------
// Per-channel sum/sumsq over [B,C,HL], HL split NS ways; grid (C,B,NS)
// ---------------------------------------------------------------------------
__global__ __launch_bounds__(256) void stats_kernel(
    const float* __restrict__ Y, float* __restrict__ st, int C, int HL,
    int NS) {
  const int c = blockIdx.x, b = blockIdx.y, z = blockIdx.z;
  const int slice = HL / NS;
  const float* p = Y + ((size_t)b * C + c) * HL + (size_t)z * slice;
  float s = 0.f, q = 0.f;
  for (int i = threadIdx.x; i < slice; i += 256) {
    float v = p[i];
    s += v;
    q += v * v;
  }
#pragma unroll
  for (int off = 32; off > 0; off >>= 1) {
    s += __shfl_down(s, off, 64);
    q += __shfl_down(q, off, 64);
  }
  __shared__ float ls[4], lq[4];
  const int wid = threadIdx.x >> 6, lane = threadIdx.x & 63;
  if (lane == 0) { ls[wid] = s; lq[wid] = q; }
  __syncthreads();
  if (threadIdx.x == 0) {
    atomicAdd(&st[c], ls[0] + ls[1] + ls[2] + ls[3]);
    atomicAdd(&st[512 + c], lq[0] + lq[1] + lq[2] + lq[3]);
  }
}

// ---------------------------------------------------------------------------
// reduce NS partial buffers: y[i] = sum_k p[k*stride + i]
// ---------------------------------------------------------------------------
__global__ __launch_bounds__(256) void reduce_parts_kernel(
    const float* __restrict__ p, float* __restrict__ y, int n, int stride,
    int ns) {
  int i = blockIdx.x * 256 + threadIdx.x;
  if (i >= n) return;
  float s = 0.f;
  for (int k = 0; k < ns; ++k) s += p[(size_t)k * stride + i];
  y[i] = s;
}

// ---------------------------------------------------------------------------
// BN(train)+ReLU+pool4, fp32 out
// ---------------------------------------------------------------------------
__global__ __launch_bounds__(256) void bnrelu_pool_kernel(
    const float* __restrict__ Y, const float* __restrict__ st,
    const float* __restrict__ g, const float* __restrict__ bb,
    float* __restrict__ Z, int C, int H, int Lin, float invN,
    unsigned int total) {
  unsigned int idx = blockIdx.x * 256u + threadIdx.x;
  if (idx >= total) return;
  const unsigned int Lo = (unsigned int)(Lin >> 2);
  unsigned int lo = idx % Lo;
  unsigned int r1 = idx / Lo;
  unsigned int h = r1 % (unsigned int)H;
  unsigned int r2 = r1 / (unsigned int)H;
  unsigned int c = r2 % (unsigned int)C;
  unsigned int b = r2 / (unsigned int)C;
  float m = st[c] * invN;
  float v = st[512 + c] * invN - m * m;
  float sc = g[c] * rsqrtf(v + EPSBN);
  float bi = bb[c] - m * sc;
  const float* p = Y + (((size_t)b * C + c) * H + h) * Lin + 4u * lo;
  float a0 = p[0] * sc + bi, a1 = p[1] * sc + bi;
  float a2 = p[2] * sc + bi, a3 = p[3] * sc + bi;
  float r = fmaxf(fmaxf(a0, a1), fmaxf(a2, a3));
  Z[idx] = fmaxf(r, 0.f);
}

// ---- same, bf16 out
__global__ __launch_bounds__(256) void bnrelu_pool_bf16_kernel(
    const float* __restrict__ Y, const float* __restrict__ st,
    const float* __restrict__ g, const float* __restrict__ bb,
    unsigned short* __restrict__ Z, int C, int H, int Lin, float invN,
    unsigned int total) {
  unsigned int idx = blockIdx.x * 256u + threadIdx.x;
  if (idx >= total) return;
  const unsigned int Lo = (unsigned int)(Lin >> 2);
  unsigned int lo = idx % Lo;
  unsigned int r1 = idx / Lo;
  unsigned int h = r1 % (unsigned int)H;
  unsigned int r2 = r1 / (unsigned int)H;
  unsigned int c = r2 % (unsigned int)C;
  unsigned int b = r2 / (unsigned int)C;
  float m = st[c] * invN;
  float v = st[512 + c] * invN - m * m;
  float sc = g[c] * rsqrtf(v + EPSBN);
  float bi = bb[c] - m * sc;
  const float* p = Y + (((size_t)b * C + c) * H + h) * Lin + 4u * lo;
  float a0 = p[0] * sc + bi, a1 = p[1] * sc + bi;
  float a2 = p[2] * sc + bi, a3 = p[3] * sc + bi;
  float r = fmaxf(fmaxf(a0, a1), fmaxf(a2, a3));
  Z[idx] = f2bf(fmaxf(r, 0.f));
}

// ---------------------------------------------------------------------------
// BN(train)+ReLU elementwise, fp32 / bf16 out
// ---------------------------------------------------------------------------
__global__ __launch_bounds__(256) void bnrelu_kernel(
    const float* __restrict__ Y, const float* __restrict__ st,
    const float* __restrict__ g, const float* __restrict__ bb,
    float* __restrict__ A, int C, int HL, float invN, unsigned int total) {
  unsigned int idx = blockIdx.x * 256u + threadIdx.x;
  if (idx >= total) return;
  unsigned int c = (idx / (unsigned int)HL) % (unsigned int)C;
  float m = st[c] * invN;
  float v = st[512 + c] * invN - m * m;
  float sc = g[c] * rsqrtf(v + EPSBN);
  float bi = bb[c] - m * sc;
  A[idx] = fmaxf(fmaf(Y[idx], sc, bi), 0.f);
}

__global__ __launch_bounds__(256) void bnrelu_bf16_kernel(
    const float* __restrict__ Y, const float* __restrict__ st,
    const float* __restrict__ g, const float* __restrict__ bb,
    unsigned short* __restrict__ A, int C, int HL, float invN,
    unsigned int total) {
  unsigned int idx = blockIdx.x * 256u + threadIdx.x;
  if (idx >= total) return;
  unsigned int c = (idx / (unsigned int)HL) % (unsigned int)C;
  float m = st[c] * invN;
  float v = st[512 + c] * invN - m * m;
  float sc = g[c] * rsqrtf(v + EPSBN);
  float bi = bb[c] - m * sc;
  A[idx] = f2bf(fmaxf(fmaf(Y[idx], sc, bi), 0.f));
}

// ---------------------------------------------------------------------------
// Pack fp32 weights -> per-s split bf16 packs with 2^-(s+i) folded.
// ---------------------------------------------------------------------------
__global__ __launch_bounds__(256) void pack_w2_kernel(
    const float* __restrict__ W, short* __restrict__ A, int Co, int KTOT,
    int KPAD, int COPAD, int NS, int nk3) {
  int idx = blockIdx.x * 256 + threadIdx.x;
  const int CK = COPAD * KPAD;
  if (idx >= NS * CK) return;
  int s = idx / CK;
  int rem = idx - s * CK;
  int co = rem / KPAD;
  int kk = rem - co * KPAD;
  float v = 0.f;
  if (co < Co && kk < KTOT) {
    int i = (kk % nk3) / 3;
    float scale = __uint_as_float((unsigned)(127 - (s + i)) << 23);
    v = W[co * KTOT + kk] * scale;
  }
  unsigned short hi = f2bf(v);
  unsigned short lo = f2bf(v - bf2f(hi));
  A[(size_t)s * 2 * CK + co * KPAD + kk] = (short)hi;
  A[(size_t)s * 2 * CK + CK + co * KPAD + kk] = (short)lo;
}

// ---------------------------------------------------------------------------
// gg_mfma5: bf16-input MFMA GConvGG, no fused stats (R15, unchanged)
// ---------------------------------------------------------------------------
template <int NKv, int LT>
__global__ __launch_bounds__(256) void gg_mfma5_kernel(
    const unsigned short* __restrict__ X, const short* __restrict__ Apk,
    float* __restrict__ Y, int Ci, int Co, int Hin, int L, int nL, int KTOT,
    int KPAD, int COPAD) {
  constexpr int T = LT / 16;
  constexpr int KO = 256 / LT;
  constexpr int RIT = 8 / KO;

  const int bx = blockIdx.x;
  const int lc = bx % nL;
  const int cog = bx / nL;
  const int s = blockIdx.y;
  const int b = blockIdx.z;
  const int Hout = Hin - NKv + 1;
  const int l0 = lc * LT;
  const int tid = threadIdx.x;
  const int lane = tid & 63;
  const int quad = lane >> 4;
  const int m0 = lane & 15;
  const int wv = tid >> 6;
  const int coBase = cog * 64 + wv * 16;

  __shared__ __align__(16) short Bh[LT * 72];
  __shared__ int roT[512];
  __shared__ int shT[512];

  for (int kk = tid; kk < KPAD; kk += 256) {
    int ro = 0, sh = -(1 << 30);
    if (kk < KTOT) {
      int ci = kk / (3 * NKv);
      int rem = kk - ci * (3 * NKv);
      int i = rem / 3;
      int k = rem - 3 * i;
      ro = (ci * Hin + s + i) * L;
      sh = (k - 1) * (1 << (s + i));
    }
    roT[kk] = ro;
    shT[kk] = sh;
  }
  __syncthreads();

  f32x4 acc[T];
#pragma unroll
  for (int t = 0; t < T; ++t) acc[t] = (f32x4){0.f, 0.f, 0.f, 0.f};

  const short* ApkS = Apk + (size_t)s * 2 * COPAD * KPAD;
  const short* arowH = ApkS + (size_t)(coBase + m0) * KPAD;
  const short* arowL = arowH + (size_t)COPAD * KPAD;
  const unsigned short* Xb = X + (size_t)b * Ci * Hin * L;

  const int lB = tid & (LT - 1);
  const int oc0 = tid / LT;
  const int nch = (KTOT + 63) >> 6;

  uint4 v0[RIT], v1[RIT], v2[RIT];
  auto gather = [&](int c0, uint4 (&pk)[RIT]) {
#pragma unroll
    for (int r = 0; r < RIT; ++r) {
      const int oct = oc0 + KO * r;
      const int kkb = (c0 << 6) + oct * 8;
      unsigned w[8];
#pragma unroll
      for (int j = 0; j < 8; ++j) {
        const int kk = kkb + j;
        const int pos = l0 + lB + shT[kk];
        const int posc = min(max(pos, 0), L - 1);
        unsigned u = (unsigned)Xb[roT[kk] + posc];
        w[j] = ((unsigned)pos < (unsigned)L) ? u : 0u;
      }
      pk[r].x = w[0] | (w[1] << 16);
      pk[r].y = w[2] | (w[3] << 16);
      pk[r].z = w[4] | (w[5] << 16);
      pk[r].w = w[6] | (w[7] << 16);
    }
  };

  gather(0, v0);
  if (nch > 1) gather(1, v1);
  for (int c0 = 0; c0 < nch; ++c0) {
#pragma unroll
    for (int r = 0; r < RIT; ++r)
      *(uint4*)(Bh + lB * 72 + (oc0 + KO * r) * 8) = v0[r];
    if (c0 + 2 < nch) gather(c0 + 2, v2);
    const int a0 = (c0 << 6) + quad * 8;
    short8v ah0 = *(const short8v*)(arowH + a0);
    short8v al0 = *(const short8v*)(arowL + a0);
    short8v ah1 = *(const short8v*)(arowH + a0 + 32);
    short8v al1 = *(const short8v*)(arowL + a0 + 32);
    __syncthreads();
#pragma unroll
    for (int t = 0; t < T; ++t) {
      const int l = m0 + 16 * t;
      short8v b0 = *(const short8v*)(Bh + l * 72 + quad * 8);
      short8v b1 = *(const short8v*)(Bh + l * 72 + 32 + quad * 8);
      acc[t] = __builtin_amdgcn_mfma_f32_16x16x32_bf16(ah0, b0, acc[t], 0, 0, 0);
      acc[t] = __builtin_amdgcn_mfma_f32_16x16x32_bf16(al0, b0, acc[t], 0, 0, 0);
      acc[t] = __builtin_amdgcn_mfma_f32_16x16x32_bf16(ah1, b1, acc[t], 0, 0, 0);
      acc[t] = __builtin_amdgcn_mfma_f32_16x16x32_bf16(al1, b1, acc[t], 0, 0, 0);
    }
    __syncthreads();
#pragma unroll
    for (int r = 0; r < RIT; ++r) {
      v0[r] = v1[r];
      v1[r] = v2[r];
    }
  }

#pragma unroll
  for (int reg = 0; reg < 4; ++reg) {
    const int co = coBase + quad * 4 + reg;
    if (co < Co) {
      float* yp = Y + (((size_t)b * Co + co) * Hout + s) * L + l0;
#pragma unroll
      for (int t = 0; t < T; ++t) yp[m0 + 16 * t] = acc[t][reg];
    }
  }
}

// ---------------------------------------------------------------------------
// gg_tail3: unrolled, atomic-free tail GConvGG.
// ---------------------------------------------------------------------------
template <int NK, int L, int COSUB, int UN>
__global__ __launch_bounds__(256) void gg_tail3_kernel(
    const float* __restrict__ X, const float* __restrict__ W,
    float* __restrict__ Y, int Ci, int Co, int Hin, int NSPLIT, int ciPer,
    int partStride) {
  const int l = threadIdx.x % L;
  const int cs = threadIdx.x / L;
  const int co = blockIdx.x * COSUB + cs;
  const int s = blockIdx.y / NSPLIT;
  const int seg = blockIdx.y % NSPLIT;
  const int b = blockIdx.z;
  const int Hout = Hin - NK + 1;
  const int ciBeg = seg * ciPer;
  const int ciEnd = min(Ci, ciBeg + ciPer);

  float acc[NK];
#pragma unroll
  for (int i = 0; i < NK; ++i) acc[i] = 0.f;

  const float* wbase = W + (size_t)co * Ci * NK * 3;
  const float* xbase = X + ((size_t)b * Ci * Hin + s) * L;

  int ci = ciBeg;
  for (; ci + UN <= ciEnd; ci += UN) {
    float xv[UN][NK][3];
#pragma unroll
    for (int u = 0; u < UN; ++u) {
      const float* xr = xbase + (size_t)(ci + u) * (Hin * L);
#pragma unroll
      for (int i = 0; i < NK; ++i) {
        const int d = 1 << (s + i);
        const float* row = xr + i * L;
        xv[u][i][0] = (l >= d) ? row[l - d] : 0.f;
        xv[u][i][1] = row[l];
        xv[u][i][2] = (l + d < L) ? row[l + d] : 0.f;
      }
    }
#pragma unroll
    for (int u = 0; u < UN; ++u) {
      const float* wp = wbase + (ci + u) * (NK * 3);
#pragma unroll
      for (int i = 0; i < NK; ++i)
        acc[i] = fmaf(wp[3 * i], xv[u][i][0],
                      fmaf(wp[3 * i + 1], xv[u][i][1],
                           fmaf(wp[3 * i + 2], xv[u][i][2], acc[i])));
    }
  }
  for (; ci < ciEnd; ++ci) {
    const float* xr = xbase + (size_t)ci * (Hin * L);
    const float* wp = wbase + ci * (NK * 3);
#pragma unroll
    for (int i = 0; i < NK; ++i) {
      const int d = 1 << (s + i);
      const float* row = xr + i * L;
      float xm = (l >= d) ? row[l - d] : 0.f;
      float xc = row[l];
      float xp = (l + d < L) ? row[l + d] : 0.f;
      acc[i] = fmaf(wp[3 * i], xm,
                    fmaf(wp[3 * i + 1], xc, fmaf(wp[3 * i + 2], xp, acc[i])));
    }
  }
  float out = 0.f;
#pragma unroll
  for (int i = 0; i < NK; ++i) {
    float invd = __uint_as_float((unsigned)(127 - (s + i)) << 23);
    out = fmaf(acc[i], invd, out);
  }
  Y[(size_t)seg * partStride + (((size_t)b * Co + co) * Hout + s) * L + l] =
      out;
}

// ---------------------------------------------------------------------------
// Final: bn10+relu, mean over L, classifier
// ---------------------------------------------------------------------------
__global__ __launch_bounds__(256) void final_kernel(
    const float* __restrict__ Y, const float* __restrict__ st,
    const float* __restrict__ g, const float* __restrict__ bb,
    const float* __restrict__ w11, float* __restrict__ out) {
  const int b = blockIdx.x;
  const int tid = threadIdx.x;
  __shared__ float tch[408];
  for (int c = tid; c < 408; c += 256) {
    float m = st[c] * (1.f / 256.f);
    float v = st[512 + c] * (1.f / 256.f) - m * m;
    float sc = g[c] * rsqrtf(v + EPSBN);
    float bi = bb[c] - m * sc;
    const float* p = Y + ((size_t)b * 408 + c) * 32;
    float ssum = 0.f;
#pragma unroll
    for (int l = 0; l < 32; ++l) ssum += fmaxf(p[l] * sc + bi, 0.f);
    tch[c] = ssum * (1.f / 32.f);
  }
  __syncthreads();
  if (tid < 10) {
    float ssum = 0.f;
    for (int c = 0; c < 408; ++c) ssum += w11[tid * 408 + c] * tch[c];
    out[b * 10 + tid] = ssum;
  }
}

// ---------------------------------------------------------------------------
extern "C" void kernel_launch(void* const* d_in, const int* in_sizes, int n_in,
                              void* d_out, int out_size, void* d_ws,
                              size_t ws_size, hipStream_t stream) {
  const float* x = (const float*)d_in[0];
  const float* w1 = (const float*)d_in[1];
  const float* w2 = (const float*)d_in[2];
  const float* w3 = (const float*)d_in[3];
  const float* w4 = (const float*)d_in[4];
  const float* w5 = (const float*)d_in[5];
  const float* w6 = (const float*)d_in[6];
  const float* w7 = (const float*)d_in[7];
  const float* w8 = (const float*)d_in[8];
  const float* w9 = (const float*)d_in[9];
  const float* w10 = (const float*)d_in[10];
  const float* w11 = (const float*)d_in[11];
  const float* gg[11];
  const float* bbv[11];
  for (int i = 1; i <= 10; ++i) {
    gg[i] = (const float*)d_in[12 + 2 * (i - 1)];
    bbv[i] = (const float*)d_in[12 + 2 * (i - 1) + 1];
  }

  float* ws = (float*)d_ws;
  const size_t AR0 = 0;
  const size_t AR1 = 30081024;
  const size_t STATS = 38900000;
  float* y1 = ws + AR0;
  unsigned* xpad = (unsigned*)(ws + AR1);                 // 456704 dw
  short* apk1 = (short*)(ws + AR1 + 460800);              // 110592 shorts
  unsigned* xpairH = (unsigned*)(ws + AR1 + 520000);      // 4110336 dw
  unsigned* xpairL = (unsigned*)(ws + AR1 + 4630336);     // 4110336 dw
  float* part1 = ws + AR1 + 8740672;                      // 512*128 fp32
  unsigned short* z1b = (unsigned short*)(ws + AR1);
  unsigned short* a3b = (unsigned short*)(ws + AR1);
  unsigned short* z3b = (unsigned short*)(ws + AR1);
  unsigned short* a5b = (unsigned short*)(ws + AR1 + 1500000);
  float* z5 = ws + AR1;
  float* a6 = ws + AR1 + 522240;
  float* a7 = ws + AR1 + 1148928;
  float* z8 = ws + AR1;
  float* a9 = ws + AR1 + 1775616;
  float* part9 = ws + AR1 + 1900000;   // 4 * 104448
  float* part10 = ws + AR1 + 2400000;  // 4 * 104448
  float* y2 = ws + AR0;
  float* y3 = ws + AR0 + 5849088;
  float* y4 = ws + AR0;
  float* y5 = ws + AR0 + 2088960;
  float* y6 = ws + AR0;
  float* y7 = ws + AR0 + 626688;
  float* y8 = ws + AR0 + 1253376;
  float* y9 = ws + AR0;
  float* y10 = ws + AR0 + 104448;
  short* apk2 = (short*)(ws + 12000000);
  short* apk3 = apk2 + 7 * 2 * 64 * 512;
  short* apk4 = apk3 + 7 * 2 * 64 * 192;
  short* apk5 = apk4 + 5 * 2 * 128 * 512;
  float* st[11];
  for (int i = 1; i <= 10; ++i) st[i] = ws + STATS + (size_t)(i - 1) * 1024;

  hipMemsetAsync((void*)(ws + STATS), 0, 10 * 1024 * sizeof(float), stream);
  hipMemsetAsync((void*)part1, 0, 512 * 128 * sizeof(float), stream);

  // ---- pad x (packed split-bf16), per-s pair arrays, pack w1, MFMA lift
  pad_x_kernel<<<(8 * PROW + 255) / 256, 256, 0, stream>>>(x, xpad);
  pad_pair_kernel<<<dim3((PROW + 255) / 256, 72), 256, 0, stream>>>(
      xpad, xpairH, xpairL);
  pack_w1_kernel<<<(9 * 64 * 96 + 255) / 256, 256, 0, stream>>>(w1, apk1);
  lift_mfma_kernel<<<dim3(512, 9, 8), 256, 0, stream>>>(xpairH, xpairL, apk1,
                                                        y1, part1);
  reduce_stats1_kernel<<<8, 128, 0, stream>>>(part1, st[1]);
  {
    unsigned int tot = 8u * 51 * 9 * 2048;
    bnrelu_pool_bf16_kernel<<<(tot + 255) / 256, 256, 0, stream>>>(
        y1, st[1], gg[1], bbv[1], z1b, 51, 9, 8192, 1.f / 589824.f, tot);
  }
  // ---- per-s weight packs
  pack_w2_kernel<<<(7 * 64 * 512 + 255) / 256, 256, 0, stream>>>(
      w2, apk2, 51, 459, 512, 64, 7, 9);
  pack_w2_kernel<<<(7 * 64 * 192 + 255) / 256, 256, 0, stream>>>(
      w3, apk3, 51, 153, 192, 64, 7, 3);
  pack_w2_kernel<<<(5 * 128 * 512 + 255) / 256, 256, 0, stream>>>(
      w4, apk4, 102, 459, 512, 128, 5, 9);
  pack_w2_kernel<<<(5 * 128 * 320 + 255) / 256, 256, 0, stream>>>(
      w5, apk5, 102, 306, 320, 128, 5, 3);
  // ---- gg2: 51->51, H 9->7, L=2048
  gg_mfma5_kernel<3, 64><<<dim3(32, 7, 8), 256, 0, stream>>>(
      z1b, apk2, y2, 51, 51, 9, 2048, 32, 459, 512, 64);
  stats_kernel<<<dim3(51, 8, 4), 256, 0, stream>>>(y2, st[2], 51, 7 * 2048, 4);
  {
    unsigned int tot = 8u * 51 * 7 * 2048;
    bnrelu_bf16_kernel<<<(tot + 255) / 256, 256, 0, stream>>>(
        y2, st[2], gg[2], bbv[2], a3b, 51, 7 * 2048, 1.f / 114688.f, tot);
  }
  // ---- gg3: 51->51, H7, L=2048
  gg_mfma5_kernel<1, 64><<<dim3(32, 7, 8), 256, 0, stream>>>(
      a3b, apk3, y3, 51, 51, 7, 2048, 32, 153, 192, 64);
  stats_kernel<<<dim3(51, 8, 4), 256, 0, stream>>>(y3, st[3], 51, 7 * 2048, 4);
  {
    unsigned int tot = 8u * 51 * 7 * 512;
    bnrelu_pool_bf16_kernel<<<(tot + 255) / 256, 256, 0, stream>>>(
        y3, st[3], gg[3], bbv[3], z3b, 51, 7, 2048, 1.f / 114688.f, tot);
  }
  // ---- gg4: 51->102, H 7->5, L=512
  gg_mfma5_kernel<3, 32><<<dim3(32, 5, 8), 256, 0, stream>>>(
      z3b, apk4, y4, 51, 102, 7, 512, 16, 459, 512, 128);
  stats_kernel<<<dim3(102, 8, 2), 256, 0, stream>>>(y4, st[4], 102, 5 * 512,
                                                    2);
  {
    unsigned int tot = 8u * 102 * 5 * 512;
    bnrelu_bf16_kernel<<<(tot + 255) / 256, 256, 0, stream>>>(
        y4, st[4], gg[4], bbv[4], a5b, 102, 5 * 512, 1.f / 20480.f, tot);
  }
  // ---- gg5: 102->102, H5, L=512
  gg_mfma5_kernel<1, 32><<<dim3(32, 5, 8), 256, 0, stream>>>(
      a5b, apk5, y5, 102, 102, 5, 512, 16, 306, 320, 128);
  stats_kernel<<<dim3(102, 8, 2), 256, 0, stream>>>(y5, st[5], 102, 5 * 512,
                                                    2);
  {
    unsigned int tot = 8u * 102 * 5 * 128;
    bnrelu_pool_kernel<<<(tot + 255) / 256, 256, 0, stream>>>(
        y5, st[5], gg[5], bbv[5], z5, 102, 5, 512, 1.f / 20480.f, tot);
  }
  // ---- gg6: 102->204, H 5->3, L=128 (unrolled, direct store)
  gg_tail3_kernel<3, 128, 2, 2><<<dim3(102, 3, 8), 256, 0, stream>>>(
      z5, w6, y6, 102, 204, 5, 1, 102, 0);
  stats_kernel<<<dim3(204, 8, 1), 256, 0, stream>>>(y6, st[6], 204, 384, 1);
  {
    unsigned int tot = 8u * 204 * 3 * 128;
    bnrelu_kernel<<<(tot + 255) / 256, 256, 0, stream>>>(
        y6, st[6], gg[6], bbv[6], a6, 204, 3 * 128, 1.f / 3072.f, tot);
  }
  // ---- gg7: 204->204, H3, L=128
  gg_tail3_kernel<1, 128, 2, 8><<<dim3(102, 3, 8), 256, 0, stream>>>(
      a6, w7, y7, 204, 204, 3, 1, 204, 0);
  stats_kernel<<<dim3(204, 8, 1), 256, 0, stream>>>(y7, st[7], 204, 384, 1);
  {
    unsigned int tot = 8u * 204 * 3 * 128;
    bnrelu_kernel<<<(tot + 255) / 256, 256, 0, stream>>>(
        y7, st[7], gg[7], bbv[7], a7, 204, 3 * 128, 1.f / 3072.f, tot);
  }
  // ---- gg8: 204->204, H3, L=128
  gg_tail3_kernel<1, 128, 2, 8><<<dim3(102, 3, 8), 256, 0, stream>>>(
      a7, w8, y8, 204, 204, 3, 1, 204, 0);
  stats_kernel<<<dim3(204, 8, 1), 256, 0, stream>>>(y8, st[8], 204, 384, 1);
  {
    unsigned int tot = 8u * 204 * 3 * 32;
    bnrelu_pool_kernel<<<(tot + 255) / 256, 256, 0, stream>>>(
        y8, st[8], gg[8], bbv[8], z8, 204, 3, 128, 1.f / 3072.f, tot);
  }
  // ---- gg9: 204->408, H 3->1, L=32 (K-split x4 into partials, reduce)
  gg_tail3_kernel<3, 32, 8, 2><<<dim3(51, 4, 8), 256, 0, stream>>>(
      z8, w9, part9, 204, 408, 3, 4, 51, 104448);
  reduce_parts_kernel<<<(104448 + 255) / 256, 256, 0, stream>>>(
      part9, y9, 104448, 104448, 4);
  stats_kernel<<<dim3(408, 8, 1), 256, 0, stream>>>(y9, st[9], 408, 32, 1);
  {
    unsigned int tot = 8u * 408 * 32;
    bnrelu_kernel<<<(tot + 255) / 256, 256, 0, stream>>>(
        y9, st[9], gg[9], bbv[9], a9, 408, 32, 1.f / 256.f, tot);
  }
  // ---- gg10: 408->408, H1, L=32 (K-split x4 into partials, reduce)
  gg_tail3_kernel<1, 32, 8, 8><<<dim3(51, 4, 8), 256, 0, stream>>>(
      a9, w10, part10, 408, 408, 1, 4, 102, 104448);
  reduce_parts_kernel<<<(104448 + 255) / 256, 256, 0, stream>>>(
      part10, y10, 104448, 104448, 4);
  stats_kernel<<<dim3(408, 8, 1), 256, 0, stream>>>(y10, st[10], 408, 32, 1);
  // ---- final
  final_kernel<<<dim3(8), 256, 0, stream>>>(y10, st[10], gg[10], bbv[10], w11,
                                            (float*)d_out);
}

// Round 5
// 1010.671 us; speedup vs baseline: 1.1055x; 1.0038x over previous
//
#include <hip/hip_runtime.h>
#include <hip/hip_bf16.h>

#define EPSBN 2e-5f

typedef __attribute__((ext_vector_type(8))) short short8v;
typedef __attribute__((ext_vector_type(4))) float f32x4;

__device__ inline unsigned short f2bf(float f) {
  unsigned u = __float_as_uint(f);
  unsigned r = (u + 0x7FFFu + ((u >> 16) & 1u)) >> 16;
  return (unsigned short)r;
}
__device__ inline float bf2f(unsigned short h) {
  return __uint_as_float(((unsigned)h) << 16);
}

// ---------------------------------------------------------------------------
// Padded x staging — packed split-bf16: (hi16 << 16) | lo16.
// ---------------------------------------------------------------------------
constexpr int XPADL = 9984;
constexpr int XPADR = 14336;
constexpr int PROW = XPADL + 32768 + XPADR;  // 57088

__global__ __launch_bounds__(256) void pad_x_kernel(const float* __restrict__ x,
                                                    unsigned* __restrict__ xp) {
  int i = blockIdx.x * 256 + threadIdx.x;
  if (i >= 8 * PROW) return;
  int b = i / PROW;
  int pos = i - b * PROW - XPADL;
  float v = (pos >= 0 && pos < 32768) ? x[b * 32768 + pos] : 0.f;
  unsigned u = __float_as_uint(v);
  unsigned h = u >> 16;
  float lof = v - __uint_as_float(u & 0xffff0000u);
  unsigned lo = __float_as_uint(lof) >> 16;
  xp[i] = (h << 16) | lo;
}

// ---------------------------------------------------------------------------
// Per-scale pair-packed B source: for scale s (dilation d=2^s),
//   xpH[(s*8+b)*PROW + i] = hi(x[i]) | hi(x[i+d])<<16
//   xpL[...]              = lo(x[i]) | lo(x[i+d])<<16
// ---------------------------------------------------------------------------
__global__ __launch_bounds__(256) void pad_pair_kernel(
    const unsigned* __restrict__ xp, unsigned* __restrict__ xpH,
    unsigned* __restrict__ xpL) {
  const int i = blockIdx.x * 256 + threadIdx.x;
  if (i >= PROW) return;
  const int sb = blockIdx.y;  // s*8 + b
  const int s = sb >> 3;
  const int b = sb & 7;
  const int d = 1 << s;
  const unsigned* row = xp + b * PROW;
  unsigned u0 = row[i];
  unsigned u1 = (i + d < PROW) ? row[i + d] : 0u;
  size_t o = (size_t)sb * PROW + i;
  xpH[o] = (u0 >> 16) | (u1 & 0xffff0000u);
  xpL[o] = (u0 & 0xffffu) | (u1 << 16);
}

// ---------------------------------------------------------------------------
// Pack w1 [51][79] -> per-s split bf16 (1/2^s folded), [s][hi/lo][64][96]
// ---------------------------------------------------------------------------
__global__ __launch_bounds__(256) void pack_w1_kernel(
    const float* __restrict__ W, short* __restrict__ A) {
  int idx = blockIdx.x * 256 + threadIdx.x;
  if (idx >= 9 * 64 * 96) return;
  int s = idx / (64 * 96);
  int rem = idx - s * 64 * 96;
  int co = rem / 96;
  int k = rem - co * 96;
  float v = 0.f;
  if (co < 51 && k < 79)
    v = W[co * 79 + k] * __uint_as_float((unsigned)(127 - s) << 23);
  unsigned short hi = f2bf(v);
  unsigned short lo = f2bf(v - bf2f(hi));
  A[(size_t)s * 2 * 64 * 96 + co * 96 + k] = (short)hi;
  A[(size_t)s * 2 * 64 * 96 + 64 * 96 + co * 96 + k] = (short)lo;
}

// ---------------------------------------------------------------------------
// lift_mfma: lift conv K=79 as bf16 MFMA GEMM + fused pool4 + fused stats.
// Coalesced loads (lane nB -> offset nB). Pool-friendly LDS row permutation
// rho(nB) = ((nB&3)<<4)|(nB>>2) PLUS an XOR slot swizzle to kill the 4-way
// write bank conflict rho introduced (R4: 3.54e7 conflict cycles):
//   write slot kb -> kb ^ ((rowW>>4)<<3)   (rowW>>4 == nB&3)
//   read  slot    -> (ks*32+quad*8) ^ (t<<3)  at row n = n0+16t
// Involution matches both sides because for column c=4*n0+t, rho(c)>>4 =
// c&3 = t = n>>4. Read bank pattern is unchanged from the known-good R2
// layout (quad permuted within the ks block). Epilogue: pool4 in-register,
// 4 full-wave coalesced stores/wave, stats via shfl + lc-sliced partials.
// ---------------------------------------------------------------------------
__global__ __launch_bounds__(256) void lift_mfma_kernel(
    const unsigned* __restrict__ xpH, const unsigned* __restrict__ xpL,
    const short* __restrict__ Apk1, float* __restrict__ y1,
    float* __restrict__ part1) {
  constexpr int P = 104;
  const int bid = blockIdx.x;
  const int lc = (bid & 7) * 64 + (bid >> 3);  // 512 = 8*64, bijective
  const int s = blockIdx.y;
  const int b = blockIdx.z;
  const int d = 1 << s;
  const int l0 = lc * 64;
  const int tid = threadIdx.x;
  const int lane = tid & 63;
  const int quad = lane >> 4;
  const int n0 = lane & 15;
  const int wv = tid >> 6;
  const int coBase = wv * 16;

  __shared__ __align__(16) short Bh[64 * P];
  __shared__ __align__(16) short Bl[64 * P];
  __shared__ float sCh[2][64];

  const int nB = tid & 63;
  const int rowW = ((nB & 3) << 4) | (nB >> 2);  // LDS row permutation
  const int swzW = (nB & 3) << 3;                // write slot XOR (shorts)
  const int ogu = __builtin_amdgcn_readfirstlane(tid >> 6);
  const unsigned* xqH = xpH + (size_t)(s * 8 + b) * PROW + XPADL + l0;
  const unsigned* xqL = xpL + (size_t)(s * 8 + b) * PROW + XPADL + l0;

#pragma unroll
  for (int r = 0; r < 3; ++r) {
    const int kb = (ogu + 4 * r) * 8;
    const int base = (kb - 39) * d;
    uint4 ph, pl;
    ph.x = xqH[base + nB];
    ph.y = xqH[base + 2 * d + nB];
    ph.z = xqH[base + 4 * d + nB];
    ph.w = xqH[base + 6 * d + nB];
    pl.x = xqL[base + nB];
    pl.y = xqL[base + 2 * d + nB];
    pl.z = xqL[base + 4 * d + nB];
    pl.w = xqL[base + 6 * d + nB];
    *(uint4*)(Bh + rowW * P + (kb ^ swzW)) = ph;
    *(uint4*)(Bl + rowW * P + (kb ^ swzW)) = pl;
  }

  const short* ApkS = Apk1 + (size_t)s * 2 * 64 * 96;
  const short* arowH = ApkS + (coBase + n0) * 96;
  const short* arowL = arowH + 64 * 96;

  __syncthreads();

  f32x4 acc[4];
#pragma unroll
  for (int t = 0; t < 4; ++t) acc[t] = (f32x4){0.f, 0.f, 0.f, 0.f};

#pragma unroll
  for (int ks = 0; ks < 3; ++ks) {
    short8v ah = *(const short8v*)(arowH + ks * 32 + quad * 8);
    short8v al = *(const short8v*)(arowL + ks * 32 + quad * 8);
#pragma unroll
    for (int t = 0; t < 4; ++t) {
      const int n = n0 + 16 * t;  // row rho(4*n0+t): holds position 4*n0+t
      const int off = (ks * 32 + quad * 8) ^ (t << 3);
      short8v bh = *(const short8v*)(Bh + n * P + off);
      short8v bl = *(const short8v*)(Bl + n * P + off);
      acc[t] = __builtin_amdgcn_mfma_f32_16x16x32_bf16(ah, bh, acc[t], 0, 0, 0);
      acc[t] = __builtin_amdgcn_mfma_f32_16x16x32_bf16(ah, bl, acc[t], 0, 0, 0);
      acc[t] = __builtin_amdgcn_mfma_f32_16x16x32_bf16(al, bh, acc[t], 0, 0, 0);
    }
  }

  // Epilogue: pool4 over t in-register; lane n0 <-> pooled position l1.
#pragma unroll
  for (int reg = 0; reg < 4; ++reg) {
    const int co = coBase + quad * 4 + reg;
    float po = fmaxf(fmaxf(acc[0][reg], acc[1][reg]),
                     fmaxf(acc[2][reg], acc[3][reg]));
    const bool valid = (co < 51);
    if (valid) {
      y1[(((size_t)b * 51 + co) * 9 + s) * 8192 + (l0 >> 2) + n0] = po;
    }
    float us = valid ? po : 0.f;
    float sq = us * us;
    us += __shfl_xor(us, 1);
    sq += __shfl_xor(sq, 1);
    us += __shfl_xor(us, 2);
    sq += __shfl_xor(sq, 2);
    us += __shfl_xor(us, 4);
    sq += __shfl_xor(sq, 4);
    us += __shfl_xor(us, 8);
    sq += __shfl_xor(sq, 8);
    if (n0 == 0) {
      sCh[0][co] = us;
      sCh[1][co] = sq;
    }
  }
  __syncthreads();
  if (tid < 51) {
    float* pp = part1 + (size_t)lc * 128;
    atomicAdd(&pp[tid], sCh[0][tid]);
    atomicAdd(&pp[64 + tid], sCh[1][tid]);
  }
}

// ---------------------------------------------------------------------------
// Reduce the 512 lc-sliced stats partials (stride 128: [0..50]=sum,
// [64..114]=sumsq) into st[c], st[512+c]. 8 blocks k-split, atomic merge.
// ---------------------------------------------------------------------------
__global__ __launch_bounds__(128) void reduce_stats1_kernel(
    const float* __restrict__ p, float* __restrict__ st) {
  const int t = threadIdx.x;
  if (t >= 102) return;
  const int k0 = blockIdx.x * 64;
  const int off = (t < 51) ? t : (64 + t - 51);
  float s = 0.f;
  for (int k = k0; k < k0 + 64; ++k) s += p[k * 128 + off];
  atomicAdd(&st[(t < 51) ? t : (512 + t - 51)], s);
}

// ---------------------------------------------------------------------------
// Per-channel sum/sumsq over [B,C,HL], HL split NS ways; grid (C,B,NS)
// ---------------------------------------------------------------------------
__global__ __launch_bounds__(256) void stats_kernel(
    const float* __restrict__ Y, float* __restrict__ st, int C, int HL,
    int NS) {
  const int c = blockIdx.x, b = blockIdx.y, z = blockIdx.z;
  const int slice = HL / NS;
  const float* p = Y + ((size_t)b * C + c) * HL + (size_t)z * slice;
  float s = 0.f, q = 0.f;
  for (int i = threadIdx.x; i < slice; i += 256) {
    float v = p[i];
    s += v;
    q += v * v;
  }
#pragma unroll
  for (int off = 32; off > 0; off >>= 1) {
    s += __shfl_down(s, off, 64);
    q += __shfl_down(q, off, 64);
  }
  __shared__ float ls[4], lq[4];
  const int wid = threadIdx.x >> 6, lane = threadIdx.x & 63;
  if (lane == 0) { ls[wid] = s; lq[wid] = q; }
  __syncthreads();
  if (threadIdx.x == 0) {
    atomicAdd(&st[c], ls[0] + ls[1] + ls[2] + ls[3]);
    atomicAdd(&st[512 + c], lq[0] + lq[1] + lq[2] + lq[3]);
  }
}

// ---------------------------------------------------------------------------
// reduce NS partial buffers: y[i] = sum_k p[k*stride + i]
// ---------------------------------------------------------------------------
__global__ __launch_bounds__(256) void reduce_parts_kernel(
    const float* __restrict__ p, float* __restrict__ y, int n, int stride,
    int ns) {
  int i = blockIdx.x * 256 + threadIdx.x;
  if (i >= n) return;
  float s = 0.f;
  for (int k = 0; k < ns; ++k) s += p[(size_t)k * stride + i];
  y[i] = s;
}

// ---------------------------------------------------------------------------
// BN(train)+ReLU+pool4, fp32 out
// ---------------------------------------------------------------------------
__global__ __launch_bounds__(256) void bnrelu_pool_kernel(
    const float* __restrict__ Y, const float* __restrict__ st,
    const float* __restrict__ g, const float* __restrict__ bb,
    float* __restrict__ Z, int C, int H, int Lin, float invN,
    unsigned int total) {
  unsigned int idx = blockIdx.x * 256u + threadIdx.x;
  if (idx >= total) return;
  const unsigned int Lo = (unsigned int)(Lin >> 2);
  unsigned int lo = idx % Lo;
  unsigned int r1 = idx / Lo;
  unsigned int h = r1 % (unsigned int)H;
  unsigned int r2 = r1 / (unsigned int)H;
  unsigned int c = r2 % (unsigned int)C;
  unsigned int b = r2 / (unsigned int)C;
  float m = st[c] * invN;
  float v = st[512 + c] * invN - m * m;
  float sc = g[c] * rsqrtf(v + EPSBN);
  float bi = bb[c] - m * sc;
  const float* p = Y + (((size_t)b * C + c) * H + h) * Lin + 4u * lo;
  float a0 = p[0] * sc + bi, a1 = p[1] * sc + bi;
  float a2 = p[2] * sc + bi, a3 = p[3] * sc + bi;
  float r = fmaxf(fmaxf(a0, a1), fmaxf(a2, a3));
  Z[idx] = fmaxf(r, 0.f);
}

// ---- same, bf16 out
__global__ __launch_bounds__(256) void bnrelu_pool_bf16_kernel(
    const float* __restrict__ Y, const float* __restrict__ st,
    const float* __restrict__ g, const float* __restrict__ bb,
    unsigned short* __restrict__ Z, int C, int H, int Lin, float invN,
    unsigned int total) {
  unsigned int idx = blockIdx.x * 256u + threadIdx.x;
  if (idx >= total) return;
  const unsigned int Lo = (unsigned int)(Lin >> 2);
  unsigned int lo = idx % Lo;
  unsigned int r1 = idx / Lo;
  unsigned int h = r1 % (unsigned int)H;
  unsigned int r2 = r1 / (unsigned int)H;
  unsigned int c = r2 % (unsigned int)C;
  unsigned int b = r2 / (unsigned int)C;
  float m = st[c] * invN;
  float v = st[512 + c] * invN - m * m;
  float sc = g[c] * rsqrtf(v + EPSBN);
  float bi = bb[c] - m * sc;
  const float* p = Y + (((size_t)b * C + c) * H + h) * Lin + 4u * lo;
  float a0 = p[0] * sc + bi, a1 = p[1] * sc + bi;
  float a2 = p[2] * sc + bi, a3 = p[3] * sc + bi;
  float r = fmaxf(fmaxf(a0, a1), fmaxf(a2, a3));
  Z[idx] = f2bf(fmaxf(r, 0.f));
}

// ---------------------------------------------------------------------------
// BN(train)+ReLU elementwise, fp32 / bf16 out
// ---------------------------------------------------------------------------
__global__ __launch_bounds__(256) void bnrelu_kernel(
    const float* __restrict__ Y, const float* __restrict__ st,
    const float* __restrict__ g, const float* __restrict__ bb,
    float* __restrict__ A, int C, int HL, float invN, unsigned int total) {
  unsigned int idx = blockIdx.x * 256u + threadIdx.x;
  if (idx >= total) return;
  unsigned int c = (idx / (unsigned int)HL) % (unsigned int)C;
  float m = st[c] * invN;
  float v = st[512 + c] * invN - m * m;
  float sc = g[c] * rsqrtf(v + EPSBN);
  float bi = bb[c] - m * sc;
  A[idx] = fmaxf(fmaf(Y[idx], sc, bi), 0.f);
}

__global__ __launch_bounds__(256) void bnrelu_bf16_kernel(
    const float* __restrict__ Y, const float* __restrict__ st,
    const float* __restrict__ g, const float* __restrict__ bb,
    unsigned short* __restrict__ A, int C, int HL, float invN,
    unsigned int total) {
  unsigned int idx = blockIdx.x * 256u + threadIdx.x;
  if (idx >= total) return;
  unsigned int c = (idx / (unsigned int)HL) % (unsigned int)C;
  float m = st[c] * invN;
  float v = st[512 + c] * invN - m * m;
  float sc = g[c] * rsqrtf(v + EPSBN);
  float bi = bb[c] - m * sc;
  A[idx] = f2bf(fmaxf(fmaf(Y[idx], sc, bi), 0.f));
}

// ---------------------------------------------------------------------------
// Pack fp32 weights -> per-s split bf16 packs with 2^-(s+i) folded.
// ---------------------------------------------------------------------------
__global__ __launch_bounds__(256) void pack_w2_kernel(
    const float* __restrict__ W, short* __restrict__ A, int Co, int KTOT,
    int KPAD, int COPAD, int NS, int nk3) {
  int idx = blockIdx.x * 256 + threadIdx.x;
  const int CK = COPAD * KPAD;
  if (idx >= NS * CK) return;
  int s = idx / CK;
  int rem = idx - s * CK;
  int co = rem / KPAD;
  int kk = rem - co * KPAD;
  float v = 0.f;
  if (co < Co && kk < KTOT) {
    int i = (kk % nk3) / 3;
    float scale = __uint_as_float((unsigned)(127 - (s + i)) << 23);
    v = W[co * KTOT + kk] * scale;
  }
  unsigned short hi = f2bf(v);
  unsigned short lo = f2bf(v - bf2f(hi));
  A[(size_t)s * 2 * CK + co * KPAD + kk] = (short)hi;
  A[(size_t)s * 2 * CK + CK + co * KPAD + kk] = (short)lo;
}

// ---------------------------------------------------------------------------
// gg_mfma5: bf16-input MFMA GConvGG, no fused stats (R15, unchanged)
// ---------------------------------------------------------------------------
template <int NKv, int LT>
__global__ __launch_bounds__(256) void gg_mfma5_kernel(
    const unsigned short* __restrict__ X, const short* __restrict__ Apk,
    float* __restrict__ Y, int Ci, int Co, int Hin, int L, int nL, int KTOT,
    int KPAD, int COPAD) {
  constexpr int T = LT / 16;
  constexpr int KO = 256 / LT;
  constexpr int RIT = 8 / KO;

  const int bx = blockIdx.x;
  const int lc = bx % nL;
  const int cog = bx / nL;
  const int s = blockIdx.y;
  const int b = blockIdx.z;
  const int Hout = Hin - NKv + 1;
  const int l0 = lc * LT;
  const int tid = threadIdx.x;
  const int lane = tid & 63;
  const int quad = lane >> 4;
  const int m0 = lane & 15;
  const int wv = tid >> 6;
  const int coBase = cog * 64 + wv * 16;

  __shared__ __align__(16) short Bh[LT * 72];
  __shared__ int roT[512];
  __shared__ int shT[512];

  for (int kk = tid; kk < KPAD; kk += 256) {
    int ro = 0, sh = -(1 << 30);
    if (kk < KTOT) {
      int ci = kk / (3 * NKv);
      int rem = kk - ci * (3 * NKv);
      int i = rem / 3;
      int k = rem - 3 * i;
      ro = (ci * Hin + s + i) * L;
      sh = (k - 1) * (1 << (s + i));
    }
    roT[kk] = ro;
    shT[kk] = sh;
  }
  __syncthreads();

  f32x4 acc[T];
#pragma unroll
  for (int t = 0; t < T; ++t) acc[t] = (f32x4){0.f, 0.f, 0.f, 0.f};

  const short* ApkS = Apk + (size_t)s * 2 * COPAD * KPAD;
  const short* arowH = ApkS + (size_t)(coBase + m0) * KPAD;
  const short* arowL = arowH + (size_t)COPAD * KPAD;
  const unsigned short* Xb = X + (size_t)b * Ci * Hin * L;

  const int lB = tid & (LT - 1);
  const int oc0 = tid / LT;
  const int nch = (KTOT + 63) >> 6;

  uint4 v0[RIT], v1[RIT], v2[RIT];
  auto gather = [&](int c0, uint4 (&pk)[RIT]) {
#pragma unroll
    for (int r = 0; r < RIT; ++r) {
      const int oct = oc0 + KO * r;
      const int kkb = (c0 << 6) + oct * 8;
      unsigned w[8];
#pragma unroll
      for (int j = 0; j < 8; ++j) {
        const int kk = kkb + j;
        const int pos = l0 + lB + shT[kk];
        const int posc = min(max(pos, 0), L - 1);
        unsigned u = (unsigned)Xb[roT[kk] + posc];
        w[j] = ((unsigned)pos < (unsigned)L) ? u : 0u;
      }
      pk[r].x = w[0] | (w[1] << 16);
      pk[r].y = w[2] | (w[3] << 16);
      pk[r].z = w[4] | (w[5] << 16);
      pk[r].w = w[6] | (w[7] << 16);
    }
  };

  gather(0, v0);
  if (nch > 1) gather(1, v1);
  for (int c0 = 0; c0 < nch; ++c0) {
#pragma unroll
    for (int r = 0; r < RIT; ++r)
      *(uint4*)(Bh + lB * 72 + (oc0 + KO * r) * 8) = v0[r];
    if (c0 + 2 < nch) gather(c0 + 2, v2);
    const int a0 = (c0 << 6) + quad * 8;
    short8v ah0 = *(const short8v*)(arowH + a0);
    short8v al0 = *(const short8v*)(arowL + a0);
    short8v ah1 = *(const short8v*)(arowH + a0 + 32);
    short8v al1 = *(const short8v*)(arowL + a0 + 32);
    __syncthreads();
#pragma unroll
    for (int t = 0; t < T; ++t) {
      const int l = m0 + 16 * t;
      short8v b0 = *(const short8v*)(Bh + l * 72 + quad * 8);
      short8v b1 = *(const short8v*)(Bh + l * 72 + 32 + quad * 8);
      acc[t] = __builtin_amdgcn_mfma_f32_16x16x32_bf16(ah0, b0, acc[t], 0, 0, 0);
      acc[t] = __builtin_amdgcn_mfma_f32_16x16x32_bf16(al0, b0, acc[t], 0, 0, 0);
      acc[t] = __builtin_amdgcn_mfma_f32_16x16x32_bf16(ah1, b1, acc[t], 0, 0, 0);
      acc[t] = __builtin_amdgcn_mfma_f32_16x16x32_bf16(al1, b1, acc[t], 0, 0, 0);
    }
    __syncthreads();
#pragma unroll
    for (int r = 0; r < RIT; ++r) {
      v0[r] = v1[r];
      v1[r] = v2[r];
    }
  }

#pragma unroll
  for (int reg = 0; reg < 4; ++reg) {
    const int co = coBase + quad * 4 + reg;
    if (co < Co) {
      float* yp = Y + (((size_t)b * Co + co) * Hout + s) * L + l0;
#pragma unroll
      for (int t = 0; t < T; ++t) yp[m0 + 16 * t] = acc[t][reg];
    }
  }
}

// ---------------------------------------------------------------------------
// gg_tail3: unrolled, atomic-free tail GConvGG.
// ---------------------------------------------------------------------------
template <int NK, int L, int COSUB, int UN>
__global__ __launch_bounds__(256) void gg_tail3_kernel(
    const float* __restrict__ X, const float* __restrict__ W,
    float* __restrict__ Y, int Ci, int Co, int Hin, int NSPLIT, int ciPer,
    int partStride) {
  const int l = threadIdx.x % L;
  const int cs = threadIdx.x / L;
  const int co = blockIdx.x * COSUB + cs;
  const int s = blockIdx.y / NSPLIT;
  const int seg = blockIdx.y % NSPLIT;
  const int b = blockIdx.z;
  const int Hout = Hin - NK + 1;
  const int ciBeg = seg * ciPer;
  const int ciEnd = min(Ci, ciBeg + ciPer);

  float acc[NK];
#pragma unroll
  for (int i = 0; i < NK; ++i) acc[i] = 0.f;

  const float* wbase = W + (size_t)co * Ci * NK * 3;
  const float* xbase = X + ((size_t)b * Ci * Hin + s) * L;

  int ci = ciBeg;
  for (; ci + UN <= ciEnd; ci += UN) {
    float xv[UN][NK][3];
#pragma unroll
    for (int u = 0; u < UN; ++u) {
      const float* xr = xbase + (size_t)(ci + u) * (Hin * L);
#pragma unroll
      for (int i = 0; i < NK; ++i) {
        const int d = 1 << (s + i);
        const float* row = xr + i * L;
        xv[u][i][0] = (l >= d) ? row[l - d] : 0.f;
        xv[u][i][1] = row[l];
        xv[u][i][2] = (l + d < L) ? row[l + d] : 0.f;
      }
    }
#pragma unroll
    for (int u = 0; u < UN; ++u) {
      const float* wp = wbase + (ci + u) * (NK * 3);
#pragma unroll
      for (int i = 0; i < NK; ++i)
        acc[i] = fmaf(wp[3 * i], xv[u][i][0],
                      fmaf(wp[3 * i + 1], xv[u][i][1],
                           fmaf(wp[3 * i + 2], xv[u][i][2], acc[i])));
    }
  }
  for (; ci < ciEnd; ++ci) {
    const float* xr = xbase + (size_t)ci * (Hin * L);
    const float* wp = wbase + ci * (NK * 3);
#pragma unroll
    for (int i = 0; i < NK; ++i) {
      const int d = 1 << (s + i);
      const float* row = xr + i * L;
      float xm = (l >= d) ? row[l - d] : 0.f;
      float xc = row[l];
      float xp = (l + d < L) ? row[l + d] : 0.f;
      acc[i] = fmaf(wp[3 * i], xm,
                    fmaf(wp[3 * i + 1], xc, fmaf(wp[3 * i + 2], xp, acc[i])));
    }
  }
  float out = 0.f;
#pragma unroll
  for (int i = 0; i < NK; ++i) {
    float invd = __uint_as_float((unsigned)(127 - (s + i)) << 23);
    out = fmaf(acc[i], invd, out);
  }
  Y[(size_t)seg * partStride + (((size_t)b * Co + co) * Hout + s) * L + l] =
      out;
}

// ---------------------------------------------------------------------------
// Final: bn10+relu, mean over L, classifier
// ---------------------------------------------------------------------------
__global__ __launch_bounds__(256) void final_kernel(
    const float* __restrict__ Y, const float* __restrict__ st,
    const float* __restrict__ g, const float* __restrict__ bb,
    const float* __restrict__ w11, float* __restrict__ out) {
  const int b = blockIdx.x;
  const int tid = threadIdx.x;
  __shared__ float tch[408];
  for (int c = tid; c < 408; c += 256) {
    float m = st[c] * (1.f / 256.f);
    float v = st[512 + c] * (1.f / 256.f) - m * m;
    float sc = g[c] * rsqrtf(v + EPSBN);
    float bi = bb[c] - m * sc;
    const float* p = Y + ((size_t)b * 408 + c) * 32;
    float ssum = 0.f;
#pragma unroll
    for (int l = 0; l < 32; ++l) ssum += fmaxf(p[l] * sc + bi, 0.f);
    tch[c] = ssum * (1.f / 32.f);
  }
  __syncthreads();
  if (tid < 10) {
    float ssum = 0.f;
    for (int c = 0; c < 408; ++c) ssum += w11[tid * 408 + c] * tch[c];
    out[b * 10 + tid] = ssum;
  }
}

// ---------------------------------------------------------------------------
extern "C" void kernel_launch(void* const* d_in, const int* in_sizes, int n_in,
                              void* d_out, int out_size, void* d_ws,
                              size_t ws_size, hipStream_t stream) {
  const float* x = (const float*)d_in[0];
  const float* w1 = (const float*)d_in[1];
  const float* w2 = (const float*)d_in[2];
  const float* w3 = (const float*)d_in[3];
  const float* w4 = (const float*)d_in[4];
  const float* w5 = (const float*)d_in[5];
  const float* w6 = (const float*)d_in[6];
  const float* w7 = (const float*)d_in[7];
  const float* w8 = (const float*)d_in[8];
  const float* w9 = (const float*)d_in[9];
  const float* w10 = (const float*)d_in[10];
  const float* w11 = (const float*)d_in[11];
  const float* gg[11];
  const float* bbv[11];
  for (int i = 1; i <= 10; ++i) {
    gg[i] = (const float*)d_in[12 + 2 * (i - 1)];
    bbv[i] = (const float*)d_in[12 + 2 * (i - 1) + 1];
  }

  float* ws = (float*)d_ws;
  const size_t AR0 = 0;
  const size_t AR1 = 30081024;
  const size_t STATS = 38900000;
  float* y1 = ws + AR0;
  unsigned* xpad = (unsigned*)(ws + AR1);                 // 456704 dw
  short* apk1 = (short*)(ws + AR1 + 460800);              // 110592 shorts
  unsigned* xpairH = (unsigned*)(ws + AR1 + 520000);      // 4110336 dw
  unsigned* xpairL = (unsigned*)(ws + AR1 + 4630336);     // 4110336 dw
  float* part1 = ws + AR1 + 8740672;                      // 512*128 fp32
  unsigned short* z1b = (unsigned short*)(ws + AR1);
  unsigned short* a3b = (unsigned short*)(ws + AR1);
  unsigned short* z3b = (unsigned short*)(ws + AR1);
  unsigned short* a5b = (unsigned short*)(ws + AR1 + 1500000);
  float* z5 = ws + AR1;
  float* a6 = ws + AR1 + 522240;
  float* a7 = ws + AR1 + 1148928;
  float* z8 = ws + AR1;
  float* a9 = ws + AR1 + 1775616;
  float* part9 = ws + AR1 + 1900000;   // 4 * 104448
  float* part10 = ws + AR1 + 2400000;  // 4 * 104448
  float* y2 = ws + AR0;
  float* y3 = ws + AR0 + 5849088;
  float* y4 = ws + AR0;
  float* y5 = ws + AR0 + 2088960;
  float* y6 = ws + AR0;
  float* y7 = ws + AR0 + 626688;
  float* y8 = ws + AR0 + 1253376;
  float* y9 = ws + AR0;
  float* y10 = ws + AR0 + 104448;
  short* apk2 = (short*)(ws + 12000000);
  short* apk3 = apk2 + 7 * 2 * 64 * 512;
  short* apk4 = apk3 + 7 * 2 * 64 * 192;
  short* apk5 = apk4 + 5 * 2 * 128 * 512;
  float* st[11];
  for (int i = 1; i <= 10; ++i) st[i] = ws + STATS + (size_t)(i - 1) * 1024;

  hipMemsetAsync((void*)(ws + STATS), 0, 10 * 1024 * sizeof(float), stream);
  hipMemsetAsync((void*)part1, 0, 512 * 128 * sizeof(float), stream);

  // ---- pad x (packed split-bf16), per-s pair arrays, pack w1, MFMA lift
  pad_x_kernel<<<(8 * PROW + 255) / 256, 256, 0, stream>>>(x, xpad);
  pad_pair_kernel<<<dim3((PROW + 255) / 256, 72), 256, 0, stream>>>(
      xpad, xpairH, xpairL);
  pack_w1_kernel<<<(9 * 64 * 96 + 255) / 256, 256, 0, stream>>>(w1, apk1);
  lift_mfma_kernel<<<dim3(512, 9, 8), 256, 0, stream>>>(xpairH, xpairL, apk1,
                                                        y1, part1);
  reduce_stats1_kernel<<<8, 128, 0, stream>>>(part1, st[1]);
  {
    unsigned int tot = 8u * 51 * 9 * 2048;
    bnrelu_pool_bf16_kernel<<<(tot + 255) / 256, 256, 0, stream>>>(
        y1, st[1], gg[1], bbv[1], z1b, 51, 9, 8192, 1.f / 589824.f, tot);
  }
  // ---- per-s weight packs
  pack_w2_kernel<<<(7 * 64 * 512 + 255) / 256, 256, 0, stream>>>(
      w2, apk2, 51, 459, 512, 64, 7, 9);
  pack_w2_kernel<<<(7 * 64 * 192 + 255) / 256, 256, 0, stream>>>(
      w3, apk3, 51, 153, 192, 64, 7, 3);
  pack_w2_kernel<<<(5 * 128 * 512 + 255) / 256, 256, 0, stream>>>(
      w4, apk4, 102, 459, 512, 128, 5, 9);
  pack_w2_kernel<<<(5 * 128 * 320 + 255) / 256, 256, 0, stream>>>(
      w5, apk5, 102, 306, 320, 128, 5, 3);
  // ---- gg2: 51->51, H 9->7, L=2048
  gg_mfma5_kernel<3, 64><<<dim3(32, 7, 8), 256, 0, stream>>>(
      z1b, apk2, y2, 51, 51, 9, 2048, 32, 459, 512, 64);
  stats_kernel<<<dim3(51, 8, 4), 256, 0, stream>>>(y2, st[2], 51, 7 * 2048, 4);
  {
    unsigned int tot = 8u * 51 * 7 * 2048;
    bnrelu_bf16_kernel<<<(tot + 255) / 256, 256, 0, stream>>>(
        y2, st[2], gg[2], bbv[2], a3b, 51, 7 * 2048, 1.f / 114688.f, tot);
  }
  // ---- gg3: 51->51, H7, L=2048
  gg_mfma5_kernel<1, 64><<<dim3(32, 7, 8), 256, 0, stream>>>(
      a3b, apk3, y3, 51, 51, 7, 2048, 32, 153, 192, 64);
  stats_kernel<<<dim3(51, 8, 4), 256, 0, stream>>>(y3, st[3], 51, 7 * 2048, 4);
  {
    unsigned int tot = 8u * 51 * 7 * 512;
    bnrelu_pool_bf16_kernel<<<(tot + 255) / 256, 256, 0, stream>>>(
        y3, st[3], gg[3], bbv[3], z3b, 51, 7, 2048, 1.f / 114688.f, tot);
  }
  // ---- gg4: 51->102, H 7->5, L=512
  gg_mfma5_kernel<3, 32><<<dim3(32, 5, 8), 256, 0, stream>>>(
      z3b, apk4, y4, 51, 102, 7, 512, 16, 459, 512, 128);
  stats_kernel<<<dim3(102, 8, 2), 256, 0, stream>>>(y4, st[4], 102, 5 * 512,
                                                    2);
  {
    unsigned int tot = 8u * 102 * 5 * 512;
    bnrelu_bf16_kernel<<<(tot + 255) / 256, 256, 0, stream>>>(
        y4, st[4], gg[4], bbv[4], a5b, 102, 5 * 512, 1.f / 20480.f, tot);
  }
  // ---- gg5: 102->102, H5, L=512
  gg_mfma5_kernel<1, 32><<<dim3(32, 5, 8), 256, 0, stream>>>(
      a5b, apk5, y5, 102, 102, 5, 512, 16, 306, 320, 128);
  stats_kernel<<<dim3(102, 8, 2), 256, 0, stream>>>(y5, st[5], 102, 5 * 512,
                                                    2);
  {
    unsigned int tot = 8u * 102 * 5 * 128;
    bnrelu_pool_kernel<<<(tot + 255) / 256, 256, 0, stream>>>(
        y5, st[5], gg[5], bbv[5], z5, 102, 5, 512, 1.f / 20480.f, tot);
  }
  // ---- gg6: 102->204, H 5->3, L=128 (unrolled, direct store)
  gg_tail3_kernel<3, 128, 2, 2><<<dim3(102, 3, 8), 256, 0, stream>>>(
      z5, w6, y6, 102, 204, 5, 1, 102, 0);
  stats_kernel<<<dim3(204, 8, 1), 256, 0, stream>>>(y6, st[6], 204, 384, 1);
  {
    unsigned int tot = 8u * 204 * 3 * 128;
    bnrelu_kernel<<<(tot + 255) / 256, 256, 0, stream>>>(
        y6, st[6], gg[6], bbv[6], a6, 204, 3 * 128, 1.f / 3072.f, tot);
  }
  // ---- gg7: 204->204, H3, L=128
  gg_tail3_kernel<1, 128, 2, 8><<<dim3(102, 3, 8), 256, 0, stream>>>(
      a6, w7, y7, 204, 204, 3, 1, 204, 0);
  stats_kernel<<<dim3(204, 8, 1), 256, 0, stream>>>(y7, st[7], 204, 384, 1);
  {
    unsigned int tot = 8u * 204 * 3 * 128;
    bnrelu_kernel<<<(tot + 255) / 256, 256, 0, stream>>>(
        y7, st[7], gg[7], bbv[7], a7, 204, 3 * 128, 1.f / 3072.f, tot);
  }
  // ---- gg8: 204->204, H3, L=128
  gg_tail3_kernel<1, 128, 2, 8><<<dim3(102, 3, 8), 256, 0, stream>>>(
      a7, w8, y8, 204, 204, 3, 1, 204, 0);
  stats_kernel<<<dim3(204, 8, 1), 256, 0, stream>>>(y8, st[8], 204, 384, 1);
  {
    unsigned int tot = 8u * 204 * 3 * 32;
    bnrelu_pool_kernel<<<(tot + 255) / 256, 256, 0, stream>>>(
        y8, st[8], gg[8], bbv[8], z8, 204, 3, 128, 1.f / 3072.f, tot);
  }
  // ---- gg9: 204->408, H 3->1, L=32 (K-split x4 into partials, reduce)
  gg_tail3_kernel<3, 32, 8, 2><<<dim3(51, 4, 8), 256, 0, stream>>>(
      z8, w9, part9, 204, 408, 3, 4, 51, 104448);
  reduce_parts_kernel<<<(104448 + 255) / 256, 256, 0, stream>>>(
      part9, y9, 104448, 104448, 4);
  stats_kernel<<<dim3(408, 8, 1), 256, 0, stream>>>(y9, st[9], 408, 32, 1);
  {
    unsigned int tot = 8u * 408 * 32;
    bnrelu_kernel<<<(tot + 255) / 256, 256, 0, stream>>>(
        y9, st[9], gg[9], bbv[9], a9, 408, 32, 1.f / 256.f, tot);
  }
  // ---- gg10: 408->408, H1, L=32 (K-split x4 into partials, reduce)
  gg_tail3_kernel<1, 32, 8, 8><<<dim3(51, 4, 8), 256, 0, stream>>>(
      a9, w10, part10, 408, 408, 1, 4, 102, 104448);
  reduce_parts_kernel<<<(104448 + 255) / 256, 256, 0, stream>>>(
      part10, y10, 104448, 104448, 4);
  stats_kernel<<<dim3(408, 8, 1), 256, 0, stream>>>(y10, st[10], 408, 32, 1);
  // ---- final
  final_kernel<<<dim3(8), 256, 0, stream>>>(y10, st[10], gg[10], bbv[10], w11,
                                            (float*)d_out);
}

// Round 6
// 978.423 us; speedup vs baseline: 1.1419x; 1.0330x over previous
//
#include <hip/hip_runtime.h>
#include <hip/hip_bf16.h>

#define EPSBN 2e-5f

typedef __attribute__((ext_vector_type(8))) short short8v;
typedef __attribute__((ext_vector_type(4))) float f32x4;

__device__ inline unsigned short f2bf(float f) {
  unsigned u = __float_as_uint(f);
  unsigned r = (u + 0x7FFFu + ((u >> 16) & 1u)) >> 16;
  return (unsigned short)r;
}
__device__ inline float bf2f(unsigned short h) {
  return __uint_as_float(((unsigned)h) << 16);
}

// DPP row-rotate float add: v += rotate_within_16(v, N). VALU pipe, not LDS.
// ctrl: row_ror:N = 0x120 + N.
template <int CTRL>
__device__ inline float dpp_radd(float v) {
  int r = __builtin_amdgcn_update_dpp(0, __float_as_int(v), CTRL, 0xf, 0xf,
                                      true);
  return v + __int_as_float(r);
}

// ---------------------------------------------------------------------------
// Padded x staging — packed split-bf16: (hi16 << 16) | lo16.
// ---------------------------------------------------------------------------
constexpr int XPADL = 9984;
constexpr int XPADR = 14336;
constexpr int PROW = XPADL + 32768 + XPADR;  // 57088

__global__ __launch_bounds__(256) void pad_x_kernel(const float* __restrict__ x,
                                                    unsigned* __restrict__ xp) {
  int i = blockIdx.x * 256 + threadIdx.x;
  if (i >= 8 * PROW) return;
  int b = i / PROW;
  int pos = i - b * PROW - XPADL;
  float v = (pos >= 0 && pos < 32768) ? x[b * 32768 + pos] : 0.f;
  unsigned u = __float_as_uint(v);
  unsigned h = u >> 16;
  float lof = v - __uint_as_float(u & 0xffff0000u);
  unsigned lo = __float_as_uint(lof) >> 16;
  xp[i] = (h << 16) | lo;
}

// ---------------------------------------------------------------------------
// Per-scale pair-packed B source: for scale s (dilation d=2^s),
//   xpH[(s*8+b)*PROW + i] = hi(x[i]) | hi(x[i+d])<<16
//   xpL[...]              = lo(x[i]) | lo(x[i+d])<<16
// ---------------------------------------------------------------------------
__global__ __launch_bounds__(256) void pad_pair_kernel(
    const unsigned* __restrict__ xp, unsigned* __restrict__ xpH,
    unsigned* __restrict__ xpL) {
  const int i = blockIdx.x * 256 + threadIdx.x;
  if (i >= PROW) return;
  const int sb = blockIdx.y;  // s*8 + b
  const int s = sb >> 3;
  const int b = sb & 7;
  const int d = 1 << s;
  const unsigned* row = xp + b * PROW;
  unsigned u0 = row[i];
  unsigned u1 = (i + d < PROW) ? row[i + d] : 0u;
  size_t o = (size_t)sb * PROW + i;
  xpH[o] = (u0 >> 16) | (u1 & 0xffff0000u);
  xpL[o] = (u0 & 0xffffu) | (u1 << 16);
}

// ---------------------------------------------------------------------------
// Pack w1 [51][79] -> per-s split bf16 (1/2^s folded), [s][hi/lo][64][96]
// ---------------------------------------------------------------------------
__global__ __launch_bounds__(256) void pack_w1_kernel(
    const float* __restrict__ W, short* __restrict__ A) {
  int idx = blockIdx.x * 256 + threadIdx.x;
  if (idx >= 9 * 64 * 96) return;
  int s = idx / (64 * 96);
  int rem = idx - s * 64 * 96;
  int co = rem / 96;
  int k = rem - co * 96;
  float v = 0.f;
  if (co < 51 && k < 79)
    v = W[co * 79 + k] * __uint_as_float((unsigned)(127 - s) << 23);
  unsigned short hi = f2bf(v);
  unsigned short lo = f2bf(v - bf2f(hi));
  A[(size_t)s * 2 * 64 * 96 + co * 96 + k] = (short)hi;
  A[(size_t)s * 2 * 64 * 96 + 64 * 96 + co * 96 + k] = (short)lo;
}

// ---------------------------------------------------------------------------
// lift_mfma: lift conv K=79 as bf16 MFMA GEMM + fused pool4 + fused stats.
// Coalesced loads; rho row permutation + XOR slot swizzle (R5). Epilogue:
// pool4 in-register; the 16-lane stats reduce now uses DPP row_ror adds
// (VALU pipe) instead of 32 ds_swizzle — the LDS pipe was ~85% occupied
// (6 writes + 24 reads + 32 swizzles per wave) and was the serializing
// resource; this moves the reduce off it.
// ---------------------------------------------------------------------------
__global__ __launch_bounds__(256) void lift_mfma_kernel(
    const unsigned* __restrict__ xpH, const unsigned* __restrict__ xpL,
    const short* __restrict__ Apk1, float* __restrict__ y1,
    float* __restrict__ part1) {
  constexpr int P = 104;
  const int bid = blockIdx.x;
  const int lc = (bid & 7) * 64 + (bid >> 3);  // 512 = 8*64, bijective
  const int s = blockIdx.y;
  const int b = blockIdx.z;
  const int d = 1 << s;
  const int l0 = lc * 64;
  const int tid = threadIdx.x;
  const int lane = tid & 63;
  const int quad = lane >> 4;
  const int n0 = lane & 15;
  const int wv = tid >> 6;
  const int coBase = wv * 16;

  __shared__ __align__(16) short Bh[64 * P];
  __shared__ __align__(16) short Bl[64 * P];
  __shared__ float sCh[2][64];

  const int nB = tid & 63;
  const int rowW = ((nB & 3) << 4) | (nB >> 2);  // LDS row permutation
  const int swzW = (nB & 3) << 3;                // write slot XOR (shorts)
  const int ogu = __builtin_amdgcn_readfirstlane(tid >> 6);
  const unsigned* xqH = xpH + (size_t)(s * 8 + b) * PROW + XPADL + l0;
  const unsigned* xqL = xpL + (size_t)(s * 8 + b) * PROW + XPADL + l0;

#pragma unroll
  for (int r = 0; r < 3; ++r) {
    const int kb = (ogu + 4 * r) * 8;
    const int base = (kb - 39) * d;
    uint4 ph, pl;
    ph.x = xqH[base + nB];
    ph.y = xqH[base + 2 * d + nB];
    ph.z = xqH[base + 4 * d + nB];
    ph.w = xqH[base + 6 * d + nB];
    pl.x = xqL[base + nB];
    pl.y = xqL[base + 2 * d + nB];
    pl.z = xqL[base + 4 * d + nB];
    pl.w = xqL[base + 6 * d + nB];
    *(uint4*)(Bh + rowW * P + (kb ^ swzW)) = ph;
    *(uint4*)(Bl + rowW * P + (kb ^ swzW)) = pl;
  }

  const short* ApkS = Apk1 + (size_t)s * 2 * 64 * 96;
  const short* arowH = ApkS + (coBase + n0) * 96;
  const short* arowL = arowH + 64 * 96;

  __syncthreads();

  f32x4 acc[4];
#pragma unroll
  for (int t = 0; t < 4; ++t) acc[t] = (f32x4){0.f, 0.f, 0.f, 0.f};

#pragma unroll
  for (int ks = 0; ks < 3; ++ks) {
    short8v ah = *(const short8v*)(arowH + ks * 32 + quad * 8);
    short8v al = *(const short8v*)(arowL + ks * 32 + quad * 8);
#pragma unroll
    for (int t = 0; t < 4; ++t) {
      const int n = n0 + 16 * t;  // row rho(4*n0+t): holds position 4*n0+t
      const int off = (ks * 32 + quad * 8) ^ (t << 3);
      short8v bh = *(const short8v*)(Bh + n * P + off);
      short8v bl = *(const short8v*)(Bl + n * P + off);
      acc[t] = __builtin_amdgcn_mfma_f32_16x16x32_bf16(ah, bh, acc[t], 0, 0, 0);
      acc[t] = __builtin_amdgcn_mfma_f32_16x16x32_bf16(ah, bl, acc[t], 0, 0, 0);
      acc[t] = __builtin_amdgcn_mfma_f32_16x16x32_bf16(al, bh, acc[t], 0, 0, 0);
    }
  }

  // Epilogue: pool4 over t in-register; lane n0 <-> pooled position l1.
  // 16-lane reduce over n0 via DPP row_ror adds (VALU pipe, no LDS).
#pragma unroll
  for (int reg = 0; reg < 4; ++reg) {
    const int co = coBase + quad * 4 + reg;
    float po = fmaxf(fmaxf(acc[0][reg], acc[1][reg]),
                     fmaxf(acc[2][reg], acc[3][reg]));
    const bool valid = (co < 51);
    if (valid) {
      y1[(((size_t)b * 51 + co) * 9 + s) * 8192 + (l0 >> 2) + n0] = po;
    }
    float us = valid ? po : 0.f;
    float sq = us * us;
    us = dpp_radd<0x128>(us);  // row_ror:8
    sq = dpp_radd<0x128>(sq);
    us = dpp_radd<0x124>(us);  // row_ror:4
    sq = dpp_radd<0x124>(sq);
    us = dpp_radd<0x122>(us);  // row_ror:2
    sq = dpp_radd<0x122>(sq);
    us = dpp_radd<0x121>(us);  // row_ror:1
    sq = dpp_radd<0x121>(sq);
    if (n0 == 0) {
      sCh[0][co] = us;
      sCh[1][co] = sq;
    }
  }
  __syncthreads();
  if (tid < 51) {
    float* pp = part1 + (size_t)lc * 128;
    atomicAdd(&pp[tid], sCh[0][tid]);
    atomicAdd(&pp[64 + tid], sCh[1][tid]);
  }
}

// ---------------------------------------------------------------------------
// Reduce the 512 lc-sliced stats partials (stride 128: [0..50]=sum,
// [64..114]=sumsq) into st[c], st[512+c]. 8 blocks k-split, atomic merge.
// ---------------------------------------------------------------------------
__global__ __launch_bounds__(128) void reduce_stats1_kernel(
    const float* __restrict__ p, float* __restrict__ st) {
  const int t = threadIdx.x;
  if (t >= 102) return;
  const int k0 = blockIdx.x * 64;
  const int off = (t < 51) ? t : (64 + t - 51);
  float s = 0.f;
  for (int k = k0; k < k0 + 64; ++k) s += p[k * 128 + off];
  atomicAdd(&st[(t < 51) ? t : (512 + t - 51)], s);
}

// ---------------------------------------------------------------------------
// Per-channel sum/sumsq over [B,C,HL], HL split NS ways; grid (C,B,NS)
// ---------------------------------------------------------------------------
__global__ __launch_bounds__(256) void stats_kernel(
    const float* __restrict__ Y, float* __restrict__ st, int C, int HL,
    int NS) {
  const int c = blockIdx.x, b = blockIdx.y, z = blockIdx.z;
  const int slice = HL / NS;
  const float* p = Y + ((size_t)b * C + c) * HL + (size_t)z * slice;
  float s = 0.f, q = 0.f;
  for (int i = threadIdx.x; i < slice; i += 256) {
    float v = p[i];
    s += v;
    q += v * v;
  }
#pragma unroll
  for (int off = 32; off > 0; off >>= 1) {
    s += __shfl_down(s, off, 64);
    q += __shfl_down(q, off, 64);
  }
  __shared__ float ls[4], lq[4];
  const int wid = threadIdx.x >> 6, lane = threadIdx.x & 63;
  if (lane == 0) { ls[wid] = s; lq[wid] = q; }
  __syncthreads();
  if (threadIdx.x == 0) {
    atomicAdd(&st[c], ls[0] + ls[1] + ls[2] + ls[3]);
    atomicAdd(&st[512 + c], lq[0] + lq[1] + lq[2] + lq[3]);
  }
}

// ---------------------------------------------------------------------------
// reduce NS partial buffers: y[i] = sum_k p[k*stride + i]
// ---------------------------------------------------------------------------
__global__ __launch_bounds__(256) void reduce_parts_kernel(
    const float* __restrict__ p, float* __restrict__ y, int n, int stride,
    int ns) {
  int i = blockIdx.x * 256 + threadIdx.x;
  if (i >= n) return;
  float s = 0.f;
  for (int k = 0; k < ns; ++k) s += p[(size_t)k * stride + i];
  y[i] = s;
}

// ---------------------------------------------------------------------------
// BN(train)+ReLU+pool4, fp32 out
// ---------------------------------------------------------------------------
__global__ __launch_bounds__(256) void bnrelu_pool_kernel(
    const float* __restrict__ Y, const float* __restrict__ st,
    const float* __restrict__ g, const float* __restrict__ bb,
    float* __restrict__ Z, int C, int H, int Lin, float invN,
    unsigned int total) {
  unsigned int idx = blockIdx.x * 256u + threadIdx.x;
  if (idx >= total) return;
  const unsigned int Lo = (unsigned int)(Lin >> 2);
  unsigned int lo = idx % Lo;
  unsigned int r1 = idx / Lo;
  unsigned int h = r1 % (unsigned int)H;
  unsigned int r2 = r1 / (unsigned int)H;
  unsigned int c = r2 % (unsigned int)C;
  unsigned int b = r2 / (unsigned int)C;
  float m = st[c] * invN;
  float v = st[512 + c] * invN - m * m;
  float sc = g[c] * rsqrtf(v + EPSBN);
  float bi = bb[c] - m * sc;
  const float* p = Y + (((size_t)b * C + c) * H + h) * Lin + 4u * lo;
  float a0 = p[0] * sc + bi, a1 = p[1] * sc + bi;
  float a2 = p[2] * sc + bi, a3 = p[3] * sc + bi;
  float r = fmaxf(fmaxf(a0, a1), fmaxf(a2, a3));
  Z[idx] = fmaxf(r, 0.f);
}

// ---- same, bf16 out
__global__ __launch_bounds__(256) void bnrelu_pool_bf16_kernel(
    const float* __restrict__ Y, const float* __restrict__ st,
    const float* __restrict__ g, const float* __restrict__ bb,
    unsigned short* __restrict__ Z, int C, int H, int Lin, float invN,
    unsigned int total) {
  unsigned int idx = blockIdx.x * 256u + threadIdx.x;
  if (idx >= total) return;
  const unsigned int Lo = (unsigned int)(Lin >> 2);
  unsigned int lo = idx % Lo;
  unsigned int r1 = idx / Lo;
  unsigned int h = r1 % (unsigned int)H;
  unsigned int r2 = r1 / (unsigned int)H;
  unsigned int c = r2 % (unsigned int)C;
  unsigned int b = r2 / (unsigned int)C;
  float m = st[c] * invN;
  float v = st[512 + c] * invN - m * m;
  float sc = g[c] * rsqrtf(v + EPSBN);
  float bi = bb[c] - m * sc;
  const float* p = Y + (((size_t)b * C + c) * H + h) * Lin + 4u * lo;
  float a0 = p[0] * sc + bi, a1 = p[1] * sc + bi;
  float a2 = p[2] * sc + bi, a3 = p[3] * sc + bi;
  float r = fmaxf(fmaxf(a0, a1), fmaxf(a2, a3));
  Z[idx] = f2bf(fmaxf(r, 0.f));
}

// ---------------------------------------------------------------------------
// BN(train)+ReLU elementwise, fp32 / bf16 out
// ---------------------------------------------------------------------------
__global__ __launch_bounds__(256) void bnrelu_kernel(
    const float* __restrict__ Y, const float* __restrict__ st,
    const float* __restrict__ g, const float* __restrict__ bb,
    float* __restrict__ A, int C, int HL, float invN, unsigned int total) {
  unsigned int idx = blockIdx.x * 256u + threadIdx.x;
  if (idx >= total) return;
  unsigned int c = (idx / (unsigned int)HL) % (unsigned int)C;
  float m = st[c] * invN;
  float v = st[512 + c] * invN - m * m;
  float sc = g[c] * rsqrtf(v + EPSBN);
  float bi = bb[c] - m * sc;
  A[idx] = fmaxf(fmaf(Y[idx], sc, bi), 0.f);
}

__global__ __launch_bounds__(256) void bnrelu_bf16_kernel(
    const float* __restrict__ Y, const float* __restrict__ st,
    const float* __restrict__ g, const float* __restrict__ bb,
    unsigned short* __restrict__ A, int C, int HL, float invN,
    unsigned int total) {
  unsigned int idx = blockIdx.x * 256u + threadIdx.x;
  if (idx >= total) return;
  unsigned int c = (idx / (unsigned int)HL) % (unsigned int)C;
  float m = st[c] * invN;
  float v = st[512 + c] * invN - m * m;
  float sc = g[c] * rsqrtf(v + EPSBN);
  float bi = bb[c] - m * sc;
  A[idx] = f2bf(fmaxf(fmaf(Y[idx], sc, bi), 0.f));
}

// ---------------------------------------------------------------------------
// Pack fp32 weights -> per-s split bf16 packs with 2^-(s+i) folded.
// ---------------------------------------------------------------------------
__global__ __launch_bounds__(256) void pack_w2_kernel(
    const float* __restrict__ W, short* __restrict__ A, int Co, int KTOT,
    int KPAD, int COPAD, int NS, int nk3) {
  int idx = blockIdx.x * 256 + threadIdx.x;
  const int CK = COPAD * KPAD;
  if (idx >= NS * CK) return;
  int s = idx / CK;
  int rem = idx - s * CK;
  int co = rem / KPAD;
  int kk = rem - co * KPAD;
  float v = 0.f;
  if (co < Co && kk < KTOT) {
    int i = (kk % nk3) / 3;
    float scale = __uint_as_float((unsigned)(127 - (s + i)) << 23);
    v = W[co * KTOT + kk] * scale;
  }
  unsigned short hi = f2bf(v);
  unsigned short lo = f2bf(v - bf2f(hi));
  A[(size_t)s * 2 * CK + co * KPAD + kk] = (short)hi;
  A[(size_t)s * 2 * CK + CK + co * KPAD + kk] = (short)lo;
}

// ---------------------------------------------------------------------------
// gg_mfma5: bf16-input MFMA GConvGG, no fused stats (R15, unchanged)
// ---------------------------------------------------------------------------
template <int NKv, int LT>
__global__ __launch_bounds__(256) void gg_mfma5_kernel(
    const unsigned short* __restrict__ X, const short* __restrict__ Apk,
    float* __restrict__ Y, int Ci, int Co, int Hin, int L, int nL, int KTOT,
    int KPAD, int COPAD) {
  constexpr int T = LT / 16;
  constexpr int KO = 256 / LT;
  constexpr int RIT = 8 / KO;

  const int bx = blockIdx.x;
  const int lc = bx % nL;
  const int cog = bx / nL;
  const int s = blockIdx.y;
  const int b = blockIdx.z;
  const int Hout = Hin - NKv + 1;
  const int l0 = lc * LT;
  const int tid = threadIdx.x;
  const int lane = tid & 63;
  const int quad = lane >> 4;
  const int m0 = lane & 15;
  const int wv = tid >> 6;
  const int coBase = cog * 64 + wv * 16;

  __shared__ __align__(16) short Bh[LT * 72];
  __shared__ int roT[512];
  __shared__ int shT[512];

  for (int kk = tid; kk < KPAD; kk += 256) {
    int ro = 0, sh = -(1 << 30);
    if (kk < KTOT) {
      int ci = kk / (3 * NKv);
      int rem = kk - ci * (3 * NKv);
      int i = rem / 3;
      int k = rem - 3 * i;
      ro = (ci * Hin + s + i) * L;
      sh = (k - 1) * (1 << (s + i));
    }
    roT[kk] = ro;
    shT[kk] = sh;
  }
  __syncthreads();

  f32x4 acc[T];
#pragma unroll
  for (int t = 0; t < T; ++t) acc[t] = (f32x4){0.f, 0.f, 0.f, 0.f};

  const short* ApkS = Apk + (size_t)s * 2 * COPAD * KPAD;
  const short* arowH = ApkS + (size_t)(coBase + m0) * KPAD;
  const short* arowL = arowH + (size_t)COPAD * KPAD;
  const unsigned short* Xb = X + (size_t)b * Ci * Hin * L;

  const int lB = tid & (LT - 1);
  const int oc0 = tid / LT;
  const int nch = (KTOT + 63) >> 6;

  uint4 v0[RIT], v1[RIT], v2[RIT];
  auto gather = [&](int c0, uint4 (&pk)[RIT]) {
#pragma unroll
    for (int r = 0; r < RIT; ++r) {
      const int oct = oc0 + KO * r;
      const int kkb = (c0 << 6) + oct * 8;
      unsigned w[8];
#pragma unroll
      for (int j = 0; j < 8; ++j) {
        const int kk = kkb + j;
        const int pos = l0 + lB + shT[kk];
        const int posc = min(max(pos, 0), L - 1);
        unsigned u = (unsigned)Xb[roT[kk] + posc];
        w[j] = ((unsigned)pos < (unsigned)L) ? u : 0u;
      }
      pk[r].x = w[0] | (w[1] << 16);
      pk[r].y = w[2] | (w[3] << 16);
      pk[r].z = w[4] | (w[5] << 16);
      pk[r].w = w[6] | (w[7] << 16);
    }
  };

  gather(0, v0);
  if (nch > 1) gather(1, v1);
  for (int c0 = 0; c0 < nch; ++c0) {
#pragma unroll
    for (int r = 0; r < RIT; ++r)
      *(uint4*)(Bh + lB * 72 + (oc0 + KO * r) * 8) = v0[r];
    if (c0 + 2 < nch) gather(c0 + 2, v2);
    const int a0 = (c0 << 6) + quad * 8;
    short8v ah0 = *(const short8v*)(arowH + a0);
    short8v al0 = *(const short8v*)(arowL + a0);
    short8v ah1 = *(const short8v*)(arowH + a0 + 32);
    short8v al1 = *(const short8v*)(arowL + a0 + 32);
    __syncthreads();
#pragma unroll
    for (int t = 0; t < T; ++t) {
      const int l = m0 + 16 * t;
      short8v b0 = *(const short8v*)(Bh + l * 72 + quad * 8);
      short8v b1 = *(const short8v*)(Bh + l * 72 + 32 + quad * 8);
      acc[t] = __builtin_amdgcn_mfma_f32_16x16x32_bf16(ah0, b0, acc[t], 0, 0, 0);
      acc[t] = __builtin_amdgcn_mfma_f32_16x16x32_bf16(al0, b0, acc[t], 0, 0, 0);
      acc[t] = __builtin_amdgcn_mfma_f32_16x16x32_bf16(ah1, b1, acc[t], 0, 0, 0);
      acc[t] = __builtin_amdgcn_mfma_f32_16x16x32_bf16(al1, b1, acc[t], 0, 0, 0);
    }
    __syncthreads();
#pragma unroll
    for (int r = 0; r < RIT; ++r) {
      v0[r] = v1[r];
      v1[r] = v2[r];
    }
  }

#pragma unroll
  for (int reg = 0; reg < 4; ++reg) {
    const int co = coBase + quad * 4 + reg;
    if (co < Co) {
      float* yp = Y + (((size_t)b * Co + co) * Hout + s) * L + l0;
#pragma unroll
      for (int t = 0; t < T; ++t) yp[m0 + 16 * t] = acc[t][reg];
    }
  }
}

// ---------------------------------------------------------------------------
// gg_tail3: unrolled, atomic-free tail GConvGG.
// ---------------------------------------------------------------------------
template <int NK, int L, int COSUB, int UN>
__global__ __launch_bounds__(256) void gg_tail3_kernel(
    const float* __restrict__ X, const float* __restrict__ W,
    float* __restrict__ Y, int Ci, int Co, int Hin, int NSPLIT, int ciPer,
    int partStride) {
  const int l = threadIdx.x % L;
  const int cs = threadIdx.x / L;
  const int co = blockIdx.x * COSUB + cs;
  const int s = blockIdx.y / NSPLIT;
  const int seg = blockIdx.y % NSPLIT;
  const int b = blockIdx.z;
  const int Hout = Hin - NK + 1;
  const int ciBeg = seg * ciPer;
  const int ciEnd = min(Ci, ciBeg + ciPer);

  float acc[NK];
#pragma unroll
  for (int i = 0; i < NK; ++i) acc[i] = 0.f;

  const float* wbase = W + (size_t)co * Ci * NK * 3;
  const float* xbase = X + ((size_t)b * Ci * Hin + s) * L;

  int ci = ciBeg;
  for (; ci + UN <= ciEnd; ci += UN) {
    float xv[UN][NK][3];
#pragma unroll
    for (int u = 0; u < UN; ++u) {
      const float* xr = xbase + (size_t)(ci + u) * (Hin * L);
#pragma unroll
      for (int i = 0; i < NK; ++i) {
        const int d = 1 << (s + i);
        const float* row = xr + i * L;
        xv[u][i][0] = (l >= d) ? row[l - d] : 0.f;
        xv[u][i][1] = row[l];
        xv[u][i][2] = (l + d < L) ? row[l + d] : 0.f;
      }
    }
#pragma unroll
    for (int u = 0; u < UN; ++u) {
      const float* wp = wbase + (ci + u) * (NK * 3);
#pragma unroll
      for (int i = 0; i < NK; ++i)
        acc[i] = fmaf(wp[3 * i], xv[u][i][0],
                      fmaf(wp[3 * i + 1], xv[u][i][1],
                           fmaf(wp[3 * i + 2], xv[u][i][2], acc[i])));
    }
  }
  for (; ci < ciEnd; ++ci) {
    const float* xr = xbase + (size_t)ci * (Hin * L);
    const float* wp = wbase + ci * (NK * 3);
#pragma unroll
    for (int i = 0; i < NK; ++i) {
      const int d = 1 << (s + i);
      const float* row = xr + i * L;
      float xm = (l >= d) ? row[l - d] : 0.f;
      float xc = row[l];
      float xp = (l + d < L) ? row[l + d] : 0.f;
      acc[i] = fmaf(wp[3 * i], xm,
                    fmaf(wp[3 * i + 1], xc, fmaf(wp[3 * i + 2], xp, acc[i])));
    }
  }
  float out = 0.f;
#pragma unroll
  for (int i = 0; i < NK; ++i) {
    float invd = __uint_as_float((unsigned)(127 - (s + i)) << 23);
    out = fmaf(acc[i], invd, out);
  }
  Y[(size_t)seg * partStride + (((size_t)b * Co + co) * Hout + s) * L + l] =
      out;
}

// ---------------------------------------------------------------------------
// Final: bn10+relu, mean over L, classifier
// ---------------------------------------------------------------------------
__global__ __launch_bounds__(256) void final_kernel(
    const float* __restrict__ Y, const float* __restrict__ st,
    const float* __restrict__ g, const float* __restrict__ bb,
    const float* __restrict__ w11, float* __restrict__ out) {
  const int b = blockIdx.x;
  const int tid = threadIdx.x;
  __shared__ float tch[408];
  for (int c = tid; c < 408; c += 256) {
    float m = st[c] * (1.f / 256.f);
    float v = st[512 + c] * (1.f / 256.f) - m * m;
    float sc = g[c] * rsqrtf(v + EPSBN);
    float bi = bb[c] - m * sc;
    const float* p = Y + ((size_t)b * 408 + c) * 32;
    float ssum = 0.f;
#pragma unroll
    for (int l = 0; l < 32; ++l) ssum += fmaxf(p[l] * sc + bi, 0.f);
    tch[c] = ssum * (1.f / 32.f);
  }
  __syncthreads();
  if (tid < 10) {
    float ssum = 0.f;
    for (int c = 0; c < 408; ++c) ssum += w11[tid * 408 + c] * tch[c];
    out[b * 10 + tid] = ssum;
  }
}

// ---------------------------------------------------------------------------
extern "C" void kernel_launch(void* const* d_in, const int* in_sizes, int n_in,
                              void* d_out, int out_size, void* d_ws,
                              size_t ws_size, hipStream_t stream) {
  const float* x = (const float*)d_in[0];
  const float* w1 = (const float*)d_in[1];
  const float* w2 = (const float*)d_in[2];
  const float* w3 = (const float*)d_in[3];
  const float* w4 = (const float*)d_in[4];
  const float* w5 = (const float*)d_in[5];
  const float* w6 = (const float*)d_in[6];
  const float* w7 = (const float*)d_in[7];
  const float* w8 = (const float*)d_in[8];
  const float* w9 = (const float*)d_in[9];
  const float* w10 = (const float*)d_in[10];
  const float* w11 = (const float*)d_in[11];
  const float* gg[11];
  const float* bbv[11];
  for (int i = 1; i <= 10; ++i) {
    gg[i] = (const float*)d_in[12 + 2 * (i - 1)];
    bbv[i] = (const float*)d_in[12 + 2 * (i - 1) + 1];
  }

  float* ws = (float*)d_ws;
  const size_t AR0 = 0;
  const size_t AR1 = 30081024;
  const size_t STATS = 38900000;
  float* y1 = ws + AR0;
  unsigned* xpad = (unsigned*)(ws + AR1);                 // 456704 dw
  short* apk1 = (short*)(ws + AR1 + 460800);              // 110592 shorts
  unsigned* xpairH = (unsigned*)(ws + AR1 + 520000);      // 4110336 dw
  unsigned* xpairL = (unsigned*)(ws + AR1 + 4630336);     // 4110336 dw
  float* part1 = ws + AR1 + 8740672;                      // 512*128 fp32
  unsigned short* z1b = (unsigned short*)(ws + AR1);
  unsigned short* a3b = (unsigned short*)(ws + AR1);
  unsigned short* z3b = (unsigned short*)(ws + AR1);
  unsigned short* a5b = (unsigned short*)(ws + AR1 + 1500000);
  float* z5 = ws + AR1;
  float* a6 = ws + AR1 + 522240;
  float* a7 = ws + AR1 + 1148928;
  float* z8 = ws + AR1;
  float* a9 = ws + AR1 + 1775616;
  float* part9 = ws + AR1 + 1900000;   // 4 * 104448
  float* part10 = ws + AR1 + 2400000;  // 4 * 104448
  float* y2 = ws + AR0;
  float* y3 = ws + AR0 + 5849088;
  float* y4 = ws + AR0;
  float* y5 = ws + AR0 + 2088960;
  float* y6 = ws + AR0;
  float* y7 = ws + AR0 + 626688;
  float* y8 = ws + AR0 + 1253376;
  float* y9 = ws + AR0;
  float* y10 = ws + AR0 + 104448;
  short* apk2 = (short*)(ws + 12000000);
  short* apk3 = apk2 + 7 * 2 * 64 * 512;
  short* apk4 = apk3 + 7 * 2 * 64 * 192;
  short* apk5 = apk4 + 5 * 2 * 128 * 512;
  float* st[11];
  for (int i = 1; i <= 10; ++i) st[i] = ws + STATS + (size_t)(i - 1) * 1024;

  hipMemsetAsync((void*)(ws + STATS), 0, 10 * 1024 * sizeof(float), stream);
  hipMemsetAsync((void*)part1, 0, 512 * 128 * sizeof(float), stream);

  // ---- pad x (packed split-bf16), per-s pair arrays, pack w1, MFMA lift
  pad_x_kernel<<<(8 * PROW + 255) / 256, 256, 0, stream>>>(x, xpad);
  pad_pair_kernel<<<dim3((PROW + 255) / 256, 72), 256, 0, stream>>>(
      xpad, xpairH, xpairL);
  pack_w1_kernel<<<(9 * 64 * 96 + 255) / 256, 256, 0, stream>>>(w1, apk1);
  lift_mfma_kernel<<<dim3(512, 9, 8), 256, 0, stream>>>(xpairH, xpairL, apk1,
                                                        y1, part1);
  reduce_stats1_kernel<<<8, 128, 0, stream>>>(part1, st[1]);
  {
    unsigned int tot = 8u * 51 * 9 * 2048;
    bnrelu_pool_bf16_kernel<<<(tot + 255) / 256, 256, 0, stream>>>(
        y1, st[1], gg[1], bbv[1], z1b, 51, 9, 8192, 1.f / 589824.f, tot);
  }
  // ---- per-s weight packs
  pack_w2_kernel<<<(7 * 64 * 512 + 255) / 256, 256, 0, stream>>>(
      w2, apk2, 51, 459, 512, 64, 7, 9);
  pack_w2_kernel<<<(7 * 64 * 192 + 255) / 256, 256, 0, stream>>>(
      w3, apk3, 51, 153, 192, 64, 7, 3);
  pack_w2_kernel<<<(5 * 128 * 512 + 255) / 256, 256, 0, stream>>>(
      w4, apk4, 102, 459, 512, 128, 5, 9);
  pack_w2_kernel<<<(5 * 128 * 320 + 255) / 256, 256, 0, stream>>>(
      w5, apk5, 102, 306, 320, 128, 5, 3);
  // ---- gg2: 51->51, H 9->7, L=2048
  gg_mfma5_kernel<3, 64><<<dim3(32, 7, 8), 256, 0, stream>>>(
      z1b, apk2, y2, 51, 51, 9, 2048, 32, 459, 512, 64);
  stats_kernel<<<dim3(51, 8, 4), 256, 0, stream>>>(y2, st[2], 51, 7 * 2048, 4);
  {
    unsigned int tot = 8u * 51 * 7 * 2048;
    bnrelu_bf16_kernel<<<(tot + 255) / 256, 256, 0, stream>>>(
        y2, st[2], gg[2], bbv[2], a3b, 51, 7 * 2048, 1.f / 114688.f, tot);
  }
  // ---- gg3: 51->51, H7, L=2048
  gg_mfma5_kernel<1, 64><<<dim3(32, 7, 8), 256, 0, stream>>>(
      a3b, apk3, y3, 51, 51, 7, 2048, 32, 153, 192, 64);
  stats_kernel<<<dim3(51, 8, 4), 256, 0, stream>>>(y3, st[3], 51, 7 * 2048, 4);
  {
    unsigned int tot = 8u * 51 * 7 * 512;
    bnrelu_pool_bf16_kernel<<<(tot + 255) / 256, 256, 0, stream>>>(
        y3, st[3], gg[3], bbv[3], z3b, 51, 7, 2048, 1.f / 114688.f, tot);
  }
  // ---- gg4: 51->102, H 7->5, L=512
  gg_mfma5_kernel<3, 32><<<dim3(32, 5, 8), 256, 0, stream>>>(
      z3b, apk4, y4, 51, 102, 7, 512, 16, 459, 512, 128);
  stats_kernel<<<dim3(102, 8, 2), 256, 0, stream>>>(y4, st[4], 102, 5 * 512,
                                                    2);
  {
    unsigned int tot = 8u * 102 * 5 * 512;
    bnrelu_bf16_kernel<<<(tot + 255) / 256, 256, 0, stream>>>(
        y4, st[4], gg[4], bbv[4], a5b, 102, 5 * 512, 1.f / 20480.f, tot);
  }
  // ---- gg5: 102->102, H5, L=512
  gg_mfma5_kernel<1, 32><<<dim3(32, 5, 8), 256, 0, stream>>>(
      a5b, apk5, y5, 102, 102, 5, 512, 16, 306, 320, 128);
  stats_kernel<<<dim3(102, 8, 2), 256, 0, stream>>>(y5, st[5], 102, 5 * 512,
                                                    2);
  {
    unsigned int tot = 8u * 102 * 5 * 128;
    bnrelu_pool_kernel<<<(tot + 255) / 256, 256, 0, stream>>>(
        y5, st[5], gg[5], bbv[5], z5, 102, 5, 512, 1.f / 20480.f, tot);
  }
  // ---- gg6: 102->204, H 5->3, L=128 (unrolled, direct store)
  gg_tail3_kernel<3, 128, 2, 2><<<dim3(102, 3, 8), 256, 0, stream>>>(
      z5, w6, y6, 102, 204, 5, 1, 102, 0);
  stats_kernel<<<dim3(204, 8, 1), 256, 0, stream>>>(y6, st[6], 204, 384, 1);
  {
    unsigned int tot = 8u * 204 * 3 * 128;
    bnrelu_kernel<<<(tot + 255) / 256, 256, 0, stream>>>(
        y6, st[6], gg[6], bbv[6], a6, 204, 3 * 128, 1.f / 3072.f, tot);
  }
  // ---- gg7: 204->204, H3, L=128
  gg_tail3_kernel<1, 128, 2, 8><<<dim3(102, 3, 8), 256, 0, stream>>>(
      a6, w7, y7, 204, 204, 3, 1, 204, 0);
  stats_kernel<<<dim3(204, 8, 1), 256, 0, stream>>>(y7, st[7], 204, 384, 1);
  {
    unsigned int tot = 8u * 204 * 3 * 128;
    bnrelu_kernel<<<(tot + 255) / 256, 256, 0, stream>>>(
        y7, st[7], gg[7], bbv[7], a7, 204, 3 * 128, 1.f / 3072.f, tot);
  }
  // ---- gg8: 204->204, H3, L=128
  gg_tail3_kernel<1, 128, 2, 8><<<dim3(102, 3, 8), 256, 0, stream>>>(
      a7, w8, y8, 204, 204, 3, 1, 204, 0);
  stats_kernel<<<dim3(204, 8, 1), 256, 0, stream>>>(y8, st[8], 204, 384, 1);
  {
    unsigned int tot = 8u * 204 * 3 * 32;
    bnrelu_pool_kernel<<<(tot + 255) / 256, 256, 0, stream>>>(
        y8, st[8], gg[8], bbv[8], z8, 204, 3, 128, 1.f / 3072.f, tot);
  }
  // ---- gg9: 204->408, H 3->1, L=32 (K-split x4 into partials, reduce)
  gg_tail3_kernel<3, 32, 8, 2><<<dim3(51, 4, 8), 256, 0, stream>>>(
      z8, w9, part9, 204, 408, 3, 4, 51, 104448);
  reduce_parts_kernel<<<(104448 + 255) / 256, 256, 0, stream>>>(
      part9, y9, 104448, 104448, 4);
  stats_kernel<<<dim3(408, 8, 1), 256, 0, stream>>>(y9, st[9], 408, 32, 1);
  {
    unsigned int tot = 8u * 408 * 32;
    bnrelu_kernel<<<(tot + 255) / 256, 256, 0, stream>>>(
        y9, st[9], gg[9], bbv[9], a9, 408, 32, 1.f / 256.f, tot);
  }
  // ---- gg10: 408->408, H1, L=32 (K-split x4 into partials, reduce)
  gg_tail3_kernel<1, 32, 8, 8><<<dim3(51, 4, 8), 256, 0, stream>>>(
      a9, w10, part10, 408, 408, 1, 4, 102, 104448);
  reduce_parts_kernel<<<(104448 + 255) / 256, 256, 0, stream>>>(
      part10, y10, 104448, 104448, 4);
  stats_kernel<<<dim3(408, 8, 1), 256, 0, stream>>>(y10, st[10], 408, 32, 1);
  // ---- final
  final_kernel<<<dim3(8), 256, 0, stream>>>(y10, st[10], gg[10], bbv[10], w11,
                                            (float*)d_out);
}

// Round 7
// 973.350 us; speedup vs baseline: 1.1478x; 1.0052x over previous
//
#include <hip/hip_runtime.h>
#include <hip/hip_bf16.h>

#define EPSBN 2e-5f

typedef __attribute__((ext_vector_type(8))) short short8v;
typedef __attribute__((ext_vector_type(4))) float f32x4;

__device__ inline unsigned short f2bf(float f) {
  unsigned u = __float_as_uint(f);
  unsigned r = (u + 0x7FFFu + ((u >> 16) & 1u)) >> 16;
  return (unsigned short)r;
}
__device__ inline float bf2f(unsigned short h) {
  return __uint_as_float(((unsigned)h) << 16);
}

// DPP row-rotate float add: v += rotate_within_16(v, N). VALU pipe, not LDS.
template <int CTRL>
__device__ inline float dpp_radd(float v) {
  int r = __builtin_amdgcn_update_dpp(0, __float_as_int(v), CTRL, 0xf, 0xf,
                                      true);
  return v + __int_as_float(r);
}

// ---------------------------------------------------------------------------
// Padded x staging — packed split-bf16: (hi16 << 16) | lo16.
// ---------------------------------------------------------------------------
constexpr int XPADL = 9984;
constexpr int XPADR = 14336;
constexpr int PROW = XPADL + 32768 + XPADR;  // 57088

__global__ __launch_bounds__(256) void pad_x_kernel(const float* __restrict__ x,
                                                    unsigned* __restrict__ xp) {
  int i = blockIdx.x * 256 + threadIdx.x;
  if (i >= 8 * PROW) return;
  int b = i / PROW;
  int pos = i - b * PROW - XPADL;
  float v = (pos >= 0 && pos < 32768) ? x[b * 32768 + pos] : 0.f;
  unsigned u = __float_as_uint(v);
  unsigned h = u >> 16;
  float lof = v - __uint_as_float(u & 0xffff0000u);
  unsigned lo = __float_as_uint(lof) >> 16;
  xp[i] = (h << 16) | lo;
}

// ---------------------------------------------------------------------------
// Per-scale pair-packed B source
// ---------------------------------------------------------------------------
__global__ __launch_bounds__(256) void pad_pair_kernel(
    const unsigned* __restrict__ xp, unsigned* __restrict__ xpH,
    unsigned* __restrict__ xpL) {
  const int i = blockIdx.x * 256 + threadIdx.x;
  if (i >= PROW) return;
  const int sb = blockIdx.y;  // s*8 + b
  const int s = sb >> 3;
  const int b = sb & 7;
  const int d = 1 << s;
  const unsigned* row = xp + b * PROW;
  unsigned u0 = row[i];
  unsigned u1 = (i + d < PROW) ? row[i + d] : 0u;
  size_t o = (size_t)sb * PROW + i;
  xpH[o] = (u0 >> 16) | (u1 & 0xffff0000u);
  xpL[o] = (u0 & 0xffffu) | (u1 << 16);
}

// ---------------------------------------------------------------------------
// Pack w1 [51][79] -> per-s split bf16 (1/2^s folded), [s][hi/lo][64][96]
// ---------------------------------------------------------------------------
__global__ __launch_bounds__(256) void pack_w1_kernel(
    const float* __restrict__ W, short* __restrict__ A) {
  int idx = blockIdx.x * 256 + threadIdx.x;
  if (idx >= 9 * 64 * 96) return;
  int s = idx / (64 * 96);
  int rem = idx - s * 64 * 96;
  int co = rem / 96;
  int k = rem - co * 96;
  float v = 0.f;
  if (co < 51 && k < 79)
    v = W[co * 79 + k] * __uint_as_float((unsigned)(127 - s) << 23);
  unsigned short hi = f2bf(v);
  unsigned short lo = f2bf(v - bf2f(hi));
  A[(size_t)s * 2 * 64 * 96 + co * 96 + k] = (short)hi;
  A[(size_t)s * 2 * 64 * 96 + 64 * 96 + co * 96 + k] = (short)lo;
}

// ---------------------------------------------------------------------------
// lift_mfma (R6): MFMA GEMM + fused pool4 + DPP stats reduce.
// ---------------------------------------------------------------------------
__global__ __launch_bounds__(256) void lift_mfma_kernel(
    const unsigned* __restrict__ xpH, const unsigned* __restrict__ xpL,
    const short* __restrict__ Apk1, float* __restrict__ y1,
    float* __restrict__ part1) {
  constexpr int P = 104;
  const int bid = blockIdx.x;
  const int lc = (bid & 7) * 64 + (bid >> 3);  // 512 = 8*64, bijective
  const int s = blockIdx.y;
  const int b = blockIdx.z;
  const int d = 1 << s;
  const int l0 = lc * 64;
  const int tid = threadIdx.x;
  const int lane = tid & 63;
  const int quad = lane >> 4;
  const int n0 = lane & 15;
  const int wv = tid >> 6;
  const int coBase = wv * 16;

  __shared__ __align__(16) short Bh[64 * P];
  __shared__ __align__(16) short Bl[64 * P];
  __shared__ float sCh[2][64];

  const int nB = tid & 63;
  const int rowW = ((nB & 3) << 4) | (nB >> 2);  // LDS row permutation
  const int swzW = (nB & 3) << 3;                // write slot XOR (shorts)
  const int ogu = __builtin_amdgcn_readfirstlane(tid >> 6);
  const unsigned* xqH = xpH + (size_t)(s * 8 + b) * PROW + XPADL + l0;
  const unsigned* xqL = xpL + (size_t)(s * 8 + b) * PROW + XPADL + l0;

#pragma unroll
  for (int r = 0; r < 3; ++r) {
    const int kb = (ogu + 4 * r) * 8;
    const int base = (kb - 39) * d;
    uint4 ph, pl;
    ph.x = xqH[base + nB];
    ph.y = xqH[base + 2 * d + nB];
    ph.z = xqH[base + 4 * d + nB];
    ph.w = xqH[base + 6 * d + nB];
    pl.x = xqL[base + nB];
    pl.y = xqL[base + 2 * d + nB];
    pl.z = xqL[base + 4 * d + nB];
    pl.w = xqL[base + 6 * d + nB];
    *(uint4*)(Bh + rowW * P + (kb ^ swzW)) = ph;
    *(uint4*)(Bl + rowW * P + (kb ^ swzW)) = pl;
  }

  const short* ApkS = Apk1 + (size_t)s * 2 * 64 * 96;
  const short* arowH = ApkS + (coBase + n0) * 96;
  const short* arowL = arowH + 64 * 96;

  __syncthreads();

  f32x4 acc[4];
#pragma unroll
  for (int t = 0; t < 4; ++t) acc[t] = (f32x4){0.f, 0.f, 0.f, 0.f};

#pragma unroll
  for (int ks = 0; ks < 3; ++ks) {
    short8v ah = *(const short8v*)(arowH + ks * 32 + quad * 8);
    short8v al = *(const short8v*)(arowL + ks * 32 + quad * 8);
#pragma unroll
    for (int t = 0; t < 4; ++t) {
      const int n = n0 + 16 * t;
      const int off = (ks * 32 + quad * 8) ^ (t << 3);
      short8v bh = *(const short8v*)(Bh + n * P + off);
      short8v bl = *(const short8v*)(Bl + n * P + off);
      acc[t] = __builtin_amdgcn_mfma_f32_16x16x32_bf16(ah, bh, acc[t], 0, 0, 0);
      acc[t] = __builtin_amdgcn_mfma_f32_16x16x32_bf16(ah, bl, acc[t], 0, 0, 0);
      acc[t] = __builtin_amdgcn_mfma_f32_16x16x32_bf16(al, bh, acc[t], 0, 0, 0);
    }
  }

#pragma unroll
  for (int reg = 0; reg < 4; ++reg) {
    const int co = coBase + quad * 4 + reg;
    float po = fmaxf(fmaxf(acc[0][reg], acc[1][reg]),
                     fmaxf(acc[2][reg], acc[3][reg]));
    const bool valid = (co < 51);
    if (valid) {
      y1[(((size_t)b * 51 + co) * 9 + s) * 8192 + (l0 >> 2) + n0] = po;
    }
    float us = valid ? po : 0.f;
    float sq = us * us;
    us = dpp_radd<0x128>(us);
    sq = dpp_radd<0x128>(sq);
    us = dpp_radd<0x124>(us);
    sq = dpp_radd<0x124>(sq);
    us = dpp_radd<0x122>(us);
    sq = dpp_radd<0x122>(sq);
    us = dpp_radd<0x121>(us);
    sq = dpp_radd<0x121>(sq);
    if (n0 == 0) {
      sCh[0][co] = us;
      sCh[1][co] = sq;
    }
  }
  __syncthreads();
  if (tid < 51) {
    float* pp = part1 + (size_t)lc * 128;
    atomicAdd(&pp[tid], sCh[0][tid]);
    atomicAdd(&pp[64 + tid], sCh[1][tid]);
  }
}

// ---------------------------------------------------------------------------
// Reduce the 512 lc-sliced stats partials into st.
// ---------------------------------------------------------------------------
__global__ __launch_bounds__(128) void reduce_stats1_kernel(
    const float* __restrict__ p, float* __restrict__ st) {
  const int t = threadIdx.x;
  if (t >= 102) return;
  const int k0 = blockIdx.x * 64;
  const int off = (t < 51) ? t : (64 + t - 51);
  float s = 0.f;
  for (int k = k0; k < k0 + 64; ++k) s += p[k * 128 + off];
  atomicAdd(&st[(t < 51) ? t : (512 + t - 51)], s);
}

// ---------------------------------------------------------------------------
// Per-channel sum/sumsq over [B,C,HL], HL split NS ways; grid (C,B,NS)
// ---------------------------------------------------------------------------
__global__ __launch_bounds__(256) void stats_kernel(
    const float* __restrict__ Y, float* __restrict__ st, int C, int HL,
    int NS) {
  const int c = blockIdx.x, b = blockIdx.y, z = blockIdx.z;
  const int slice = HL / NS;
  const float* p = Y + ((size_t)b * C + c) * HL + (size_t)z * slice;
  float s = 0.f, q = 0.f;
  for (int i = threadIdx.x; i < slice; i += 256) {
    float v = p[i];
    s += v;
    q += v * v;
  }
#pragma unroll
  for (int off = 32; off > 0; off >>= 1) {
    s += __shfl_down(s, off, 64);
    q += __shfl_down(q, off, 64);
  }
  __shared__ float ls[4], lq[4];
  const int wid = threadIdx.x >> 6, lane = threadIdx.x & 63;
  if (lane == 0) { ls[wid] = s; lq[wid] = q; }
  __syncthreads();
  if (threadIdx.x == 0) {
    atomicAdd(&st[c], ls[0] + ls[1] + ls[2] + ls[3]);
    atomicAdd(&st[512 + c], lq[0] + lq[1] + lq[2] + lq[3]);
  }
}

// ---------------------------------------------------------------------------
// reduce NS partial buffers: y[i] = sum_k p[k*stride + i]
// ---------------------------------------------------------------------------
__global__ __launch_bounds__(256) void reduce_parts_kernel(
    const float* __restrict__ p, float* __restrict__ y, int n, int stride,
    int ns) {
  int i = blockIdx.x * 256 + threadIdx.x;
  if (i >= n) return;
  float s = 0.f;
  for (int k = 0; k < ns; ++k) s += p[(size_t)k * stride + i];
  y[i] = s;
}

// ---------------------------------------------------------------------------
// BN(train)+ReLU+pool4, fp32 out
// ---------------------------------------------------------------------------
__global__ __launch_bounds__(256) void bnrelu_pool_kernel(
    const float* __restrict__ Y, const float* __restrict__ st,
    const float* __restrict__ g, const float* __restrict__ bb,
    float* __restrict__ Z, int C, int H, int Lin, float invN,
    unsigned int total) {
  unsigned int idx = blockIdx.x * 256u + threadIdx.x;
  if (idx >= total) return;
  const unsigned int Lo = (unsigned int)(Lin >> 2);
  unsigned int lo = idx % Lo;
  unsigned int r1 = idx / Lo;
  unsigned int h = r1 % (unsigned int)H;
  unsigned int r2 = r1 / (unsigned int)H;
  unsigned int c = r2 % (unsigned int)C;
  unsigned int b = r2 / (unsigned int)C;
  float m = st[c] * invN;
  float v = st[512 + c] * invN - m * m;
  float sc = g[c] * rsqrtf(v + EPSBN);
  float bi = bb[c] - m * sc;
  const float* p = Y + (((size_t)b * C + c) * H + h) * Lin + 4u * lo;
  float a0 = p[0] * sc + bi, a1 = p[1] * sc + bi;
  float a2 = p[2] * sc + bi, a3 = p[3] * sc + bi;
  float r = fmaxf(fmaxf(a0, a1), fmaxf(a2, a3));
  Z[idx] = fmaxf(r, 0.f);
}

// ---- same, bf16 out
__global__ __launch_bounds__(256) void bnrelu_pool_bf16_kernel(
    const float* __restrict__ Y, const float* __restrict__ st,
    const float* __restrict__ g, const float* __restrict__ bb,
    unsigned short* __restrict__ Z, int C, int H, int Lin, float invN,
    unsigned int total) {
  unsigned int idx = blockIdx.x * 256u + threadIdx.x;
  if (idx >= total) return;
  const unsigned int Lo = (unsigned int)(Lin >> 2);
  unsigned int lo = idx % Lo;
  unsigned int r1 = idx / Lo;
  unsigned int h = r1 % (unsigned int)H;
  unsigned int r2 = r1 / (unsigned int)H;
  unsigned int c = r2 % (unsigned int)C;
  unsigned int b = r2 / (unsigned int)C;
  float m = st[c] * invN;
  float v = st[512 + c] * invN - m * m;
  float sc = g[c] * rsqrtf(v + EPSBN);
  float bi = bb[c] - m * sc;
  const float* p = Y + (((size_t)b * C + c) * H + h) * Lin + 4u * lo;
  float a0 = p[0] * sc + bi, a1 = p[1] * sc + bi;
  float a2 = p[2] * sc + bi, a3 = p[3] * sc + bi;
  float r = fmaxf(fmaxf(a0, a1), fmaxf(a2, a3));
  Z[idx] = f2bf(fmaxf(r, 0.f));
}

// ---------------------------------------------------------------------------
// BN(train)+ReLU elementwise, fp32 / bf16 out
// ---------------------------------------------------------------------------
__global__ __launch_bounds__(256) void bnrelu_kernel(
    const float* __restrict__ Y, const float* __restrict__ st,
    const float* __restrict__ g, const float* __restrict__ bb,
    float* __restrict__ A, int C, int HL, float invN, unsigned int total) {
  unsigned int idx = blockIdx.x * 256u + threadIdx.x;
  if (idx >= total) return;
  unsigned int c = (idx / (unsigned int)HL) % (unsigned int)C;
  float m = st[c] * invN;
  float v = st[512 + c] * invN - m * m;
  float sc = g[c] * rsqrtf(v + EPSBN);
  float bi = bb[c] - m * sc;
  A[idx] = fmaxf(fmaf(Y[idx], sc, bi), 0.f);
}

__global__ __launch_bounds__(256) void bnrelu_bf16_kernel(
    const float* __restrict__ Y, const float* __restrict__ st,
    const float* __restrict__ g, const float* __restrict__ bb,
    unsigned short* __restrict__ A, int C, int HL, float invN,
    unsigned int total) {
  unsigned int idx = blockIdx.x * 256u + threadIdx.x;
  if (idx >= total) return;
  unsigned int c = (idx / (unsigned int)HL) % (unsigned int)C;
  float m = st[c] * invN;
  float v = st[512 + c] * invN - m * m;
  float sc = g[c] * rsqrtf(v + EPSBN);
  float bi = bb[c] - m * sc;
  A[idx] = f2bf(fmaxf(fmaf(Y[idx], sc, bi), 0.f));
}

// ---------------------------------------------------------------------------
// Pack fp32 weights -> per-s split bf16 packs with 2^-(s+i) folded.
// ---------------------------------------------------------------------------
__global__ __launch_bounds__(256) void pack_w2_kernel(
    const float* __restrict__ W, short* __restrict__ A, int Co, int KTOT,
    int KPAD, int COPAD, int NS, int nk3) {
  int idx = blockIdx.x * 256 + threadIdx.x;
  const int CK = COPAD * KPAD;
  if (idx >= NS * CK) return;
  int s = idx / CK;
  int rem = idx - s * CK;
  int co = rem / KPAD;
  int kk = rem - co * KPAD;
  float v = 0.f;
  if (co < Co && kk < KTOT) {
    int i = (kk % nk3) / 3;
    float scale = __uint_as_float((unsigned)(127 - (s + i)) << 23);
    v = W[co * KTOT + kk] * scale;
  }
  unsigned short hi = f2bf(v);
  unsigned short lo = f2bf(v - bf2f(hi));
  A[(size_t)s * 2 * CK + co * KPAD + kk] = (short)hi;
  A[(size_t)s * 2 * CK + CK + co * KPAD + kk] = (short)lo;
}

// ---------------------------------------------------------------------------
// gg_mfma5: bf16-input MFMA GConvGG, no fused stats (R15, unchanged)
// ---------------------------------------------------------------------------
template <int NKv, int LT>
__global__ __launch_bounds__(256) void gg_mfma5_kernel(
    const unsigned short* __restrict__ X, const short* __restrict__ Apk,
    float* __restrict__ Y, int Ci, int Co, int Hin, int L, int nL, int KTOT,
    int KPAD, int COPAD) {
  constexpr int T = LT / 16;
  constexpr int KO = 256 / LT;
  constexpr int RIT = 8 / KO;

  const int bx = blockIdx.x;
  const int lc = bx % nL;
  const int cog = bx / nL;
  const int s = blockIdx.y;
  const int b = blockIdx.z;
  const int Hout = Hin - NKv + 1;
  const int l0 = lc * LT;
  const int tid = threadIdx.x;
  const int lane = tid & 63;
  const int quad = lane >> 4;
  const int m0 = lane & 15;
  const int wv = tid >> 6;
  const int coBase = cog * 64 + wv * 16;

  __shared__ __align__(16) short Bh[LT * 72];
  __shared__ int roT[512];
  __shared__ int shT[512];

  for (int kk = tid; kk < KPAD; kk += 256) {
    int ro = 0, sh = -(1 << 30);
    if (kk < KTOT) {
      int ci = kk / (3 * NKv);
      int rem = kk - ci * (3 * NKv);
      int i = rem / 3;
      int k = rem - 3 * i;
      ro = (ci * Hin + s + i) * L;
      sh = (k - 1) * (1 << (s + i));
    }
    roT[kk] = ro;
    shT[kk] = sh;
  }
  __syncthreads();

  f32x4 acc[T];
#pragma unroll
  for (int t = 0; t < T; ++t) acc[t] = (f32x4){0.f, 0.f, 0.f, 0.f};

  const short* ApkS = Apk + (size_t)s * 2 * COPAD * KPAD;
  const short* arowH = ApkS + (size_t)(coBase + m0) * KPAD;
  const short* arowL = arowH + (size_t)COPAD * KPAD;
  const unsigned short* Xb = X + (size_t)b * Ci * Hin * L;

  const int lB = tid & (LT - 1);
  const int oc0 = tid / LT;
  const int nch = (KTOT + 63) >> 6;

  uint4 v0[RIT], v1[RIT], v2[RIT];
  auto gather = [&](int c0, uint4 (&pk)[RIT]) {
#pragma unroll
    for (int r = 0; r < RIT; ++r) {
      const int oct = oc0 + KO * r;
      const int kkb = (c0 << 6) + oct * 8;
      unsigned w[8];
#pragma unroll
      for (int j = 0; j < 8; ++j) {
        const int kk = kkb + j;
        const int pos = l0 + lB + shT[kk];
        const int posc = min(max(pos, 0), L - 1);
        unsigned u = (unsigned)Xb[roT[kk] + posc];
        w[j] = ((unsigned)pos < (unsigned)L) ? u : 0u;
      }
      pk[r].x = w[0] | (w[1] << 16);
      pk[r].y = w[2] | (w[3] << 16);
      pk[r].z = w[4] | (w[5] << 16);
      pk[r].w = w[6] | (w[7] << 16);
    }
  };

  gather(0, v0);
  if (nch > 1) gather(1, v1);
  for (int c0 = 0; c0 < nch; ++c0) {
#pragma unroll
    for (int r = 0; r < RIT; ++r)
      *(uint4*)(Bh + lB * 72 + (oc0 + KO * r) * 8) = v0[r];
    if (c0 + 2 < nch) gather(c0 + 2, v2);
    const int a0 = (c0 << 6) + quad * 8;
    short8v ah0 = *(const short8v*)(arowH + a0);
    short8v al0 = *(const short8v*)(arowL + a0);
    short8v ah1 = *(const short8v*)(arowH + a0 + 32);
    short8v al1 = *(const short8v*)(arowL + a0 + 32);
    __syncthreads();
#pragma unroll
    for (int t = 0; t < T; ++t) {
      const int l = m0 + 16 * t;
      short8v b0 = *(const short8v*)(Bh + l * 72 + quad * 8);
      short8v b1 = *(const short8v*)(Bh + l * 72 + 32 + quad * 8);
      acc[t] = __builtin_amdgcn_mfma_f32_16x16x32_bf16(ah0, b0, acc[t], 0, 0, 0);
      acc[t] = __builtin_amdgcn_mfma_f32_16x16x32_bf16(al0, b0, acc[t], 0, 0, 0);
      acc[t] = __builtin_amdgcn_mfma_f32_16x16x32_bf16(ah1, b1, acc[t], 0, 0, 0);
      acc[t] = __builtin_amdgcn_mfma_f32_16x16x32_bf16(al1, b1, acc[t], 0, 0, 0);
    }
    __syncthreads();
#pragma unroll
    for (int r = 0; r < RIT; ++r) {
      v0[r] = v1[r];
      v1[r] = v2[r];
    }
  }

#pragma unroll
  for (int reg = 0; reg < 4; ++reg) {
    const int co = coBase + quad * 4 + reg;
    if (co < Co) {
      float* yp = Y + (((size_t)b * Co + co) * Hout + s) * L + l0;
#pragma unroll
      for (int t = 0; t < T; ++t) yp[m0 + 16 * t] = acc[t][reg];
    }
  }
}

// ---------------------------------------------------------------------------
// gg_tail4: software-pipelined tail GConvGG.
// Register double-buffer (A/B batches, static indexing): batch k+1's X AND
// W loads issue before batch k's FMA phase, so the fmaf chain is
// pure-register and global latency hides under compute+issue of the
// neighboring batch. Replaces gg_tail3, whose FMA phase re-loaded weights
// from global per link (R6: VALUBusy 26.6%, all pipes idle, 152 µs).
// ---------------------------------------------------------------------------
template <int NK, int L, int COSUB, int UN>
__global__ __launch_bounds__(256) void gg_tail4_kernel(
    const float* __restrict__ X, const float* __restrict__ W,
    float* __restrict__ Y, int Ci, int Co, int Hin, int NSPLIT, int ciPer,
    int partStride) {
  const int l = threadIdx.x % L;
  const int cs = threadIdx.x / L;
  const int co = blockIdx.x * COSUB + cs;
  const int s = blockIdx.y / NSPLIT;
  const int seg = blockIdx.y % NSPLIT;
  const int b = blockIdx.z;
  const int Hout = Hin - NK + 1;
  const int ciBeg = seg * ciPer;
  const int ciEnd = min(Ci, ciBeg + ciPer);

  float acc[NK];
#pragma unroll
  for (int i = 0; i < NK; ++i) acc[i] = 0.f;

  const float* wbase = W + (size_t)co * Ci * NK * 3;
  const float* xbase = X + ((size_t)b * Ci * Hin + s) * L;

  float xA[UN][NK][3], wA[UN][NK][3];
  float xB[UN][NK][3], wB[UN][NK][3];

  auto loadB = [&](int ci0, float (&xv)[UN][NK][3], float (&wv)[UN][NK][3]) {
#pragma unroll
    for (int u = 0; u < UN; ++u) {
      const float* xr = xbase + (size_t)(ci0 + u) * (Hin * L);
      const float* wp = wbase + (ci0 + u) * (NK * 3);
#pragma unroll
      for (int i = 0; i < NK; ++i) {
        const int d = 1 << (s + i);
        const float* row = xr + i * L;
        xv[u][i][0] = (l >= d) ? row[l - d] : 0.f;
        xv[u][i][1] = row[l];
        xv[u][i][2] = (l + d < L) ? row[l + d] : 0.f;
        wv[u][i][0] = wp[3 * i];
        wv[u][i][1] = wp[3 * i + 1];
        wv[u][i][2] = wp[3 * i + 2];
      }
    }
  };
  auto fmaB = [&](const float (&xv)[UN][NK][3], const float (&wv)[UN][NK][3]) {
#pragma unroll
    for (int u = 0; u < UN; ++u)
#pragma unroll
      for (int i = 0; i < NK; ++i)
        acc[i] = fmaf(wv[u][i][0], xv[u][i][0],
                      fmaf(wv[u][i][1], xv[u][i][1],
                           fmaf(wv[u][i][2], xv[u][i][2], acc[i])));
  };

  int ci = ciBeg;
  const int nb = (ciEnd - ciBeg) / UN;
  if (nb > 0) {
    loadB(ci, xA, wA);
    int k = 1;
    for (; k + 1 < nb; k += 2) {
      loadB(ci + k * UN, xB, wB);
      fmaB(xA, wA);
      loadB(ci + (k + 1) * UN, xA, wA);
      fmaB(xB, wB);
    }
    if (k < nb) {
      loadB(ci + k * UN, xB, wB);
      fmaB(xA, wA);
      fmaB(xB, wB);
    } else {
      fmaB(xA, wA);
    }
    ci += nb * UN;
  }
  for (; ci < ciEnd; ++ci) {
    const float* xr = xbase + (size_t)ci * (Hin * L);
    const float* wp = wbase + ci * (NK * 3);
#pragma unroll
    for (int i = 0; i < NK; ++i) {
      const int d = 1 << (s + i);
      const float* row = xr + i * L;
      float xm = (l >= d) ? row[l - d] : 0.f;
      float xc = row[l];
      float xp = (l + d < L) ? row[l + d] : 0.f;
      acc[i] = fmaf(wp[3 * i], xm,
                    fmaf(wp[3 * i + 1], xc, fmaf(wp[3 * i + 2], xp, acc[i])));
    }
  }
  float out = 0.f;
#pragma unroll
  for (int i = 0; i < NK; ++i) {
    float invd = __uint_as_float((unsigned)(127 - (s + i)) << 23);
    out = fmaf(acc[i], invd, out);
  }
  Y[(size_t)seg * partStride + (((size_t)b * Co + co) * Hout + s) * L + l] =
      out;
}

// ---------------------------------------------------------------------------
// Final: bn10+relu, mean over L, classifier
// ---------------------------------------------------------------------------
__global__ __launch_bounds__(256) void final_kernel(
    const float* __restrict__ Y, const float* __restrict__ st,
    const float* __restrict__ g, const float* __restrict__ bb,
    const float* __restrict__ w11, float* __restrict__ out) {
  const int b = blockIdx.x;
  const int tid = threadIdx.x;
  __shared__ float tch[408];
  for (int c = tid; c < 408; c += 256) {
    float m = st[c] * (1.f / 256.f);
    float v = st[512 + c] * (1.f / 256.f) - m * m;
    float sc = g[c] * rsqrtf(v + EPSBN);
    float bi = bb[c] - m * sc;
    const float* p = Y + ((size_t)b * 408 + c) * 32;
    float ssum = 0.f;
#pragma unroll
    for (int l = 0; l < 32; ++l) ssum += fmaxf(p[l] * sc + bi, 0.f);
    tch[c] = ssum * (1.f / 32.f);
  }
  __syncthreads();
  if (tid < 10) {
    float ssum = 0.f;
    for (int c = 0; c < 408; ++c) ssum += w11[tid * 408 + c] * tch[c];
    out[b * 10 + tid] = ssum;
  }
}

// ---------------------------------------------------------------------------
extern "C" void kernel_launch(void* const* d_in, const int* in_sizes, int n_in,
                              void* d_out, int out_size, void* d_ws,
                              size_t ws_size, hipStream_t stream) {
  const float* x = (const float*)d_in[0];
  const float* w1 = (const float*)d_in[1];
  const float* w2 = (const float*)d_in[2];
  const float* w3 = (const float*)d_in[3];
  const float* w4 = (const float*)d_in[4];
  const float* w5 = (const float*)d_in[5];
  const float* w6 = (const float*)d_in[6];
  const float* w7 = (const float*)d_in[7];
  const float* w8 = (const float*)d_in[8];
  const float* w9 = (const float*)d_in[9];
  const float* w10 = (const float*)d_in[10];
  const float* w11 = (const float*)d_in[11];
  const float* gg[11];
  const float* bbv[11];
  for (int i = 1; i <= 10; ++i) {
    gg[i] = (const float*)d_in[12 + 2 * (i - 1)];
    bbv[i] = (const float*)d_in[12 + 2 * (i - 1) + 1];
  }

  float* ws = (float*)d_ws;
  const size_t AR0 = 0;
  const size_t AR1 = 30081024;
  const size_t STATS = 38900000;
  float* y1 = ws + AR0;
  unsigned* xpad = (unsigned*)(ws + AR1);                 // 456704 dw
  short* apk1 = (short*)(ws + AR1 + 460800);              // 110592 shorts
  unsigned* xpairH = (unsigned*)(ws + AR1 + 520000);      // 4110336 dw
  unsigned* xpairL = (unsigned*)(ws + AR1 + 4630336);     // 4110336 dw
  float* part1 = ws + AR1 + 8740672;                      // 512*128 fp32
  unsigned short* z1b = (unsigned short*)(ws + AR1);
  unsigned short* a3b = (unsigned short*)(ws + AR1);
  unsigned short* z3b = (unsigned short*)(ws + AR1);
  unsigned short* a5b = (unsigned short*)(ws + AR1 + 1500000);
  float* z5 = ws + AR1;
  float* a6 = ws + AR1 + 522240;
  float* a7 = ws + AR1 + 1148928;
  float* z8 = ws + AR1;
  float* a9 = ws + AR1 + 1775616;
  float* part9 = ws + AR1 + 1900000;   // 4 * 104448
  float* part10 = ws + AR1 + 2400000;  // 4 * 104448
  float* y2 = ws + AR0;
  float* y3 = ws + AR0 + 5849088;
  float* y4 = ws + AR0;
  float* y5 = ws + AR0 + 2088960;
  float* y6 = ws + AR0;
  float* y7 = ws + AR0 + 626688;
  float* y8 = ws + AR0 + 1253376;
  float* y9 = ws + AR0;
  float* y10 = ws + AR0 + 104448;
  short* apk2 = (short*)(ws + 12000000);
  short* apk3 = apk2 + 7 * 2 * 64 * 512;
  short* apk4 = apk3 + 7 * 2 * 64 * 192;
  short* apk5 = apk4 + 5 * 2 * 128 * 512;
  float* st[11];
  for (int i = 1; i <= 10; ++i) st[i] = ws + STATS + (size_t)(i - 1) * 1024;

  hipMemsetAsync((void*)(ws + STATS), 0, 10 * 1024 * sizeof(float), stream);
  hipMemsetAsync((void*)part1, 0, 512 * 128 * sizeof(float), stream);

  // ---- pad x (packed split-bf16), per-s pair arrays, pack w1, MFMA lift
  pad_x_kernel<<<(8 * PROW + 255) / 256, 256, 0, stream>>>(x, xpad);
  pad_pair_kernel<<<dim3((PROW + 255) / 256, 72), 256, 0, stream>>>(
      xpad, xpairH, xpairL);
  pack_w1_kernel<<<(9 * 64 * 96 + 255) / 256, 256, 0, stream>>>(w1, apk1);
  lift_mfma_kernel<<<dim3(512, 9, 8), 256, 0, stream>>>(xpairH, xpairL, apk1,
                                                        y1, part1);
  reduce_stats1_kernel<<<8, 128, 0, stream>>>(part1, st[1]);
  {
    unsigned int tot = 8u * 51 * 9 * 2048;
    bnrelu_pool_bf16_kernel<<<(tot + 255) / 256, 256, 0, stream>>>(
        y1, st[1], gg[1], bbv[1], z1b, 51, 9, 8192, 1.f / 589824.f, tot);
  }
  // ---- per-s weight packs
  pack_w2_kernel<<<(7 * 64 * 512 + 255) / 256, 256, 0, stream>>>(
      w2, apk2, 51, 459, 512, 64, 7, 9);
  pack_w2_kernel<<<(7 * 64 * 192 + 255) / 256, 256, 0, stream>>>(
      w3, apk3, 51, 153, 192, 64, 7, 3);
  pack_w2_kernel<<<(5 * 128 * 512 + 255) / 256, 256, 0, stream>>>(
      w4, apk4, 102, 459, 512, 128, 5, 9);
  pack_w2_kernel<<<(5 * 128 * 320 + 255) / 256, 256, 0, stream>>>(
      w5, apk5, 102, 306, 320, 128, 5, 3);
  // ---- gg2: 51->51, H 9->7, L=2048
  gg_mfma5_kernel<3, 64><<<dim3(32, 7, 8), 256, 0, stream>>>(
      z1b, apk2, y2, 51, 51, 9, 2048, 32, 459, 512, 64);
  stats_kernel<<<dim3(51, 8, 4), 256, 0, stream>>>(y2, st[2], 51, 7 * 2048, 4);
  {
    unsigned int tot = 8u * 51 * 7 * 2048;
    bnrelu_bf16_kernel<<<(tot + 255) / 256, 256, 0, stream>>>(
        y2, st[2], gg[2], bbv[2], a3b, 51, 7 * 2048, 1.f / 114688.f, tot);
  }
  // ---- gg3: 51->51, H7, L=2048
  gg_mfma5_kernel<1, 64><<<dim3(32, 7, 8), 256, 0, stream>>>(
      a3b, apk3, y3, 51, 51, 7, 2048, 32, 153, 192, 64);
  stats_kernel<<<dim3(51, 8, 4), 256, 0, stream>>>(y3, st[3], 51, 7 * 2048, 4);
  {
    unsigned int tot = 8u * 51 * 7 * 512;
    bnrelu_pool_bf16_kernel<<<(tot + 255) / 256, 256, 0, stream>>>(
        y3, st[3], gg[3], bbv[3], z3b, 51, 7, 2048, 1.f / 114688.f, tot);
  }
  // ---- gg4: 51->102, H 7->5, L=512
  gg_mfma5_kernel<3, 32><<<dim3(32, 5, 8), 256, 0, stream>>>(
      z3b, apk4, y4, 51, 102, 7, 512, 16, 459, 512, 128);
  stats_kernel<<<dim3(102, 8, 2), 256, 0, stream>>>(y4, st[4], 102, 5 * 512,
                                                    2);
  {
    unsigned int tot = 8u * 102 * 5 * 512;
    bnrelu_bf16_kernel<<<(tot + 255) / 256, 256, 0, stream>>>(
        y4, st[4], gg[4], bbv[4], a5b, 102, 5 * 512, 1.f / 20480.f, tot);
  }
  // ---- gg5: 102->102, H5, L=512
  gg_mfma5_kernel<1, 32><<<dim3(32, 5, 8), 256, 0, stream>>>(
      a5b, apk5, y5, 102, 102, 5, 512, 16, 306, 320, 128);
  stats_kernel<<<dim3(102, 8, 2), 256, 0, stream>>>(y5, st[5], 102, 5 * 512,
                                                    2);
  {
    unsigned int tot = 8u * 102 * 5 * 128;
    bnrelu_pool_kernel<<<(tot + 255) / 256, 256, 0, stream>>>(
        y5, st[5], gg[5], bbv[5], z5, 102, 5, 512, 1.f / 20480.f, tot);
  }
  // ---- gg6: 102->204, H 5->3, L=128 (pipelined, direct store)
  gg_tail4_kernel<3, 128, 2, 2><<<dim3(102, 3, 8), 256, 0, stream>>>(
      z5, w6, y6, 102, 204, 5, 1, 102, 0);
  stats_kernel<<<dim3(204, 8, 1), 256, 0, stream>>>(y6, st[6], 204, 384, 1);
  {
    unsigned int tot = 8u * 204 * 3 * 128;
    bnrelu_kernel<<<(tot + 255) / 256, 256, 0, stream>>>(
        y6, st[6], gg[6], bbv[6], a6, 204, 3 * 128, 1.f / 3072.f, tot);
  }
  // ---- gg7: 204->204, H3, L=128
  gg_tail4_kernel<1, 128, 2, 4><<<dim3(102, 3, 8), 256, 0, stream>>>(
      a6, w7, y7, 204, 204, 3, 1, 204, 0);
  stats_kernel<<<dim3(204, 8, 1), 256, 0, stream>>>(y7, st[7], 204, 384, 1);
  {
    unsigned int tot = 8u * 204 * 3 * 128;
    bnrelu_kernel<<<(tot + 255) / 256, 256, 0, stream>>>(
        y7, st[7], gg[7], bbv[7], a7, 204, 3 * 128, 1.f / 3072.f, tot);
  }
  // ---- gg8: 204->204, H3, L=128
  gg_tail4_kernel<1, 128, 2, 4><<<dim3(102, 3, 8), 256, 0, stream>>>(
      a7, w8, y8, 204, 204, 3, 1, 204, 0);
  stats_kernel<<<dim3(204, 8, 1), 256, 0, stream>>>(y8, st[8], 204, 384, 1);
  {
    unsigned int tot = 8u * 204 * 3 * 32;
    bnrelu_pool_kernel<<<(tot + 255) / 256, 256, 0, stream>>>(
        y8, st[8], gg[8], bbv[8], z8, 204, 3, 128, 1.f / 3072.f, tot);
  }
  // ---- gg9: 204->408, H 3->1, L=32 (K-split x4 into partials, reduce)
  gg_tail4_kernel<3, 32, 8, 2><<<dim3(51, 4, 8), 256, 0, stream>>>(
      z8, w9, part9, 204, 408, 3, 4, 51, 104448);
  reduce_parts_kernel<<<(104448 + 255) / 256, 256, 0, stream>>>(
      part9, y9, 104448, 104448, 4);
  stats_kernel<<<dim3(408, 8, 1), 256, 0, stream>>>(y9, st[9], 408, 32, 1);
  {
    unsigned int tot = 8u * 408 * 32;
    bnrelu_kernel<<<(tot + 255) / 256, 256, 0, stream>>>(
        y9, st[9], gg[9], bbv[9], a9, 408, 32, 1.f / 256.f, tot);
  }
  // ---- gg10: 408->408, H1, L=32 (K-split x4 into partials, reduce)
  gg_tail4_kernel<1, 32, 8, 4><<<dim3(51, 4, 8), 256, 0, stream>>>(
      a9, w10, part10, 408, 408, 1, 4, 102, 104448);
  reduce_parts_kernel<<<(104448 + 255) / 256, 256, 0, stream>>>(
      part10, y10, 104448, 104448, 4);
  stats_kernel<<<dim3(408, 8, 1), 256, 0, stream>>>(y10, st[10], 408, 32, 1);
  // ---- final
  final_kernel<<<dim3(8), 256, 0, stream>>>(y10, st[10], gg[10], bbv[10], w11,
                                            (float*)d_out);
}

// Round 8
// 686.681 us; speedup vs baseline: 1.6270x; 1.4175x over previous
//
#include <hip/hip_runtime.h>
#include <hip/hip_bf16.h>

#define EPSBN 2e-5f

typedef __attribute__((ext_vector_type(8))) short short8v;
typedef __attribute__((ext_vector_type(4))) float f32x4;

__device__ inline unsigned short f2bf(float f) {
  unsigned u = __float_as_uint(f);
  unsigned r = (u + 0x7FFFu + ((u >> 16) & 1u)) >> 16;
  return (unsigned short)r;
}
__device__ inline float bf2f(unsigned short h) {
  return __uint_as_float(((unsigned)h) << 16);
}

// DPP row-rotate float add: v += rotate_within_16(v, N). VALU pipe, not LDS.
template <int CTRL>
__device__ inline float dpp_radd(float v) {
  int r = __builtin_amdgcn_update_dpp(0, __float_as_int(v), CTRL, 0xf, 0xf,
                                      true);
  return v + __int_as_float(r);
}

// ---------------------------------------------------------------------------
// Padded x staging — packed split-bf16: (hi16 << 16) | lo16.
// ---------------------------------------------------------------------------
constexpr int XPADL = 9984;
constexpr int XPADR = 14336;
constexpr int PROW = XPADL + 32768 + XPADR;  // 57088

__global__ __launch_bounds__(256) void pad_x_kernel(const float* __restrict__ x,
                                                    unsigned* __restrict__ xp) {
  int i = blockIdx.x * 256 + threadIdx.x;
  if (i >= 8 * PROW) return;
  int b = i / PROW;
  int pos = i - b * PROW - XPADL;
  float v = (pos >= 0 && pos < 32768) ? x[b * 32768 + pos] : 0.f;
  unsigned u = __float_as_uint(v);
  unsigned h = u >> 16;
  float lof = v - __uint_as_float(u & 0xffff0000u);
  unsigned lo = __float_as_uint(lof) >> 16;
  xp[i] = (h << 16) | lo;
}

// ---------------------------------------------------------------------------
// Per-scale pair-packed B source
// ---------------------------------------------------------------------------
__global__ __launch_bounds__(256) void pad_pair_kernel(
    const unsigned* __restrict__ xp, unsigned* __restrict__ xpH,
    unsigned* __restrict__ xpL) {
  const int i = blockIdx.x * 256 + threadIdx.x;
  if (i >= PROW) return;
  const int sb = blockIdx.y;  // s*8 + b
  const int s = sb >> 3;
  const int b = sb & 7;
  const int d = 1 << s;
  const unsigned* row = xp + b * PROW;
  unsigned u0 = row[i];
  unsigned u1 = (i + d < PROW) ? row[i + d] : 0u;
  size_t o = (size_t)sb * PROW + i;
  xpH[o] = (u0 >> 16) | (u1 & 0xffff0000u);
  xpL[o] = (u0 & 0xffffu) | (u1 << 16);
}

// ---------------------------------------------------------------------------
// Pack w1 [51][79] -> per-s split bf16 (1/2^s folded), [s][hi/lo][64][96]
// ---------------------------------------------------------------------------
__global__ __launch_bounds__(256) void pack_w1_kernel(
    const float* __restrict__ W, short* __restrict__ A) {
  int idx = blockIdx.x * 256 + threadIdx.x;
  if (idx >= 9 * 64 * 96) return;
  int s = idx / (64 * 96);
  int rem = idx - s * 64 * 96;
  int co = rem / 96;
  int k = rem - co * 96;
  float v = 0.f;
  if (co < 51 && k < 79)
    v = W[co * 79 + k] * __uint_as_float((unsigned)(127 - s) << 23);
  unsigned short hi = f2bf(v);
  unsigned short lo = f2bf(v - bf2f(hi));
  A[(size_t)s * 2 * 64 * 96 + co * 96 + k] = (short)hi;
  A[(size_t)s * 2 * 64 * 96 + 64 * 96 + co * 96 + k] = (short)lo;
}

// ---------------------------------------------------------------------------
// lift_mfma (R6): MFMA GEMM + fused pool4 + DPP stats reduce.
// ---------------------------------------------------------------------------
__global__ __launch_bounds__(256) void lift_mfma_kernel(
    const unsigned* __restrict__ xpH, const unsigned* __restrict__ xpL,
    const short* __restrict__ Apk1, float* __restrict__ y1,
    float* __restrict__ part1) {
  constexpr int P = 104;
  const int bid = blockIdx.x;
  const int lc = (bid & 7) * 64 + (bid >> 3);  // 512 = 8*64, bijective
  const int s = blockIdx.y;
  const int b = blockIdx.z;
  const int d = 1 << s;
  const int l0 = lc * 64;
  const int tid = threadIdx.x;
  const int lane = tid & 63;
  const int quad = lane >> 4;
  const int n0 = lane & 15;
  const int wv = tid >> 6;
  const int coBase = wv * 16;

  __shared__ __align__(16) short Bh[64 * P];
  __shared__ __align__(16) short Bl[64 * P];
  __shared__ float sCh[2][64];

  const int nB = tid & 63;
  const int rowW = ((nB & 3) << 4) | (nB >> 2);  // LDS row permutation
  const int swzW = (nB & 3) << 3;                // write slot XOR (shorts)
  const int ogu = __builtin_amdgcn_readfirstlane(tid >> 6);
  const unsigned* xqH = xpH + (size_t)(s * 8 + b) * PROW + XPADL + l0;
  const unsigned* xqL = xpL + (size_t)(s * 8 + b) * PROW + XPADL + l0;

#pragma unroll
  for (int r = 0; r < 3; ++r) {
    const int kb = (ogu + 4 * r) * 8;
    const int base = (kb - 39) * d;
    uint4 ph, pl;
    ph.x = xqH[base + nB];
    ph.y = xqH[base + 2 * d + nB];
    ph.z = xqH[base + 4 * d + nB];
    ph.w = xqH[base + 6 * d + nB];
    pl.x = xqL[base + nB];
    pl.y = xqL[base + 2 * d + nB];
    pl.z = xqL[base + 4 * d + nB];
    pl.w = xqL[base + 6 * d + nB];
    *(uint4*)(Bh + rowW * P + (kb ^ swzW)) = ph;
    *(uint4*)(Bl + rowW * P + (kb ^ swzW)) = pl;
  }

  const short* ApkS = Apk1 + (size_t)s * 2 * 64 * 96;
  const short* arowH = ApkS + (coBase + n0) * 96;
  const short* arowL = arowH + 64 * 96;

  __syncthreads();

  f32x4 acc[4];
#pragma unroll
  for (int t = 0; t < 4; ++t) acc[t] = (f32x4){0.f, 0.f, 0.f, 0.f};

#pragma unroll
  for (int ks = 0; ks < 3; ++ks) {
    short8v ah = *(const short8v*)(arowH + ks * 32 + quad * 8);
    short8v al = *(const short8v*)(arowL + ks * 32 + quad * 8);
#pragma unroll
    for (int t = 0; t < 4; ++t) {
      const int n = n0 + 16 * t;
      const int off = (ks * 32 + quad * 8) ^ (t << 3);
      short8v bh = *(const short8v*)(Bh + n * P + off);
      short8v bl = *(const short8v*)(Bl + n * P + off);
      acc[t] = __builtin_amdgcn_mfma_f32_16x16x32_bf16(ah, bh, acc[t], 0, 0, 0);
      acc[t] = __builtin_amdgcn_mfma_f32_16x16x32_bf16(ah, bl, acc[t], 0, 0, 0);
      acc[t] = __builtin_amdgcn_mfma_f32_16x16x32_bf16(al, bh, acc[t], 0, 0, 0);
    }
  }

#pragma unroll
  for (int reg = 0; reg < 4; ++reg) {
    const int co = coBase + quad * 4 + reg;
    float po = fmaxf(fmaxf(acc[0][reg], acc[1][reg]),
                     fmaxf(acc[2][reg], acc[3][reg]));
    const bool valid = (co < 51);
    if (valid) {
      y1[(((size_t)b * 51 + co) * 9 + s) * 8192 + (l0 >> 2) + n0] = po;
    }
    float us = valid ? po : 0.f;
    float sq = us * us;
    us = dpp_radd<0x128>(us);
    sq = dpp_radd<0x128>(sq);
    us = dpp_radd<0x124>(us);
    sq = dpp_radd<0x124>(sq);
    us = dpp_radd<0x122>(us);
    sq = dpp_radd<0x122>(sq);
    us = dpp_radd<0x121>(us);
    sq = dpp_radd<0x121>(sq);
    if (n0 == 0) {
      sCh[0][co] = us;
      sCh[1][co] = sq;
    }
  }
  __syncthreads();
  if (tid < 51) {
    float* pp = part1 + (size_t)lc * 128;
    atomicAdd(&pp[tid], sCh[0][tid]);
    atomicAdd(&pp[64 + tid], sCh[1][tid]);
  }
}

// ---------------------------------------------------------------------------
// Reduce the 512 lc-sliced stats partials into st.
// ---------------------------------------------------------------------------
__global__ __launch_bounds__(128) void reduce_stats1_kernel(
    const float* __restrict__ p, float* __restrict__ st) {
  const int t = threadIdx.x;
  if (t >= 102) return;
  const int k0 = blockIdx.x * 64;
  const int off = (t < 51) ? t : (64 + t - 51);
  float s = 0.f;
  for (int k = k0; k < k0 + 64; ++k) s += p[k * 128 + off];
  atomicAdd(&st[(t < 51) ? t : (512 + t - 51)], s);
}

// ---------------------------------------------------------------------------
// Per-channel sum/sumsq over [B,C,HL], HL split NS ways; grid (C,B,NS)
// ---------------------------------------------------------------------------
__global__ __launch_bounds__(256) void stats_kernel(
    const float* __restrict__ Y, float* __restrict__ st, int C, int HL,
    int NS) {
  const int c = blockIdx.x, b = blockIdx.y, z = blockIdx.z;
  const int slice = HL / NS;
  const float* p = Y + ((size_t)b * C + c) * HL + (size_t)z * slice;
  float s = 0.f, q = 0.f;
  for (int i = threadIdx.x; i < slice; i += 256) {
    float v = p[i];
    s += v;
    q += v * v;
  }
#pragma unroll
  for (int off = 32; off > 0; off >>= 1) {
    s += __shfl_down(s, off, 64);
    q += __shfl_down(q, off, 64);
  }
  __shared__ float ls[4], lq[4];
  const int wid = threadIdx.x >> 6, lane = threadIdx.x & 63;
  if (lane == 0) { ls[wid] = s; lq[wid] = q; }
  __syncthreads();
  if (threadIdx.x == 0) {
    atomicAdd(&st[c], ls[0] + ls[1] + ls[2] + ls[3]);
    atomicAdd(&st[512 + c], lq[0] + lq[1] + lq[2] + lq[3]);
  }
}

// ---------------------------------------------------------------------------
// reduce NS partial buffers: y[i] = sum_k p[k*stride + i]
// ---------------------------------------------------------------------------
__global__ __launch_bounds__(256) void reduce_parts_kernel(
    const float* __restrict__ p, float* __restrict__ y, int n, int stride,
    int ns) {
  int i = blockIdx.x * 256 + threadIdx.x;
  if (i >= n) return;
  float s = 0.f;
  for (int k = 0; k < ns; ++k) s += p[(size_t)k * stride + i];
  y[i] = s;
}

// ---------------------------------------------------------------------------
// BN(train)+ReLU+pool4, fp32 out
// ---------------------------------------------------------------------------
__global__ __launch_bounds__(256) void bnrelu_pool_kernel(
    const float* __restrict__ Y, const float* __restrict__ st,
    const float* __restrict__ g, const float* __restrict__ bb,
    float* __restrict__ Z, int C, int H, int Lin, float invN,
    unsigned int total) {
  unsigned int idx = blockIdx.x * 256u + threadIdx.x;
  if (idx >= total) return;
  const unsigned int Lo = (unsigned int)(Lin >> 2);
  unsigned int lo = idx % Lo;
  unsigned int r1 = idx / Lo;
  unsigned int h = r1 % (unsigned int)H;
  unsigned int r2 = r1 / (unsigned int)H;
  unsigned int c = r2 % (unsigned int)C;
  unsigned int b = r2 / (unsigned int)C;
  float m = st[c] * invN;
  float v = st[512 + c] * invN - m * m;
  float sc = g[c] * rsqrtf(v + EPSBN);
  float bi = bb[c] - m * sc;
  const float* p = Y + (((size_t)b * C + c) * H + h) * Lin + 4u * lo;
  float a0 = p[0] * sc + bi, a1 = p[1] * sc + bi;
  float a2 = p[2] * sc + bi, a3 = p[3] * sc + bi;
  float r = fmaxf(fmaxf(a0, a1), fmaxf(a2, a3));
  Z[idx] = fmaxf(r, 0.f);
}

// ---- same, bf16 out
__global__ __launch_bounds__(256) void bnrelu_pool_bf16_kernel(
    const float* __restrict__ Y, const float* __restrict__ st,
    const float* __restrict__ g, const float* __restrict__ bb,
    unsigned short* __restrict__ Z, int C, int H, int Lin, float invN,
    unsigned int total) {
  unsigned int idx = blockIdx.x * 256u + threadIdx.x;
  if (idx >= total) return;
  const unsigned int Lo = (unsigned int)(Lin >> 2);
  unsigned int lo = idx % Lo;
  unsigned int r1 = idx / Lo;
  unsigned int h = r1 % (unsigned int)H;
  unsigned int r2 = r1 / (unsigned int)H;
  unsigned int c = r2 % (unsigned int)C;
  unsigned int b = r2 / (unsigned int)C;
  float m = st[c] * invN;
  float v = st[512 + c] * invN - m * m;
  float sc = g[c] * rsqrtf(v + EPSBN);
  float bi = bb[c] - m * sc;
  const float* p = Y + (((size_t)b * C + c) * H + h) * Lin + 4u * lo;
  float a0 = p[0] * sc + bi, a1 = p[1] * sc + bi;
  float a2 = p[2] * sc + bi, a3 = p[3] * sc + bi;
  float r = fmaxf(fmaxf(a0, a1), fmaxf(a2, a3));
  Z[idx] = f2bf(fmaxf(r, 0.f));
}

// ---------------------------------------------------------------------------
// BN(train)+ReLU elementwise, fp32 / bf16 out
// ---------------------------------------------------------------------------
__global__ __launch_bounds__(256) void bnrelu_kernel(
    const float* __restrict__ Y, const float* __restrict__ st,
    const float* __restrict__ g, const float* __restrict__ bb,
    float* __restrict__ A, int C, int HL, float invN, unsigned int total) {
  unsigned int idx = blockIdx.x * 256u + threadIdx.x;
  if (idx >= total) return;
  unsigned int c = (idx / (unsigned int)HL) % (unsigned int)C;
  float m = st[c] * invN;
  float v = st[512 + c] * invN - m * m;
  float sc = g[c] * rsqrtf(v + EPSBN);
  float bi = bb[c] - m * sc;
  A[idx] = fmaxf(fmaf(Y[idx], sc, bi), 0.f);
}

__global__ __launch_bounds__(256) void bnrelu_bf16_kernel(
    const float* __restrict__ Y, const float* __restrict__ st,
    const float* __restrict__ g, const float* __restrict__ bb,
    unsigned short* __restrict__ A, int C, int HL, float invN,
    unsigned int total) {
  unsigned int idx = blockIdx.x * 256u + threadIdx.x;
  if (idx >= total) return;
  unsigned int c = (idx / (unsigned int)HL) % (unsigned int)C;
  float m = st[c] * invN;
  float v = st[512 + c] * invN - m * m;
  float sc = g[c] * rsqrtf(v + EPSBN);
  float bi = bb[c] - m * sc;
  A[idx] = f2bf(fmaxf(fmaf(Y[idx], sc, bi), 0.f));
}

// ---------------------------------------------------------------------------
// Pack fp32 weights -> per-s split bf16 packs with 2^-(s+i) folded.
// ---------------------------------------------------------------------------
__global__ __launch_bounds__(256) void pack_w2_kernel(
    const float* __restrict__ W, short* __restrict__ A, int Co, int KTOT,
    int KPAD, int COPAD, int NS, int nk3) {
  int idx = blockIdx.x * 256 + threadIdx.x;
  const int CK = COPAD * KPAD;
  if (idx >= NS * CK) return;
  int s = idx / CK;
  int rem = idx - s * CK;
  int co = rem / KPAD;
  int kk = rem - co * KPAD;
  float v = 0.f;
  if (co < Co && kk < KTOT) {
    int i = (kk % nk3) / 3;
    float scale = __uint_as_float((unsigned)(127 - (s + i)) << 23);
    v = W[co * KTOT + kk] * scale;
  }
  unsigned short hi = f2bf(v);
  unsigned short lo = f2bf(v - bf2f(hi));
  A[(size_t)s * 2 * CK + co * KPAD + kk] = (short)hi;
  A[(size_t)s * 2 * CK + CK + co * KPAD + kk] = (short)lo;
}

// ---------------------------------------------------------------------------
// gg_mfma5: bf16-input MFMA GConvGG. Tables sized 1024 to admit the deep-K
// tail layers (gg6: KPAD=960, gg7/8: 640) alongside gg2-gg5.
// ---------------------------------------------------------------------------
template <int NKv, int LT>
__global__ __launch_bounds__(256) void gg_mfma5_kernel(
    const unsigned short* __restrict__ X, const short* __restrict__ Apk,
    float* __restrict__ Y, int Ci, int Co, int Hin, int L, int nL, int KTOT,
    int KPAD, int COPAD) {
  constexpr int T = LT / 16;
  constexpr int KO = 256 / LT;
  constexpr int RIT = 8 / KO;

  const int bx = blockIdx.x;
  const int lc = bx % nL;
  const int cog = bx / nL;
  const int s = blockIdx.y;
  const int b = blockIdx.z;
  const int Hout = Hin - NKv + 1;
  const int l0 = lc * LT;
  const int tid = threadIdx.x;
  const int lane = tid & 63;
  const int quad = lane >> 4;
  const int m0 = lane & 15;
  const int wv = tid >> 6;
  const int coBase = cog * 64 + wv * 16;

  __shared__ __align__(16) short Bh[LT * 72];
  __shared__ int roT[1024];
  __shared__ int shT[1024];

  for (int kk = tid; kk < KPAD; kk += 256) {
    int ro = 0, sh = -(1 << 30);
    if (kk < KTOT) {
      int ci = kk / (3 * NKv);
      int rem = kk - ci * (3 * NKv);
      int i = rem / 3;
      int k = rem - 3 * i;
      ro = (ci * Hin + s + i) * L;
      sh = (k - 1) * (1 << (s + i));
    }
    roT[kk] = ro;
    shT[kk] = sh;
  }
  __syncthreads();

  f32x4 acc[T];
#pragma unroll
  for (int t = 0; t < T; ++t) acc[t] = (f32x4){0.f, 0.f, 0.f, 0.f};

  const short* ApkS = Apk + (size_t)s * 2 * COPAD * KPAD;
  const short* arowH = ApkS + (size_t)(coBase + m0) * KPAD;
  const short* arowL = arowH + (size_t)COPAD * KPAD;
  const unsigned short* Xb = X + (size_t)b * Ci * Hin * L;

  const int lB = tid & (LT - 1);
  const int oc0 = tid / LT;
  const int nch = (KTOT + 63) >> 6;

  uint4 v0[RIT], v1[RIT], v2[RIT];
  auto gather = [&](int c0, uint4 (&pk)[RIT]) {
#pragma unroll
    for (int r = 0; r < RIT; ++r) {
      const int oct = oc0 + KO * r;
      const int kkb = (c0 << 6) + oct * 8;
      unsigned w[8];
#pragma unroll
      for (int j = 0; j < 8; ++j) {
        const int kk = kkb + j;
        const int pos = l0 + lB + shT[kk];
        const int posc = min(max(pos, 0), L - 1);
        unsigned u = (unsigned)Xb[roT[kk] + posc];
        w[j] = ((unsigned)pos < (unsigned)L) ? u : 0u;
      }
      pk[r].x = w[0] | (w[1] << 16);
      pk[r].y = w[2] | (w[3] << 16);
      pk[r].z = w[4] | (w[5] << 16);
      pk[r].w = w[6] | (w[7] << 16);
    }
  };

  gather(0, v0);
  if (nch > 1) gather(1, v1);
  for (int c0 = 0; c0 < nch; ++c0) {
#pragma unroll
    for (int r = 0; r < RIT; ++r)
      *(uint4*)(Bh + lB * 72 + (oc0 + KO * r) * 8) = v0[r];
    if (c0 + 2 < nch) gather(c0 + 2, v2);
    const int a0 = (c0 << 6) + quad * 8;
    short8v ah0 = *(const short8v*)(arowH + a0);
    short8v al0 = *(const short8v*)(arowL + a0);
    short8v ah1 = *(const short8v*)(arowH + a0 + 32);
    short8v al1 = *(const short8v*)(arowL + a0 + 32);
    __syncthreads();
#pragma unroll
    for (int t = 0; t < T; ++t) {
      const int l = m0 + 16 * t;
      short8v b0 = *(const short8v*)(Bh + l * 72 + quad * 8);
      short8v b1 = *(const short8v*)(Bh + l * 72 + 32 + quad * 8);
      acc[t] = __builtin_amdgcn_mfma_f32_16x16x32_bf16(ah0, b0, acc[t], 0, 0, 0);
      acc[t] = __builtin_amdgcn_mfma_f32_16x16x32_bf16(al0, b0, acc[t], 0, 0, 0);
      acc[t] = __builtin_amdgcn_mfma_f32_16x16x32_bf16(ah1, b1, acc[t], 0, 0, 0);
      acc[t] = __builtin_amdgcn_mfma_f32_16x16x32_bf16(al1, b1, acc[t], 0, 0, 0);
    }
    __syncthreads();
#pragma unroll
    for (int r = 0; r < RIT; ++r) {
      v0[r] = v1[r];
      v1[r] = v2[r];
    }
  }

#pragma unroll
  for (int reg = 0; reg < 4; ++reg) {
    const int co = coBase + quad * 4 + reg;
    if (co < Co) {
      float* yp = Y + (((size_t)b * Co + co) * Hout + s) * L + l0;
#pragma unroll
      for (int t = 0; t < T; ++t) yp[m0 + 16 * t] = acc[t][reg];
    }
  }
}

// ---------------------------------------------------------------------------
// gg_tail3: unrolled, atomic-free tail GConvGG (R6 config — 32 VGPR, high
// occupancy; tail4's reg double-buffer cost occupancy 64->29% and regressed).
// Kept for gg9/gg10 only.
// ---------------------------------------------------------------------------
template <int NK, int L, int COSUB, int UN>
__global__ __launch_bounds__(256) void gg_tail3_kernel(
    const float* __restrict__ X, const float* __restrict__ W,
    float* __restrict__ Y, int Ci, int Co, int Hin, int NSPLIT, int ciPer,
    int partStride) {
  const int l = threadIdx.x % L;
  const int cs = threadIdx.x / L;
  const int co = blockIdx.x * COSUB + cs;
  const int s = blockIdx.y / NSPLIT;
  const int seg = blockIdx.y % NSPLIT;
  const int b = blockIdx.z;
  const int Hout = Hin - NK + 1;
  const int ciBeg = seg * ciPer;
  const int ciEnd = min(Ci, ciBeg + ciPer);

  float acc[NK];
#pragma unroll
  for (int i = 0; i < NK; ++i) acc[i] = 0.f;

  const float* wbase = W + (size_t)co * Ci * NK * 3;
  const float* xbase = X + ((size_t)b * Ci * Hin + s) * L;

  int ci = ciBeg;
  for (; ci + UN <= ciEnd; ci += UN) {
    float xv[UN][NK][3];
#pragma unroll
    for (int u = 0; u < UN; ++u) {
      const float* xr = xbase + (size_t)(ci + u) * (Hin * L);
#pragma unroll
      for (int i = 0; i < NK; ++i) {
        const int d = 1 << (s + i);
        const float* row = xr + i * L;
        xv[u][i][0] = (l >= d) ? row[l - d] : 0.f;
        xv[u][i][1] = row[l];
        xv[u][i][2] = (l + d < L) ? row[l + d] : 0.f;
      }
    }
#pragma unroll
    for (int u = 0; u < UN; ++u) {
      const float* wp = wbase + (ci + u) * (NK * 3);
#pragma unroll
      for (int i = 0; i < NK; ++i)
        acc[i] = fmaf(wp[3 * i], xv[u][i][0],
                      fmaf(wp[3 * i + 1], xv[u][i][1],
                           fmaf(wp[3 * i + 2], xv[u][i][2], acc[i])));
    }
  }
  for (; ci < ciEnd; ++ci) {
    const float* xr = xbase + (size_t)ci * (Hin * L);
    const float* wp = wbase + ci * (NK * 3);
#pragma unroll
    for (int i = 0; i < NK; ++i) {
      const int d = 1 << (s + i);
      const float* row = xr + i * L;
      float xm = (l >= d) ? row[l - d] : 0.f;
      float xc = row[l];
      float xp = (l + d < L) ? row[l + d] : 0.f;
      acc[i] = fmaf(wp[3 * i], xm,
                    fmaf(wp[3 * i + 1], xc, fmaf(wp[3 * i + 2], xp, acc[i])));
    }
  }
  float out = 0.f;
#pragma unroll
  for (int i = 0; i < NK; ++i) {
    float invd = __uint_as_float((unsigned)(127 - (s + i)) << 23);
    out = fmaf(acc[i], invd, out);
  }
  Y[(size_t)seg * partStride + (((size_t)b * Co + co) * Hout + s) * L + l] =
      out;
}

// ---------------------------------------------------------------------------
// Final: bn10+relu, mean over L, classifier
// ---------------------------------------------------------------------------
__global__ __launch_bounds__(256) void final_kernel(
    const float* __restrict__ Y, const float* __restrict__ st,
    const float* __restrict__ g, const float* __restrict__ bb,
    const float* __restrict__ w11, float* __restrict__ out) {
  const int b = blockIdx.x;
  const int tid = threadIdx.x;
  __shared__ float tch[408];
  for (int c = tid; c < 408; c += 256) {
    float m = st[c] * (1.f / 256.f);
    float v = st[512 + c] * (1.f / 256.f) - m * m;
    float sc = g[c] * rsqrtf(v + EPSBN);
    float bi = bb[c] - m * sc;
    const float* p = Y + ((size_t)b * 408 + c) * 32;
    float ssum = 0.f;
#pragma unroll
    for (int l = 0; l < 32; ++l) ssum += fmaxf(p[l] * sc + bi, 0.f);
    tch[c] = ssum * (1.f / 32.f);
  }
  __syncthreads();
  if (tid < 10) {
    float ssum = 0.f;
    for (int c = 0; c < 408; ++c) ssum += w11[tid * 408 + c] * tch[c];
    out[b * 10 + tid] = ssum;
  }
}

// ---------------------------------------------------------------------------
extern "C" void kernel_launch(void* const* d_in, const int* in_sizes, int n_in,
                              void* d_out, int out_size, void* d_ws,
                              size_t ws_size, hipStream_t stream) {
  const float* x = (const float*)d_in[0];
  const float* w1 = (const float*)d_in[1];
  const float* w2 = (const float*)d_in[2];
  const float* w3 = (const float*)d_in[3];
  const float* w4 = (const float*)d_in[4];
  const float* w5 = (const float*)d_in[5];
  const float* w6 = (const float*)d_in[6];
  const float* w7 = (const float*)d_in[7];
  const float* w8 = (const float*)d_in[8];
  const float* w9 = (const float*)d_in[9];
  const float* w10 = (const float*)d_in[10];
  const float* w11 = (const float*)d_in[11];
  const float* gg[11];
  const float* bbv[11];
  for (int i = 1; i <= 10; ++i) {
    gg[i] = (const float*)d_in[12 + 2 * (i - 1)];
    bbv[i] = (const float*)d_in[12 + 2 * (i - 1) + 1];
  }

  float* ws = (float*)d_ws;
  const size_t AR0 = 0;
  const size_t AR1 = 30081024;
  const size_t STATS = 38900000;
  float* y1 = ws + AR0;
  unsigned* xpad = (unsigned*)(ws + AR1);                 // 456704 dw
  short* apk1 = (short*)(ws + AR1 + 460800);              // 110592 shorts
  unsigned* xpairH = (unsigned*)(ws + AR1 + 520000);      // 4110336 dw
  unsigned* xpairL = (unsigned*)(ws + AR1 + 4630336);     // 4110336 dw
  float* part1 = ws + AR1 + 8740672;                      // 512*128 fp32
  unsigned short* z1b = (unsigned short*)(ws + AR1);
  unsigned short* a3b = (unsigned short*)(ws + AR1);
  unsigned short* z3b = (unsigned short*)(ws + AR1);
  unsigned short* a5b = (unsigned short*)(ws + AR1 + 1500000);
  unsigned short* z5b = (unsigned short*)(ws + AR1);          // 522240 sh
  unsigned short* a6b = (unsigned short*)(ws + AR1 + 522240); // 626688 sh
  unsigned short* a7b = (unsigned short*)(ws + AR1 + 1148928);
  float* z8 = ws + AR1;
  float* a9 = ws + AR1 + 1775616;
  float* part9 = ws + AR1 + 1900000;   // 4 * 104448
  float* part10 = ws + AR1 + 2400000;  // 4 * 104448
  float* y2 = ws + AR0;
  float* y3 = ws + AR0 + 5849088;
  float* y4 = ws + AR0;
  float* y5 = ws + AR0 + 2088960;
  float* y6 = ws + AR0;
  float* y7 = ws + AR0 + 626688;
  float* y8 = ws + AR0 + 1253376;
  float* y9 = ws + AR0;
  float* y10 = ws + AR0 + 104448;
  short* apk2 = (short*)(ws + 12000000);
  short* apk3 = apk2 + 7 * 2 * 64 * 512;
  short* apk4 = apk3 + 7 * 2 * 64 * 192;
  short* apk5 = apk4 + 5 * 2 * 128 * 512;
  short* apk6 = apk5 + 5 * 2 * 128 * 320;   // 3*2*256*960 shorts
  short* apk7 = apk6 + 3 * 2 * 256 * 960;   // 3*2*256*640
  short* apk8 = apk7 + 3 * 2 * 256 * 640;   // 3*2*256*640
  float* st[11];
  for (int i = 1; i <= 10; ++i) st[i] = ws + STATS + (size_t)(i - 1) * 1024;

  hipMemsetAsync((void*)(ws + STATS), 0, 10 * 1024 * sizeof(float), stream);
  hipMemsetAsync((void*)part1, 0, 512 * 128 * sizeof(float), stream);

  // ---- pad x (packed split-bf16), per-s pair arrays, pack w1, MFMA lift
  pad_x_kernel<<<(8 * PROW + 255) / 256, 256, 0, stream>>>(x, xpad);
  pad_pair_kernel<<<dim3((PROW + 255) / 256, 72), 256, 0, stream>>>(
      xpad, xpairH, xpairL);
  pack_w1_kernel<<<(9 * 64 * 96 + 255) / 256, 256, 0, stream>>>(w1, apk1);
  lift_mfma_kernel<<<dim3(512, 9, 8), 256, 0, stream>>>(xpairH, xpairL, apk1,
                                                        y1, part1);
  reduce_stats1_kernel<<<8, 128, 0, stream>>>(part1, st[1]);
  {
    unsigned int tot = 8u * 51 * 9 * 2048;
    bnrelu_pool_bf16_kernel<<<(tot + 255) / 256, 256, 0, stream>>>(
        y1, st[1], gg[1], bbv[1], z1b, 51, 9, 8192, 1.f / 589824.f, tot);
  }
  // ---- per-s weight packs
  pack_w2_kernel<<<(7 * 64 * 512 + 255) / 256, 256, 0, stream>>>(
      w2, apk2, 51, 459, 512, 64, 7, 9);
  pack_w2_kernel<<<(7 * 64 * 192 + 255) / 256, 256, 0, stream>>>(
      w3, apk3, 51, 153, 192, 64, 7, 3);
  pack_w2_kernel<<<(5 * 128 * 512 + 255) / 256, 256, 0, stream>>>(
      w4, apk4, 102, 459, 512, 128, 5, 9);
  pack_w2_kernel<<<(5 * 128 * 320 + 255) / 256, 256, 0, stream>>>(
      w5, apk5, 102, 306, 320, 128, 5, 3);
  pack_w2_kernel<<<(3 * 256 * 960 + 255) / 256, 256, 0, stream>>>(
      w6, apk6, 204, 918, 960, 256, 3, 9);
  pack_w2_kernel<<<(3 * 256 * 640 + 255) / 256, 256, 0, stream>>>(
      w7, apk7, 204, 612, 640, 256, 3, 3);
  pack_w2_kernel<<<(3 * 256 * 640 + 255) / 256, 256, 0, stream>>>(
      w8, apk8, 204, 612, 640, 256, 3, 3);
  // ---- gg2: 51->51, H 9->7, L=2048
  gg_mfma5_kernel<3, 64><<<dim3(32, 7, 8), 256, 0, stream>>>(
      z1b, apk2, y2, 51, 51, 9, 2048, 32, 459, 512, 64);
  stats_kernel<<<dim3(51, 8, 4), 256, 0, stream>>>(y2, st[2], 51, 7 * 2048, 4);
  {
    unsigned int tot = 8u * 51 * 7 * 2048;
    bnrelu_bf16_kernel<<<(tot + 255) / 256, 256, 0, stream>>>(
        y2, st[2], gg[2], bbv[2], a3b, 51, 7 * 2048, 1.f / 114688.f, tot);
  }
  // ---- gg3: 51->51, H7, L=2048
  gg_mfma5_kernel<1, 64><<<dim3(32, 7, 8), 256, 0, stream>>>(
      a3b, apk3, y3, 51, 51, 7, 2048, 32, 153, 192, 64);
  stats_kernel<<<dim3(51, 8, 4), 256, 0, stream>>>(y3, st[3], 51, 7 * 2048, 4);
  {
    unsigned int tot = 8u * 51 * 7 * 512;
    bnrelu_pool_bf16_kernel<<<(tot + 255) / 256, 256, 0, stream>>>(
        y3, st[3], gg[3], bbv[3], z3b, 51, 7, 2048, 1.f / 114688.f, tot);
  }
  // ---- gg4: 51->102, H 7->5, L=512
  gg_mfma5_kernel<3, 32><<<dim3(32, 5, 8), 256, 0, stream>>>(
      z3b, apk4, y4, 51, 102, 7, 512, 16, 459, 512, 128);
  stats_kernel<<<dim3(102, 8, 2), 256, 0, stream>>>(y4, st[4], 102, 5 * 512,
                                                    2);
  {
    unsigned int tot = 8u * 102 * 5 * 512;
    bnrelu_bf16_kernel<<<(tot + 255) / 256, 256, 0, stream>>>(
        y4, st[4], gg[4], bbv[4], a5b, 102, 5 * 512, 1.f / 20480.f, tot);
  }
  // ---- gg5: 102->102, H5, L=512
  gg_mfma5_kernel<1, 32><<<dim3(32, 5, 8), 256, 0, stream>>>(
      a5b, apk5, y5, 102, 102, 5, 512, 16, 306, 320, 128);
  stats_kernel<<<dim3(102, 8, 2), 256, 0, stream>>>(y5, st[5], 102, 5 * 512,
                                                    2);
  {
    unsigned int tot = 8u * 102 * 5 * 128;
    bnrelu_pool_bf16_kernel<<<(tot + 255) / 256, 256, 0, stream>>>(
        y5, st[5], gg[5], bbv[5], z5b, 102, 5, 512, 1.f / 20480.f, tot);
  }
  // ---- gg6: 102->204, H 5->3, L=128 — MFMA path (was gg_tail, 165 µs)
  gg_mfma5_kernel<3, 32><<<dim3(16, 3, 8), 256, 0, stream>>>(
      z5b, apk6, y6, 102, 204, 5, 128, 4, 918, 960, 256);
  stats_kernel<<<dim3(204, 8, 1), 256, 0, stream>>>(y6, st[6], 204, 384, 1);
  {
    unsigned int tot = 8u * 204 * 3 * 128;
    bnrelu_bf16_kernel<<<(tot + 255) / 256, 256, 0, stream>>>(
        y6, st[6], gg[6], bbv[6], a6b, 204, 3 * 128, 1.f / 3072.f, tot);
  }
  // ---- gg7: 204->204, H3, L=128 — MFMA path
  gg_mfma5_kernel<1, 32><<<dim3(16, 3, 8), 256, 0, stream>>>(
      a6b, apk7, y7, 204, 204, 3, 128, 4, 612, 640, 256);
  stats_kernel<<<dim3(204, 8, 1), 256, 0, stream>>>(y7, st[7], 204, 384, 1);
  {
    unsigned int tot = 8u * 204 * 3 * 128;
    bnrelu_bf16_kernel<<<(tot + 255) / 256, 256, 0, stream>>>(
        y7, st[7], gg[7], bbv[7], a7b, 204, 3 * 128, 1.f / 3072.f, tot);
  }
  // ---- gg8: 204->204, H3, L=128 — MFMA path
  gg_mfma5_kernel<1, 32><<<dim3(16, 3, 8), 256, 0, stream>>>(
      a7b, apk8, y8, 204, 204, 3, 128, 4, 612, 640, 256);
  stats_kernel<<<dim3(204, 8, 1), 256, 0, stream>>>(y8, st[8], 204, 384, 1);
  {
    unsigned int tot = 8u * 204 * 3 * 32;
    bnrelu_pool_kernel<<<(tot + 255) / 256, 256, 0, stream>>>(
        y8, st[8], gg[8], bbv[8], z8, 204, 3, 128, 1.f / 3072.f, tot);
  }
  // ---- gg9: 204->408, H 3->1, L=32 (K-split x4 into partials, reduce)
  gg_tail3_kernel<3, 32, 8, 2><<<dim3(51, 4, 8), 256, 0, stream>>>(
      z8, w9, part9, 204, 408, 3, 4, 51, 104448);
  reduce_parts_kernel<<<(104448 + 255) / 256, 256, 0, stream>>>(
      part9, y9, 104448, 104448, 4);
  stats_kernel<<<dim3(408, 8, 1), 256, 0, stream>>>(y9, st[9], 408, 32, 1);
  {
    unsigned int tot = 8u * 408 * 32;
    bnrelu_kernel<<<(tot + 255) / 256, 256, 0, stream>>>(
        y9, st[9], gg[9], bbv[9], a9, 408, 32, 1.f / 256.f, tot);
  }
  // ---- gg10: 408->408, H1, L=32 (K-split x4 into partials, reduce)
  gg_tail3_kernel<1, 32, 8, 8><<<dim3(51, 4, 8), 256, 0, stream>>>(
      a9, w10, part10, 408, 408, 1, 4, 102, 104448);
  reduce_parts_kernel<<<(104448 + 255) / 256, 256, 0, stream>>>(
      part10, y10, 104448, 104448, 4);
  stats_kernel<<<dim3(408, 8, 1), 256, 0, stream>>>(y10, st[10], 408, 32, 1);
  // ---- final
  final_kernel<<<dim3(8), 256, 0, stream>>>(y10, st[10], gg[10], bbv[10], w11,
                                            (float*)d_out);
}

// Round 10
// 607.489 us; speedup vs baseline: 1.8391x; 1.1304x over previous
//
#include <hip/hip_runtime.h>
#include <hip/hip_bf16.h>

#define EPSBN 2e-5f

typedef __attribute__((ext_vector_type(8))) short short8v;
typedef __attribute__((ext_vector_type(4))) float f32x4;

__device__ inline unsigned short f2bf(float f) {
  unsigned u = __float_as_uint(f);
  unsigned r = (u + 0x7FFFu + ((u >> 16) & 1u)) >> 16;
  return (unsigned short)r;
}
__device__ inline float bf2f(unsigned short h) {
  return __uint_as_float(((unsigned)h) << 16);
}

// DPP row-rotate float add: v += rotate_within_16(v, N). VALU pipe, not LDS.
template <int CTRL>
__device__ inline float dpp_radd(float v) {
  int r = __builtin_amdgcn_update_dpp(0, __float_as_int(v), CTRL, 0xf, 0xf,
                                      true);
  return v + __int_as_float(r);
}

// ---------------------------------------------------------------------------
// Padded x staging — packed split-bf16: (hi16 << 16) | lo16.
// ---------------------------------------------------------------------------
constexpr int XPADL = 9984;
constexpr int XPADR = 14336;
constexpr int PROW = XPADL + 32768 + XPADR;  // 57088

__global__ __launch_bounds__(256) void pad_x_kernel(const float* __restrict__ x,
                                                    unsigned* __restrict__ xp) {
  int i = blockIdx.x * 256 + threadIdx.x;
  if (i >= 8 * PROW) return;
  int b = i / PROW;
  int pos = i - b * PROW - XPADL;
  float v = (pos >= 0 && pos < 32768) ? x[b * 32768 + pos] : 0.f;
  unsigned u = __float_as_uint(v);
  unsigned h = u >> 16;
  float lof = v - __uint_as_float(u & 0xffff0000u);
  unsigned lo = __float_as_uint(lof) >> 16;
  xp[i] = (h << 16) | lo;
}

// ---------------------------------------------------------------------------
// Per-scale pair-packed B source
// ---------------------------------------------------------------------------
__global__ __launch_bounds__(256) void pad_pair_kernel(
    const unsigned* __restrict__ xp, unsigned* __restrict__ xpH,
    unsigned* __restrict__ xpL) {
  const int i = blockIdx.x * 256 + threadIdx.x;
  if (i >= PROW) return;
  const int sb = blockIdx.y;  // s*8 + b
  const int s = sb >> 3;
  const int b = sb & 7;
  const int d = 1 << s;
  const unsigned* row = xp + b * PROW;
  unsigned u0 = row[i];
  unsigned u1 = (i + d < PROW) ? row[i + d] : 0u;
  size_t o = (size_t)sb * PROW + i;
  xpH[o] = (u0 >> 16) | (u1 & 0xffff0000u);
  xpL[o] = (u0 & 0xffffu) | (u1 << 16);
}

// ---------------------------------------------------------------------------
// Pack w1 [51][79] -> per-s split bf16 (1/2^s folded), [s][hi/lo][64][96]
// ---------------------------------------------------------------------------
__global__ __launch_bounds__(256) void pack_w1_kernel(
    const float* __restrict__ W, short* __restrict__ A) {
  int idx = blockIdx.x * 256 + threadIdx.x;
  if (idx >= 9 * 64 * 96) return;
  int s = idx / (64 * 96);
  int rem = idx - s * 64 * 96;
  int co = rem / 96;
  int k = rem - co * 96;
  float v = 0.f;
  if (co < 51 && k < 79)
    v = W[co * 79 + k] * __uint_as_float((unsigned)(127 - s) << 23);
  unsigned short hi = f2bf(v);
  unsigned short lo = f2bf(v - bf2f(hi));
  A[(size_t)s * 2 * 64 * 96 + co * 96 + k] = (short)hi;
  A[(size_t)s * 2 * 64 * 96 + 64 * 96 + co * 96 + k] = (short)lo;
}

// ---------------------------------------------------------------------------
// lift_mfma: MFMA GEMM + fused pool4 + DPP stats reduce. y1 fp32 (R9's bf16
// y1 broke absmax: first-layer pre-BN rounding propagates 9 layers).
// ---------------------------------------------------------------------------
__global__ __launch_bounds__(256) void lift_mfma_kernel(
    const unsigned* __restrict__ xpH, const unsigned* __restrict__ xpL,
    const short* __restrict__ Apk1, float* __restrict__ y1,
    float* __restrict__ part1) {
  constexpr int P = 104;
  const int bid = blockIdx.x;
  const int lc = (bid & 7) * 64 + (bid >> 3);  // 512 = 8*64, bijective
  const int s = blockIdx.y;
  const int b = blockIdx.z;
  const int d = 1 << s;
  const int l0 = lc * 64;
  const int tid = threadIdx.x;
  const int lane = tid & 63;
  const int quad = lane >> 4;
  const int n0 = lane & 15;
  const int wv = tid >> 6;
  const int coBase = wv * 16;

  __shared__ __align__(16) short Bh[64 * P];
  __shared__ __align__(16) short Bl[64 * P];
  __shared__ float sCh[2][64];

  const int nB = tid & 63;
  const int rowW = ((nB & 3) << 4) | (nB >> 2);  // LDS row permutation
  const int swzW = (nB & 3) << 3;                // write slot XOR (shorts)
  const int ogu = __builtin_amdgcn_readfirstlane(tid >> 6);
  const unsigned* xqH = xpH + (size_t)(s * 8 + b) * PROW + XPADL + l0;
  const unsigned* xqL = xpL + (size_t)(s * 8 + b) * PROW + XPADL + l0;

#pragma unroll
  for (int r = 0; r < 3; ++r) {
    const int kb = (ogu + 4 * r) * 8;
    const int base = (kb - 39) * d;
    uint4 ph, pl;
    ph.x = xqH[base + nB];
    ph.y = xqH[base + 2 * d + nB];
    ph.z = xqH[base + 4 * d + nB];
    ph.w = xqH[base + 6 * d + nB];
    pl.x = xqL[base + nB];
    pl.y = xqL[base + 2 * d + nB];
    pl.z = xqL[base + 4 * d + nB];
    pl.w = xqL[base + 6 * d + nB];
    *(uint4*)(Bh + rowW * P + (kb ^ swzW)) = ph;
    *(uint4*)(Bl + rowW * P + (kb ^ swzW)) = pl;
  }

  const short* ApkS = Apk1 + (size_t)s * 2 * 64 * 96;
  const short* arowH = ApkS + (coBase + n0) * 96;
  const short* arowL = arowH + 64 * 96;

  __syncthreads();

  f32x4 acc[4];
#pragma unroll
  for (int t = 0; t < 4; ++t) acc[t] = (f32x4){0.f, 0.f, 0.f, 0.f};

#pragma unroll
  for (int ks = 0; ks < 3; ++ks) {
    short8v ah = *(const short8v*)(arowH + ks * 32 + quad * 8);
    short8v al = *(const short8v*)(arowL + ks * 32 + quad * 8);
#pragma unroll
    for (int t = 0; t < 4; ++t) {
      const int n = n0 + 16 * t;
      const int off = (ks * 32 + quad * 8) ^ (t << 3);
      short8v bh = *(const short8v*)(Bh + n * P + off);
      short8v bl = *(const short8v*)(Bl + n * P + off);
      acc[t] = __builtin_amdgcn_mfma_f32_16x16x32_bf16(ah, bh, acc[t], 0, 0, 0);
      acc[t] = __builtin_amdgcn_mfma_f32_16x16x32_bf16(ah, bl, acc[t], 0, 0, 0);
      acc[t] = __builtin_amdgcn_mfma_f32_16x16x32_bf16(al, bh, acc[t], 0, 0, 0);
    }
  }

#pragma unroll
  for (int reg = 0; reg < 4; ++reg) {
    const int co = coBase + quad * 4 + reg;
    float po = fmaxf(fmaxf(acc[0][reg], acc[1][reg]),
                     fmaxf(acc[2][reg], acc[3][reg]));
    const bool valid = (co < 51);
    if (valid) {
      y1[(((size_t)b * 51 + co) * 9 + s) * 8192 + (l0 >> 2) + n0] = po;
    }
    float us = valid ? po : 0.f;
    float sq = us * us;
    us = dpp_radd<0x128>(us);
    sq = dpp_radd<0x128>(sq);
    us = dpp_radd<0x124>(us);
    sq = dpp_radd<0x124>(sq);
    us = dpp_radd<0x122>(us);
    sq = dpp_radd<0x122>(sq);
    us = dpp_radd<0x121>(us);
    sq = dpp_radd<0x121>(sq);
    if (n0 == 0) {
      sCh[0][co] = us;
      sCh[1][co] = sq;
    }
  }
  __syncthreads();
  if (tid < 51) {
    float* pp = part1 + (size_t)lc * 128;
    atomicAdd(&pp[tid], sCh[0][tid]);
    atomicAdd(&pp[64 + tid], sCh[1][tid]);
  }
}

// ---------------------------------------------------------------------------
// Reduce the 512 lc-sliced stats partials into st.
// ---------------------------------------------------------------------------
__global__ __launch_bounds__(128) void reduce_stats1_kernel(
    const float* __restrict__ p, float* __restrict__ st) {
  const int t = threadIdx.x;
  if (t >= 102) return;
  const int k0 = blockIdx.x * 64;
  const int off = (t < 51) ? t : (64 + t - 51);
  float s = 0.f;
  for (int k = k0; k < k0 + 64; ++k) s += p[k * 128 + off];
  atomicAdd(&st[(t < 51) ? t : (512 + t - 51)], s);
}

// ---------------------------------------------------------------------------
// Per-channel sum/sumsq over [B,C,HL], HL split NS ways; grid (C,B,NS)
// (kept for layers 9/10 only)
// ---------------------------------------------------------------------------
__global__ __launch_bounds__(256) void stats_kernel(
    const float* __restrict__ Y, float* __restrict__ st, int C, int HL,
    int NS) {
  const int c = blockIdx.x, b = blockIdx.y, z = blockIdx.z;
  const int slice = HL / NS;
  const float* p = Y + ((size_t)b * C + c) * HL + (size_t)z * slice;
  float s = 0.f, q = 0.f;
  for (int i = threadIdx.x; i < slice; i += 256) {
    float v = p[i];
    s += v;
    q += v * v;
  }
#pragma unroll
  for (int off = 32; off > 0; off >>= 1) {
    s += __shfl_down(s, off, 64);
    q += __shfl_down(q, off, 64);
  }
  __shared__ float ls[4], lq[4];
  const int wid = threadIdx.x >> 6, lane = threadIdx.x & 63;
  if (lane == 0) { ls[wid] = s; lq[wid] = q; }
  __syncthreads();
  if (threadIdx.x == 0) {
    atomicAdd(&st[c], ls[0] + ls[1] + ls[2] + ls[3]);
    atomicAdd(&st[512 + c], lq[0] + lq[1] + lq[2] + lq[3]);
  }
}

// ---------------------------------------------------------------------------
// reduce NS partial buffers: y[i] = sum_k p[k*stride + i]
// ---------------------------------------------------------------------------
__global__ __launch_bounds__(256) void reduce_parts_kernel(
    const float* __restrict__ p, float* __restrict__ y, int n, int stride,
    int ns) {
  int i = blockIdx.x * 256 + threadIdx.x;
  if (i >= n) return;
  float s = 0.f;
  for (int k = 0; k < ns; ++k) s += p[(size_t)k * stride + i];
  y[i] = s;
}

// ---------------------------------------------------------------------------
// Inline 8-slice parts stats: m/v from pp[k*1024 + c], pp[k*1024 + 512 + c]
// ---------------------------------------------------------------------------
__device__ inline void parts_bn(const float* __restrict__ pp, unsigned c,
                                float invN, const float* __restrict__ g,
                                const float* __restrict__ bb, float& sc,
                                float& bi) {
  float ssum = 0.f, sqs = 0.f;
#pragma unroll
  for (int k = 0; k < 8; ++k) {
    ssum += pp[k * 1024 + c];
    sqs += pp[k * 1024 + 512 + c];
  }
  float m = ssum * invN;
  float v = sqs * invN - m * m;
  sc = g[c] * rsqrtf(v + EPSBN);
  bi = bb[c] - m * sc;
}

// ---------------------------------------------------------------------------
// BN(train)+ReLU+pool4, fp32 out — parts stats (layer 8)
// ---------------------------------------------------------------------------
__global__ __launch_bounds__(256) void bnrelu_pool_parts_kernel(
    const float* __restrict__ Y, const float* __restrict__ pp,
    const float* __restrict__ g, const float* __restrict__ bb,
    float* __restrict__ Z, int C, int H, int Lin, float invN,
    unsigned int total) {
  unsigned int idx = blockIdx.x * 256u + threadIdx.x;
  if (idx >= total) return;
  const unsigned int Lo = (unsigned int)(Lin >> 2);
  unsigned int lo = idx % Lo;
  unsigned int r1 = idx / Lo;
  unsigned int h = r1 % (unsigned int)H;
  unsigned int r2 = r1 / (unsigned int)H;
  unsigned int c = r2 % (unsigned int)C;
  unsigned int b = r2 / (unsigned int)C;
  float sc, bi;
  parts_bn(pp, c, invN, g, bb, sc, bi);
  const float* p = Y + (((size_t)b * C + c) * H + h) * Lin + 4u * lo;
  float a0 = p[0] * sc + bi, a1 = p[1] * sc + bi;
  float a2 = p[2] * sc + bi, a3 = p[3] * sc + bi;
  float r = fmaxf(fmaxf(a0, a1), fmaxf(a2, a3));
  Z[idx] = fmaxf(r, 0.f);
}

// ---- BN+ReLU+pool4 bf16-out, parts stats (layers 3,5)
__global__ __launch_bounds__(256) void bnrelu_pool_bf16_parts_kernel(
    const float* __restrict__ Y, const float* __restrict__ pp,
    const float* __restrict__ g, const float* __restrict__ bb,
    unsigned short* __restrict__ Z, int C, int H, int Lin, float invN,
    unsigned int total) {
  unsigned int idx = blockIdx.x * 256u + threadIdx.x;
  if (idx >= total) return;
  const unsigned int Lo = (unsigned int)(Lin >> 2);
  unsigned int lo = idx % Lo;
  unsigned int r1 = idx / Lo;
  unsigned int h = r1 % (unsigned int)H;
  unsigned int r2 = r1 / (unsigned int)H;
  unsigned int c = r2 % (unsigned int)C;
  unsigned int b = r2 / (unsigned int)C;
  float sc, bi;
  parts_bn(pp, c, invN, g, bb, sc, bi);
  const float* p = Y + (((size_t)b * C + c) * H + h) * Lin + 4u * lo;
  float a0 = p[0] * sc + bi, a1 = p[1] * sc + bi;
  float a2 = p[2] * sc + bi, a3 = p[3] * sc + bi;
  float r = fmaxf(fmaxf(a0, a1), fmaxf(a2, a3));
  Z[idx] = f2bf(fmaxf(r, 0.f));
}

// ---- BN+ReLU+pool4 bf16-out, fp32 input, st stats (layer 1)
__global__ __launch_bounds__(256) void bnrelu_pool_bf16_kernel(
    const float* __restrict__ Y, const float* __restrict__ st,
    const float* __restrict__ g, const float* __restrict__ bb,
    unsigned short* __restrict__ Z, int C, int H, int Lin, float invN,
    unsigned int total) {
  unsigned int idx = blockIdx.x * 256u + threadIdx.x;
  if (idx >= total) return;
  const unsigned int Lo = (unsigned int)(Lin >> 2);
  unsigned int lo = idx % Lo;
  unsigned int r1 = idx / Lo;
  unsigned int h = r1 % (unsigned int)H;
  unsigned int r2 = r1 / (unsigned int)H;
  unsigned int c = r2 % (unsigned int)C;
  unsigned int b = r2 / (unsigned int)C;
  float m = st[c] * invN;
  float v = st[512 + c] * invN - m * m;
  float sc = g[c] * rsqrtf(v + EPSBN);
  float bi = bb[c] - m * sc;
  const float* p = Y + (((size_t)b * C + c) * H + h) * Lin + 4u * lo;
  float a0 = p[0] * sc + bi, a1 = p[1] * sc + bi;
  float a2 = p[2] * sc + bi, a3 = p[3] * sc + bi;
  float r = fmaxf(fmaxf(a0, a1), fmaxf(a2, a3));
  Z[idx] = f2bf(fmaxf(r, 0.f));
}

// ---------------------------------------------------------------------------
// BN(train)+ReLU elementwise, fp32 out (layer 9) — st stats
// ---------------------------------------------------------------------------
__global__ __launch_bounds__(256) void bnrelu_kernel(
    const float* __restrict__ Y, const float* __restrict__ st,
    const float* __restrict__ g, const float* __restrict__ bb,
    float* __restrict__ A, int C, int HL, float invN, unsigned int total) {
  unsigned int idx = blockIdx.x * 256u + threadIdx.x;
  if (idx >= total) return;
  unsigned int c = (idx / (unsigned int)HL) % (unsigned int)C;
  float m = st[c] * invN;
  float v = st[512 + c] * invN - m * m;
  float sc = g[c] * rsqrtf(v + EPSBN);
  float bi = bb[c] - m * sc;
  A[idx] = fmaxf(fmaf(Y[idx], sc, bi), 0.f);
}

// ---- BN+ReLU bf16-out, parts stats (layers 2,4,6,7)
__global__ __launch_bounds__(256) void bnrelu_bf16_parts_kernel(
    const float* __restrict__ Y, const float* __restrict__ pp,
    const float* __restrict__ g, const float* __restrict__ bb,
    unsigned short* __restrict__ A, int C, int HL, float invN,
    unsigned int total) {
  unsigned int idx = blockIdx.x * 256u + threadIdx.x;
  if (idx >= total) return;
  unsigned int c = (idx / (unsigned int)HL) % (unsigned int)C;
  float sc, bi;
  parts_bn(pp, c, invN, g, bb, sc, bi);
  A[idx] = f2bf(fmaxf(fmaf(Y[idx], sc, bi), 0.f));
}

// ---------------------------------------------------------------------------
// Pack fp32 weights -> per-s split bf16 packs with 2^-(s+i) folded.
// ---------------------------------------------------------------------------
__global__ __launch_bounds__(256) void pack_w2_kernel(
    const float* __restrict__ W, short* __restrict__ A, int Co, int KTOT,
    int KPAD, int COPAD, int NS, int nk3) {
  int idx = blockIdx.x * 256 + threadIdx.x;
  const int CK = COPAD * KPAD;
  if (idx >= NS * CK) return;
  int s = idx / CK;
  int rem = idx - s * CK;
  int co = rem / KPAD;
  int kk = rem - co * KPAD;
  float v = 0.f;
  if (co < Co && kk < KTOT) {
    int i = (kk % nk3) / 3;
    float scale = __uint_as_float((unsigned)(127 - (s + i)) << 23);
    v = W[co * KTOT + kk] * scale;
  }
  unsigned short hi = f2bf(v);
  unsigned short lo = f2bf(v - bf2f(hi));
  A[(size_t)s * 2 * CK + co * KPAD + kk] = (short)hi;
  A[(size_t)s * 2 * CK + CK + co * KPAD + kk] = (short)lo;
}

// ---------------------------------------------------------------------------
// gg_mfma5: bf16-input MFMA GConvGG + fused per-channel stats (DPP reduce
// per 16-lane quad-row, lc-sliced atomic parts).
// ---------------------------------------------------------------------------
template <int NKv, int LT>
__global__ __launch_bounds__(256) void gg_mfma5_kernel(
    const unsigned short* __restrict__ X, const short* __restrict__ Apk,
    float* __restrict__ Y, float* __restrict__ part, int Ci, int Co, int Hin,
    int L, int nL, int KTOT, int KPAD, int COPAD) {
  constexpr int T = LT / 16;
  constexpr int KO = 256 / LT;
  constexpr int RIT = 8 / KO;

  const int bx = blockIdx.x;
  const int lc = bx % nL;
  const int cog = bx / nL;
  const int s = blockIdx.y;
  const int b = blockIdx.z;
  const int Hout = Hin - NKv + 1;
  const int l0 = lc * LT;
  const int tid = threadIdx.x;
  const int lane = tid & 63;
  const int quad = lane >> 4;
  const int m0 = lane & 15;
  const int wv = tid >> 6;
  const int coBase = cog * 64 + wv * 16;

  __shared__ __align__(16) short Bh[LT * 72];
  __shared__ int roT[1024];
  __shared__ int shT[1024];
  __shared__ float sCh[2][64];

  for (int kk = tid; kk < KPAD; kk += 256) {
    int ro = 0, sh = -(1 << 30);
    if (kk < KTOT) {
      int ci = kk / (3 * NKv);
      int rem = kk - ci * (3 * NKv);
      int i = rem / 3;
      int k = rem - 3 * i;
      ro = (ci * Hin + s + i) * L;
      sh = (k - 1) * (1 << (s + i));
    }
    roT[kk] = ro;
    shT[kk] = sh;
  }
  __syncthreads();

  f32x4 acc[T];
#pragma unroll
  for (int t = 0; t < T; ++t) acc[t] = (f32x4){0.f, 0.f, 0.f, 0.f};

  const short* ApkS = Apk + (size_t)s * 2 * COPAD * KPAD;
  const short* arowH = ApkS + (size_t)(coBase + m0) * KPAD;
  const short* arowL = arowH + (size_t)COPAD * KPAD;
  const unsigned short* Xb = X + (size_t)b * Ci * Hin * L;

  const int lB = tid & (LT - 1);
  const int oc0 = tid / LT;
  const int nch = (KTOT + 63) >> 6;

  uint4 v0[RIT], v1[RIT], v2[RIT];
  auto gather = [&](int c0, uint4 (&pk)[RIT]) {
#pragma unroll
    for (int r = 0; r < RIT; ++r) {
      const int oct = oc0 + KO * r;
      const int kkb = (c0 << 6) + oct * 8;
      unsigned w[8];
#pragma unroll
      for (int j = 0; j < 8; ++j) {
        const int kk = kkb + j;
        const int pos = l0 + lB + shT[kk];
        const int posc = min(max(pos, 0), L - 1);
        unsigned u = (unsigned)Xb[roT[kk] + posc];
        w[j] = ((unsigned)pos < (unsigned)L) ? u : 0u;
      }
      pk[r].x = w[0] | (w[1] << 16);
      pk[r].y = w[2] | (w[3] << 16);
      pk[r].z = w[4] | (w[5] << 16);
      pk[r].w = w[6] | (w[7] << 16);
    }
  };

  gather(0, v0);
  if (nch > 1) gather(1, v1);
  for (int c0 = 0; c0 < nch; ++c0) {
#pragma unroll
    for (int r = 0; r < RIT; ++r)
      *(uint4*)(Bh + lB * 72 + (oc0 + KO * r) * 8) = v0[r];
    if (c0 + 2 < nch) gather(c0 + 2, v2);
    const int a0 = (c0 << 6) + quad * 8;
    short8v ah0 = *(const short8v*)(arowH + a0);
    short8v al0 = *(const short8v*)(arowL + a0);
    short8v ah1 = *(const short8v*)(arowH + a0 + 32);
    short8v al1 = *(const short8v*)(arowL + a0 + 32);
    __syncthreads();
#pragma unroll
    for (int t = 0; t < T; ++t) {
      const int l = m0 + 16 * t;
      short8v b0 = *(const short8v*)(Bh + l * 72 + quad * 8);
      short8v b1 = *(const short8v*)(Bh + l * 72 + 32 + quad * 8);
      acc[t] = __builtin_amdgcn_mfma_f32_16x16x32_bf16(ah0, b0, acc[t], 0, 0, 0);
      acc[t] = __builtin_amdgcn_mfma_f32_16x16x32_bf16(al0, b0, acc[t], 0, 0, 0);
      acc[t] = __builtin_amdgcn_mfma_f32_16x16x32_bf16(ah1, b1, acc[t], 0, 0, 0);
      acc[t] = __builtin_amdgcn_mfma_f32_16x16x32_bf16(al1, b1, acc[t], 0, 0, 0);
    }
    __syncthreads();
#pragma unroll
    for (int r = 0; r < RIT; ++r) {
      v0[r] = v1[r];
      v1[r] = v2[r];
    }
  }

#pragma unroll
  for (int reg = 0; reg < 4; ++reg) {
    const int co = coBase + quad * 4 + reg;
    float ss = 0.f, sq = 0.f;
    if (co < Co) {
      float* yp = Y + (((size_t)b * Co + co) * Hout + s) * L + l0;
#pragma unroll
      for (int t = 0; t < T; ++t) {
        float v = acc[t][reg];
        yp[m0 + 16 * t] = v;
        ss += v;
        sq = fmaf(v, v, sq);
      }
    }
    ss = dpp_radd<0x128>(ss);
    sq = dpp_radd<0x128>(sq);
    ss = dpp_radd<0x124>(ss);
    sq = dpp_radd<0x124>(sq);
    ss = dpp_radd<0x122>(ss);
    sq = dpp_radd<0x122>(sq);
    ss = dpp_radd<0x121>(ss);
    sq = dpp_radd<0x121>(sq);
    if (m0 == 0) {
      sCh[0][wv * 16 + quad * 4 + reg] = ss;
      sCh[1][wv * 16 + quad * 4 + reg] = sq;
    }
  }
  __syncthreads();
  if (tid < 64) {
    const int co = cog * 64 + tid;
    if (co < Co) {
      float* pp = part + (size_t)(lc & 7) * 1024;
      atomicAdd(&pp[co], sCh[0][tid]);
      atomicAdd(&pp[512 + co], sCh[1][tid]);
    }
  }
}

// ---------------------------------------------------------------------------
// gg_tail3: unrolled, atomic-free tail GConvGG (layers 9/10).
// ---------------------------------------------------------------------------
template <int NK, int L, int COSUB, int UN>
__global__ __launch_bounds__(256) void gg_tail3_kernel(
    const float* __restrict__ X, const float* __restrict__ W,
    float* __restrict__ Y, int Ci, int Co, int Hin, int NSPLIT, int ciPer,
    int partStride) {
  const int l = threadIdx.x % L;
  const int cs = threadIdx.x / L;
  const int co = blockIdx.x * COSUB + cs;
  const int s = blockIdx.y / NSPLIT;
  const int seg = blockIdx.y % NSPLIT;
  const int b = blockIdx.z;
  const int Hout = Hin - NK + 1;
  const int ciBeg = seg * ciPer;
  const int ciEnd = min(Ci, ciBeg + ciPer);

  float acc[NK];
#pragma unroll
  for (int i = 0; i < NK; ++i) acc[i] = 0.f;

  const float* wbase = W + (size_t)co * Ci * NK * 3;
  const float* xbase = X + ((size_t)b * Ci * Hin + s) * L;

  int ci = ciBeg;
  for (; ci + UN <= ciEnd; ci += UN) {
    float xv[UN][NK][3];
#pragma unroll
    for (int u = 0; u < UN; ++u) {
      const float* xr = xbase + (size_t)(ci + u) * (Hin * L);
#pragma unroll
      for (int i = 0; i < NK; ++i) {
        const int d = 1 << (s + i);
        const float* row = xr + i * L;
        xv[u][i][0] = (l >= d) ? row[l - d] : 0.f;
        xv[u][i][1] = row[l];
        xv[u][i][2] = (l + d < L) ? row[l + d] : 0.f;
      }
    }
#pragma unroll
    for (int u = 0; u < UN; ++u) {
      const float* wp = wbase + (ci + u) * (NK * 3);
#pragma unroll
      for (int i = 0; i < NK; ++i)
        acc[i] = fmaf(wp[3 * i], xv[u][i][0],
                      fmaf(wp[3 * i + 1], xv[u][i][1],
                           fmaf(wp[3 * i + 2], xv[u][i][2], acc[i])));
    }
  }
  for (; ci < ciEnd; ++ci) {
    const float* xr = xbase + (size_t)ci * (Hin * L);
    const float* wp = wbase + ci * (NK * 3);
#pragma unroll
    for (int i = 0; i < NK; ++i) {
      const int d = 1 << (s + i);
      const float* row = xr + i * L;
      float xm = (l >= d) ? row[l - d] : 0.f;
      float xc = row[l];
      float xp = (l + d < L) ? row[l + d] : 0.f;
      acc[i] = fmaf(wp[3 * i], xm,
                    fmaf(wp[3 * i + 1], xc, fmaf(wp[3 * i + 2], xp, acc[i])));
    }
  }
  float out = 0.f;
#pragma unroll
  for (int i = 0; i < NK; ++i) {
    float invd = __uint_as_float((unsigned)(127 - (s + i)) << 23);
    out = fmaf(acc[i], invd, out);
  }
  Y[(size_t)seg * partStride + (((size_t)b * Co + co) * Hout + s) * L + l] =
      out;
}

// ---------------------------------------------------------------------------
// Final: bn10+relu, mean over L, classifier
// ---------------------------------------------------------------------------
__global__ __launch_bounds__(256) void final_kernel(
    const float* __restrict__ Y, const float* __restrict__ st,
    const float* __restrict__ g, const float* __restrict__ bb,
    const float* __restrict__ w11, float* __restrict__ out) {
  const int b = blockIdx.x;
  const int tid = threadIdx.x;
  __shared__ float tch[408];
  for (int c = tid; c < 408; c += 256) {
    float m = st[c] * (1.f / 256.f);
    float v = st[512 + c] * (1.f / 256.f) - m * m;
    float sc = g[c] * rsqrtf(v + EPSBN);
    float bi = bb[c] - m * sc;
    const float* p = Y + ((size_t)b * 408 + c) * 32;
    float ssum = 0.f;
#pragma unroll
    for (int l = 0; l < 32; ++l) ssum += fmaxf(p[l] * sc + bi, 0.f);
    tch[c] = ssum * (1.f / 32.f);
  }
  __syncthreads();
  if (tid < 10) {
    float ssum = 0.f;
    for (int c = 0; c < 408; ++c) ssum += w11[tid * 408 + c] * tch[c];
    out[b * 10 + tid] = ssum;
  }
}

// ---------------------------------------------------------------------------
extern "C" void kernel_launch(void* const* d_in, const int* in_sizes, int n_in,
                              void* d_out, int out_size, void* d_ws,
                              size_t ws_size, hipStream_t stream) {
  const float* x = (const float*)d_in[0];
  const float* w1 = (const float*)d_in[1];
  const float* w2 = (const float*)d_in[2];
  const float* w3 = (const float*)d_in[3];
  const float* w4 = (const float*)d_in[4];
  const float* w5 = (const float*)d_in[5];
  const float* w6 = (const float*)d_in[6];
  const float* w7 = (const float*)d_in[7];
  const float* w8 = (const float*)d_in[8];
  const float* w9 = (const float*)d_in[9];
  const float* w10 = (const float*)d_in[10];
  const float* w11 = (const float*)d_in[11];
  const float* gg[11];
  const float* bbv[11];
  for (int i = 1; i <= 10; ++i) {
    gg[i] = (const float*)d_in[12 + 2 * (i - 1)];
    bbv[i] = (const float*)d_in[12 + 2 * (i - 1) + 1];
  }

  float* ws = (float*)d_ws;
  const size_t AR0 = 0;
  const size_t AR1 = 30081024;
  const size_t STATS = 38900000;
  float* y1 = ws + AR0;
  unsigned* xpad = (unsigned*)(ws + AR1);                 // 456704 dw
  short* apk1 = (short*)(ws + AR1 + 460800);              // 110592 shorts
  unsigned* xpairH = (unsigned*)(ws + AR1 + 520000);      // 4110336 dw
  unsigned* xpairL = (unsigned*)(ws + AR1 + 4630336);     // 4110336 dw
  float* part1 = ws + AR1 + 8740672;                      // 512*128 fp32
  unsigned short* z1b = (unsigned short*)(ws + AR1);
  unsigned short* a3b = (unsigned short*)(ws + AR1);
  unsigned short* z3b = (unsigned short*)(ws + AR1);
  unsigned short* a5b = (unsigned short*)(ws + AR1 + 1500000);
  unsigned short* z5b = (unsigned short*)(ws + AR1);          // 522240 sh
  unsigned short* a6b = (unsigned short*)(ws + AR1 + 522240); // 626688 sh
  unsigned short* a7b = (unsigned short*)(ws + AR1 + 1148928);
  float* z8 = ws + AR1;
  float* a9 = ws + AR1 + 1775616;
  float* part9 = ws + AR1 + 1900000;   // 4 * 104448
  float* part10 = ws + AR1 + 2400000;  // 4 * 104448
  float* y2 = ws + AR0;
  float* y3 = ws + AR0 + 5849088;
  float* y4 = ws + AR0;
  float* y5 = ws + AR0 + 2088960;
  float* y6 = ws + AR0;
  float* y7 = ws + AR0 + 626688;
  float* y8 = ws + AR0 + 1253376;
  float* y9 = ws + AR0;
  float* y10 = ws + AR0 + 104448;
  short* apk2 = (short*)(ws + 12000000);
  short* apk3 = apk2 + 7 * 2 * 64 * 512;
  short* apk4 = apk3 + 7 * 2 * 64 * 192;
  short* apk5 = apk4 + 5 * 2 * 128 * 512;
  short* apk6 = apk5 + 5 * 2 * 128 * 320;   // 3*2*256*960 shorts
  short* apk7 = apk6 + 3 * 2 * 256 * 960;   // 3*2*256*640
  short* apk8 = apk7 + 3 * 2 * 256 * 640;   // 3*2*256*640
  float* st[11];
  for (int i = 1; i <= 10; ++i) st[i] = ws + STATS + (size_t)(i - 1) * 1024;
  // per-layer 8-slice stats parts for layers 2..8 (8*1024 floats each)
  float* partg = ws + STATS + 10240;
  float* part2 = partg;
  float* part3 = partg + 8192;
  float* part4 = partg + 2 * 8192;
  float* part5 = partg + 3 * 8192;
  float* part6 = partg + 4 * 8192;
  float* part7 = partg + 5 * 8192;
  float* part8 = partg + 6 * 8192;

  hipMemsetAsync((void*)(ws + STATS), 0, 10 * 1024 * sizeof(float), stream);
  hipMemsetAsync((void*)part1, 0, 512 * 128 * sizeof(float), stream);
  hipMemsetAsync((void*)partg, 0, 7 * 8192 * sizeof(float), stream);

  // ---- pad x (packed split-bf16), per-s pair arrays, pack w1, MFMA lift
  pad_x_kernel<<<(8 * PROW + 255) / 256, 256, 0, stream>>>(x, xpad);
  pad_pair_kernel<<<dim3((PROW + 255) / 256, 72), 256, 0, stream>>>(
      xpad, xpairH, xpairL);
  pack_w1_kernel<<<(9 * 64 * 96 + 255) / 256, 256, 0, stream>>>(w1, apk1);
  lift_mfma_kernel<<<dim3(512, 9, 8), 256, 0, stream>>>(xpairH, xpairL, apk1,
                                                        y1, part1);
  reduce_stats1_kernel<<<8, 128, 0, stream>>>(part1, st[1]);
  {
    unsigned int tot = 8u * 51 * 9 * 2048;
    bnrelu_pool_bf16_kernel<<<(tot + 255) / 256, 256, 0, stream>>>(
        y1, st[1], gg[1], bbv[1], z1b, 51, 9, 8192, 1.f / 589824.f, tot);
  }
  // ---- per-s weight packs
  pack_w2_kernel<<<(7 * 64 * 512 + 255) / 256, 256, 0, stream>>>(
      w2, apk2, 51, 459, 512, 64, 7, 9);
  pack_w2_kernel<<<(7 * 64 * 192 + 255) / 256, 256, 0, stream>>>(
      w3, apk3, 51, 153, 192, 64, 7, 3);
  pack_w2_kernel<<<(5 * 128 * 512 + 255) / 256, 256, 0, stream>>>(
      w4, apk4, 102, 459, 512, 128, 5, 9);
  pack_w2_kernel<<<(5 * 128 * 320 + 255) / 256, 256, 0, stream>>>(
      w5, apk5, 102, 306, 320, 128, 5, 3);
  pack_w2_kernel<<<(3 * 256 * 960 + 255) / 256, 256, 0, stream>>>(
      w6, apk6, 204, 918, 960, 256, 3, 9);
  pack_w2_kernel<<<(3 * 256 * 640 + 255) / 256, 256, 0, stream>>>(
      w7, apk7, 204, 612, 640, 256, 3, 3);
  pack_w2_kernel<<<(3 * 256 * 640 + 255) / 256, 256, 0, stream>>>(
      w8, apk8, 204, 612, 640, 256, 3, 3);
  // ---- gg2: 51->51, H 9->7, L=2048 (fused stats)
  gg_mfma5_kernel<3, 64><<<dim3(32, 7, 8), 256, 0, stream>>>(
      z1b, apk2, y2, part2, 51, 51, 9, 2048, 32, 459, 512, 64);
  {
    unsigned int tot = 8u * 51 * 7 * 2048;
    bnrelu_bf16_parts_kernel<<<(tot + 255) / 256, 256, 0, stream>>>(
        y2, part2, gg[2], bbv[2], a3b, 51, 7 * 2048, 1.f / 114688.f, tot);
  }
  // ---- gg3: 51->51, H7, L=2048 (fused stats)
  gg_mfma5_kernel<1, 64><<<dim3(32, 7, 8), 256, 0, stream>>>(
      a3b, apk3, y3, part3, 51, 51, 7, 2048, 32, 153, 192, 64);
  {
    unsigned int tot = 8u * 51 * 7 * 512;
    bnrelu_pool_bf16_parts_kernel<<<(tot + 255) / 256, 256, 0, stream>>>(
        y3, part3, gg[3], bbv[3], z3b, 51, 7, 2048, 1.f / 114688.f, tot);
  }
  // ---- gg4: 51->102, H 7->5, L=512 (fused stats)
  gg_mfma5_kernel<3, 32><<<dim3(32, 5, 8), 256, 0, stream>>>(
      z3b, apk4, y4, part4, 51, 102, 7, 512, 16, 459, 512, 128);
  {
    unsigned int tot = 8u * 102 * 5 * 512;
    bnrelu_bf16_parts_kernel<<<(tot + 255) / 256, 256, 0, stream>>>(
        y4, part4, gg[4], bbv[4], a5b, 102, 5 * 512, 1.f / 20480.f, tot);
  }
  // ---- gg5: 102->102, H5, L=512 (fused stats)
  gg_mfma5_kernel<1, 32><<<dim3(32, 5, 8), 256, 0, stream>>>(
      a5b, apk5, y5, part5, 102, 102, 5, 512, 16, 306, 320, 128);
  {
    unsigned int tot = 8u * 102 * 5 * 128;
    bnrelu_pool_bf16_parts_kernel<<<(tot + 255) / 256, 256, 0, stream>>>(
        y5, part5, gg[5], bbv[5], z5b, 102, 5, 512, 1.f / 20480.f, tot);
  }
  // ---- gg6: 102->204, H 5->3, L=128 — MFMA + fused stats
  gg_mfma5_kernel<3, 32><<<dim3(16, 3, 8), 256, 0, stream>>>(
      z5b, apk6, y6, part6, 102, 204, 5, 128, 4, 918, 960, 256);
  {
    unsigned int tot = 8u * 204 * 3 * 128;
    bnrelu_bf16_parts_kernel<<<(tot + 255) / 256, 256, 0, stream>>>(
        y6, part6, gg[6], bbv[6], a6b, 204, 3 * 128, 1.f / 3072.f, tot);
  }
  // ---- gg7: 204->204, H3, L=128 — MFMA + fused stats
  gg_mfma5_kernel<1, 32><<<dim3(16, 3, 8), 256, 0, stream>>>(
      a6b, apk7, y7, part7, 204, 204, 3, 128, 4, 612, 640, 256);
  {
    unsigned int tot = 8u * 204 * 3 * 128;
    bnrelu_bf16_parts_kernel<<<(tot + 255) / 256, 256, 0, stream>>>(
        y7, part7, gg[7], bbv[7], a7b, 204, 3 * 128, 1.f / 3072.f, tot);
  }
  // ---- gg8: 204->204, H3, L=128 — MFMA + fused stats
  gg_mfma5_kernel<1, 32><<<dim3(16, 3, 8), 256, 0, stream>>>(
      a7b, apk8, y8, part8, 204, 204, 3, 128, 4, 612, 640, 256);
  {
    unsigned int tot = 8u * 204 * 3 * 32;
    bnrelu_pool_parts_kernel<<<(tot + 255) / 256, 256, 0, stream>>>(
        y8, part8, gg[8], bbv[8], z8, 204, 3, 128, 1.f / 3072.f, tot);
  }
  // ---- gg9: 204->408, H 3->1, L=32 (K-split x4 into partials, reduce)
  gg_tail3_kernel<3, 32, 8, 2><<<dim3(51, 4, 8), 256, 0, stream>>>(
      z8, w9, part9, 204, 408, 3, 4, 51, 104448);
  reduce_parts_kernel<<<(104448 + 255) / 256, 256, 0, stream>>>(
      part9, y9, 104448, 104448, 4);
  stats_kernel<<<dim3(408, 8, 1), 256, 0, stream>>>(y9, st[9], 408, 32, 1);
  {
    unsigned int tot = 8u * 408 * 32;
    bnrelu_kernel<<<(tot + 255) / 256, 256, 0, stream>>>(
        y9, st[9], gg[9], bbv[9], a9, 408, 32, 1.f / 256.f, tot);
  }
  // ---- gg10: 408->408, H1, L=32 (K-split x4 into partials, reduce)
  gg_tail3_kernel<1, 32, 8, 8><<<dim3(51, 4, 8), 256, 0, stream>>>(
      a9, w10, part10, 408, 408, 1, 4, 102, 104448);
  reduce_parts_kernel<<<(104448 + 255) / 256, 256, 0, stream>>>(
      part10, y10, 104448, 104448, 4);
  stats_kernel<<<dim3(408, 8, 1), 256, 0, stream>>>(y10, st[10], 408, 32, 1);
  // ---- final
  final_kernel<<<dim3(8), 256, 0, stream>>>(y10, st[10], gg[10], bbv[10], w11,
                                            (float*)d_out);
}